// Round 7
// baseline (1557.673 us; speedup 1.0000x reference)
//
#include <hip/hip_runtime.h>
#include <hip/hip_bf16.h>
#include <cfloat>

using bf16 = __hip_bfloat16;

typedef short short8 __attribute__((ext_vector_type(8)));
typedef float floatx16 __attribute__((ext_vector_type(16)));
union Frag { short8 v; uint2 u2[2]; };
union FragQ { short8 v; uint4 q; uint2 u2[2]; };
union U4b { uint4 q; unsigned short s[8]; };

constexpr int Bb = 8, Nn = 4096, Kk = 20;
constexpr int BN = Bb * Nn;                     // 32768
constexpr int Mrows = BN * Kk;                  // 655360
constexpr float EPSf = 1e-5f;

static __device__ __forceinline__ float b2f(bf16 v){ return __bfloat162float(v); }
static __device__ __forceinline__ bf16 f2b(float v){ return __float2bfloat16(v); }
static __device__ __forceinline__ unsigned short f2bu(float v){
  union { bf16 b; unsigned short u; } cv; cv.b = __float2bfloat16(v); return cv.u;
}
static __device__ __forceinline__ float bits2f(unsigned short u){
  union { unsigned int i; float f; } c; c.i = ((unsigned)u)<<16; return c.f;
}
static __device__ __forceinline__ float ldf(bf16 v){ return b2f(v); }
static __device__ __forceinline__ float ldf(float v){ return v; }

// ---------------- zero workspace region ----------------
__global__ void zero_kernel(float* __restrict__ p, int n){
  int i = blockIdx.x*256 + threadIdx.x;
  if (i < n) p[i] = 0.f;
}

// ---------------- W3^T bf16 pack ----------------
__global__ void w3t_kernel(const float* __restrict__ W3f, bf16* __restrict__ W3T){
  int id = blockIdx.x*256 + threadIdx.x;   // 128*64 = 8192 elems
  if (id >= 128*64) return;
  int n = id >> 6, k = id & 63;
  W3T[id] = f2b(W3f[(size_t)k*128 + n]);
}

// ---------------- W4^T bf16 pack ----------------
__global__ void w4t_kernel(const float* __restrict__ W4f, bf16* __restrict__ W4T){
  int id = blockIdx.x*256 + threadIdx.x;   // 128*256 = 32768 elems
  if (id >= 128*256) return;
  int k = id >> 8, c = id & 255;           // coalesced read of W4f
  W4T[(size_t)c*128 + k] = f2b(W4f[id]);
}

// ---------------- W5^T bf16 pack ----------------
__global__ void w5t_kernel(const float* __restrict__ W5f, bf16* __restrict__ W5T){
  int id = blockIdx.x*256 + threadIdx.x;   // 512*512 = 262144 elems
  if (id >= 512*512) return;
  int k = id >> 9, c = id & 511;           // coalesced read of W5f
  W5T[(size_t)c*512 + k] = f2b(W5f[id]);
}

// ---------------- KNN phase A v4: fast-fma threshold (groups of 16) + exact final ----
// Pass A computes nd with a 4-op fused form (margin-compensated); threshold = 20th-
// largest of 32 group-maxes, nudged down by |thr|*1e-4+1e-6 (>> fp discrepancy vs the
// exact contract-off formula). Pass B admits via fast compare (superset). Final sort
// recomputes nd with the EXACT original formula => selection identical to reference.
// CAP=48 (E~30); exact full-scan fallback if a lane saturates (correct for all inputs).
__global__ __launch_bounds__(256) void knnA_kernel(const float* __restrict__ x,
                                                   float* __restrict__ pv, int* __restrict__ pi){
#pragma clang fp contract(off)
  __shared__ float4 p4[512];
  __shared__ unsigned short lst[256*48];
  int blk = blockIdx.x;
  int stripe = blk & 7;
  int chunk  = (blk >> 3) & 15;
  int b      = blk >> 7;
  const float* xb = x + b*3*Nn;
  int j0 = stripe*512;
  for (int u = threadIdx.x; u < 512; u += 256){
    int j = j0 + u;
    float a0 = xb[j];
    float a1 = xb[Nn + j];
    float a2 = xb[2*Nn + j];
    float s = a0*a0; s = s + a1*a1; s = s + a2*a2;
    p4[u] = make_float4(a0, a1, a2, s);
  }
  __syncthreads();
  int i = chunk*256 + threadIdx.x;
  float xi = xb[i], yi = xb[Nn+i], zi = xb[2*Nn+i];
  float ni = xi*xi; ni = ni + yi*yi; ni = ni + zi*zi;
  float mni = -ni;
  float xi2 = xi + xi, yi2 = yi + yi, zi2 = zi + zi;
  // ---- pass A: 32 group-maxes (groups of 16, fast nd) -> top-20 min/max network ----
  float tv[Kk];
  #pragma unroll
  for (int s=0;s<Kk;++s) tv[s] = -FLT_MAX;
  for (int g=0; g<32; ++g){
    float gm = -FLT_MAX;
    #pragma unroll
    for (int e=0;e<16;++e){
      float4 p = p4[g*16+e];
      float base = mni - p.w;
      float nd = fmaf(xi2, p.x, fmaf(yi2, p.y, fmaf(zi2, p.z, base)));
      gm = fmaxf(gm, nd);
    }
    #pragma unroll
    for (int s=Kk-1; s>=1; --s)
      tv[s] = fmaxf(tv[s], fminf(tv[s-1], gm));
    tv[0] = fmaxf(tv[0], gm);
  }
  float thr = tv[Kk-1];
  thr = thr - (fabsf(thr)*1e-4f + 1e-6f);   // margin >> fast-vs-exact fp discrepancy
  // ---- pass B: fast compare, collect indices (ascending u => stable) ----
  unsigned short* ml = &lst[threadIdx.x*48];
  int cnt = 0;
  for (int u=0; u<512; ++u){
    float4 p = p4[u];
    float base = mni - p.w;
    float nd = fmaf(xi2, p.x, fmaf(yi2, p.y, fmaf(zi2, p.z, base)));
    if (nd >= thr && cnt < 48){ ml[cnt] = (unsigned short)u; ++cnt; }
  }
  // ---- final: EXACT (val,idx) insertion sort ----
  float av[Kk]; int ai[Kk];
  #pragma unroll
  for (int s=0;s<Kk;++s){ av[s] = -FLT_MAX; ai[s] = 0; }
  if (cnt >= 48){
    // exact fallback: full branchy scan (rare; correctness guarantee)
    for (int u=0; u<512; ++u){
      float4 p = p4[u];
      float dot = xi*p.x; dot = dot + yi*p.y; dot = dot + zi*p.z;
      float inner = -2.0f*dot;
      float nd = mni - inner; nd = nd - p.w;
      if (nd > av[Kk-1]){
        #pragma unroll
        for (int s=Kk-1; s>=1; --s){
          bool cs = nd > av[s];
          bool cp = nd > av[s-1];
          av[s] = cs ? (cp ? av[s-1] : nd) : av[s];
          ai[s] = cs ? (cp ? ai[s-1] : (j0+u)) : ai[s];
        }
        if (nd > av[0]){ av[0] = nd; ai[0] = j0+u; }
      }
    }
  } else {
    for (int t=0; t<cnt; ++t){
      int lj = ml[t];
      float4 p = p4[lj];
      float dot = xi*p.x; dot = dot + yi*p.y; dot = dot + zi*p.z;
      float inner = -2.0f*dot;
      float nd = mni - inner; nd = nd - p.w;
      if (nd > av[Kk-1]){
        #pragma unroll
        for (int s=Kk-1; s>=1; --s){
          bool cs = nd > av[s];
          bool cp = nd > av[s-1];
          av[s] = cs ? (cp ? av[s-1] : nd) : av[s];
          ai[s] = cs ? (cp ? ai[s-1] : (j0+lj)) : ai[s];
        }
        if (nd > av[0]){ av[0] = nd; ai[0] = j0+lj; }
      }
    }
  }
  long long base = ((long long)(b*Nn + i)*8 + stripe)*Kk;
  #pragma unroll
  for (int s=0;s<Kk;++s){ pv[base+s] = av[s]; pi[base+s] = ai[s]; }
}

// ---------------- KNN phase B: merge 8 stripes ----------------
__global__ __launch_bounds__(256) void knnB_kernel(const float* __restrict__ pv,
                                                   const int* __restrict__ pi,
                                                   int* __restrict__ idx){
  int p = blockIdx.x*256 + threadIdx.x;
  if (p >= BN) return;
  long long base = (long long)p*8*Kk;
  float av[Kk]; int ai[Kk];
  #pragma unroll
  for (int s=0;s<Kk;++s){ av[s]=pv[base+s]; ai[s]=pi[base+s]; }
  for (int t=Kk; t<8*Kk; ++t){
    float nd = pv[base+t]; int j = pi[base+t];
    if (nd > av[Kk-1]){
      #pragma unroll
      for (int s=Kk-1;s>=1;--s){
        bool cs = nd > av[s];
        bool cp = nd > av[s-1];
        av[s] = cs ? (cp?av[s-1]:nd) : av[s];
        ai[s] = cs ? (cp?ai[s-1]:j) : ai[s];
      }
      if (nd > av[0]){ av[0]=nd; ai[0]=j; }
    }
  }
  #pragma unroll
  for (int s=0;s<Kk;++s) idx[(long long)p*Kk+s] = ai[s];
}

// ---------------- layer-1 feature stats ----------------
__global__ __launch_bounds__(256) void gramf_kernel(const float* __restrict__ x,
                                                    const int* __restrict__ idx,
                                                    float* __restrict__ part){
  float acc[36]; float s6[6];
  #pragma unroll
  for (int a=0;a<36;++a) acc[a]=0.f;
  #pragma unroll
  for (int a=0;a<6;++a) s6[a]=0.f;
  for (long long row = blockIdx.x*256 + threadIdx.x; row < Mrows; row += (long long)gridDim.x*256){
    int bn = (int)(row / Kk);
    int b = bn >> 12, n = bn & 4095;
    int j = idx[row];
    const float* xb = x + b*3*Nn;
    float f[6];
    f[0]=xb[j];  f[1]=xb[Nn+j];  f[2]=xb[2*Nn+j];
    f[3]=xb[n];  f[4]=xb[Nn+n];  f[5]=xb[2*Nn+n];
    #pragma unroll
    for (int a=0;a<6;++a){
      s6[a] += f[a];
      #pragma unroll
      for (int c=0;c<6;++c) acc[a*6+c] = fmaf(f[a], f[c], acc[a*6+c]);
    }
  }
  __shared__ float red[256];
  for (int v=0; v<42; ++v){
    red[threadIdx.x] = (v<36)? acc[v] : s6[v-36];
    __syncthreads();
    for (int s=128; s>0; s>>=1){
      if (threadIdx.x < s) red[threadIdx.x] += red[threadIdx.x+s];
      __syncthreads();
    }
    if (threadIdx.x==0) part[blockIdx.x*48 + v] = red[0];
    __syncthreads();
  }
}

__global__ void reducef_kernel(const float* __restrict__ part, float* __restrict__ Gf,
                               float* __restrict__ sumf){
  int t = threadIdx.x;
  if (t < 42){
    float s = 0.f;
    for (int i=0;i<256;++i) s += part[i*48 + t];
    if (t<36) Gf[t]=s; else sumf[t-36]=s;
  }
}

// ---------------- MFMA Gram: G = H^T H over bf16 H ----------------
template<int CIN>
__global__ __launch_bounds__(256) void gramM_kernel(const bf16* __restrict__ H, int M,
                                                    float* __restrict__ G){
  constexpr int Tt = CIN/64;
  int tile = blockIdx.x % (Tt*Tt);
  int chunk = blockIdx.x / (Tt*Tt);
  int nchunks = gridDim.x / (Tt*Tt);
  int tr = tile / Tt, tc = tile % Tt;
  bool diag = (tr == tc);
  __shared__ short HTa[64*68];
  __shared__ short HTb[64*68];
  int rpc = M / nchunks;
  int r0 = chunk*rpc;
  int tid = threadIdx.x, lane = tid & 63, w = tid >> 6;
  int mt = w >> 1, nt = w & 1;
  floatx16 acc;
  #pragma unroll
  for (int q=0;q<16;++q) acc[q]=0.f;
  const short* Bbase = diag ? HTa : HTb;
  int arow = (mt*32 + (lane&31))*68;
  int brow = (nt*32 + (lane&31))*68;
  int ko = (lane>>5)*8;
  for (int rb=r0; rb<r0+rpc; rb+=64){
    #pragma unroll
    for (int s=0;s<2;++s){
      int e = tid + s*256;
      int row = e >> 3, c0 = (e & 7)*8;
      U4b va; va.q = *(const uint4*)&H[(size_t)(rb+row)*CIN + tr*64 + c0];
      #pragma unroll
      for (int j=0;j<8;++j) HTa[(c0+j)*68 + row] = (short)va.s[j];
      if (!diag){
        U4b vb; vb.q = *(const uint4*)&H[(size_t)(rb+row)*CIN + tc*64 + c0];
        #pragma unroll
        for (int j=0;j<8;++j) HTb[(c0+j)*68 + row] = (short)vb.s[j];
      }
    }
    __syncthreads();
    #pragma unroll
    for (int kc=0;kc<64;kc+=16){
      Frag a, b;
      const short* ap = &HTa[arow + kc + ko];
      const short* bp = &Bbase[brow + kc + ko];
      a.u2[0] = *(const uint2*)ap;  a.u2[1] = *(const uint2*)(ap+4);
      b.u2[0] = *(const uint2*)bp;  b.u2[1] = *(const uint2*)(bp+4);
      acc = __builtin_amdgcn_mfma_f32_32x32x16_bf16(a.v, b.v, acc, 0, 0, 0);
    }
    __syncthreads();
  }
  int col = lane & 31, rbase = 4*(lane>>5);
  #pragma unroll
  for (int r=0;r<16;++r){
    int row = (r&3) + 8*(r>>2) + rbase;
    atomicAdd(&G[(size_t)(tr*64 + mt*32 + row)*CIN + tc*64 + nt*32 + col], acc[r]);
  }
}

// ---------------- column sums of H ----------------
template<int CIN, typename T>
__global__ __launch_bounds__(256) void colsum_kernel(const T* __restrict__ H, int M,
                                                     float* __restrict__ sumh){
  int rpb = (M + gridDim.x - 1)/gridDim.x;
  int r0 = blockIdx.x*rpb, r1 = min(M, r0+rpb);
  if constexpr (CIN <= 256){
    constexpr int RP = 256/CIN;
    int c = threadIdx.x % CIN;
    int sub = threadIdx.x / CIN;
    float a = 0.f;
    for (int r=r0+sub; r<r1; r+=RP) a += ldf(H[(size_t)r*CIN + c]);
    atomicAdd(&sumh[c], a);
  } else {
    float a0=0.f, a1=0.f;
    for (int r=r0;r<r1;++r){
      a0 += ldf(H[(size_t)r*CIN + threadIdx.x]);
      a1 += ldf(H[(size_t)r*CIN + threadIdx.x + 256]);
    }
    atomicAdd(&sumh[threadIdx.x], a0);
    atomicAdd(&sumh[threadIdx.x+256], a1);
  }
}

// ---------------- P = G @ W ----------------
__global__ void kP_kernel(const float* __restrict__ G, const float* __restrict__ Wf,
                          float* __restrict__ P, int Cin, int Cout){
  int id = blockIdx.x*256 + threadIdx.x;
  if (id >= Cin*Cout) return;
  int i = id / Cout, j = id - i*Cout;
  float s = 0.f;
  for (int k=0;k<Cin;++k) s = fmaf(G[(size_t)i*Cin+k], Wf[(size_t)k*Cout+j], s);
  P[id] = s;
}

// ---------------- scale/shift from Gram-derived BN stats ----------------
__global__ void kFinal_kernel(const float* __restrict__ P, const float* __restrict__ sumh,
                              const float* __restrict__ Wf, const float* __restrict__ g,
                              const float* __restrict__ bb, float* __restrict__ scale,
                              float* __restrict__ shift, int Cin, int Cout, float invM){
  int j = blockIdx.x*256 + threadIdx.x;
  if (j >= Cout) return;
  float mean=0.f, e2=0.f;
  for (int i=0;i<Cin;++i){
    float w = Wf[(size_t)i*Cout + j];
    mean = fmaf(sumh[i], w, mean);
    e2   = fmaf(w, P[(size_t)i*Cout + j], e2);
  }
  mean *= invM; e2 *= invM;
  float var = e2 - mean*mean;
  float inv = rsqrtf(var + EPSf);
  float sc = g[j]*inv;
  scale[j]=sc;
  shift[j]=bb[j] - mean*sc;
}

// ---------------- layer-2 stats ----------------
__global__ __launch_bounds__(512) void stats2_kernel(const float* __restrict__ x,
    const int* __restrict__ idx, const float* __restrict__ W1f,
    const float* __restrict__ sc1v, const float* __restrict__ sh1v,
    float* __restrict__ G2, float* __restrict__ sum2){
  __shared__ float W1s[6][64];
  __shared__ float fsh[64][8];
  __shared__ short H1T[64*68];
  __shared__ float csum[64];
  int tid = threadIdx.x, lane = tid & 63, w = tid >> 6;   // 8 waves
  if (tid < 384) W1s[tid>>6][tid&63] = W1f[tid];
  if (tid < 64) csum[tid] = 0.f;
  int rp = tid >> 4, cq = tid & 15, c0 = cq*4;
  float sca[4], sha[4];
  #pragma unroll
  for (int k=0;k<4;++k){ sca[k]=sc1v[c0+k]; sha[k]=sh1v[c0+k]; }
  int mt = w & 1, nt = (w>>1) & 1, kh = w >> 2;
  int arow = (mt*32 + (lane&31))*68;
  int brow = (nt*32 + (lane&31))*68;
  int ko = (lane>>5)*8;
  floatx16 acc;
  #pragma unroll
  for (int q=0;q<16;++q) acc[q]=0.f;
  float cs[4] = {0.f,0.f,0.f,0.f};
  int rpc = Mrows / gridDim.x;
  int r0 = blockIdx.x * rpc;
  __syncthreads();
  for (int rb=r0; rb<r0+rpc; rb+=64){
    {
      int r = tid>>3, e = tid&7;
      if (e < 6){
        int grow = rb + r;
        int bn = grow / Kk;
        int b = bn >> 12, n = bn & 4095;
        int j = idx[grow];
        const float* xb = x + b*3*Nn;
        fsh[r][e] = (e<3) ? xb[e*Nn + j] : xb[(e-3)*Nn + n];
      }
    }
    __syncthreads();
    {
      float y0[4]={0,0,0,0}, y1[4]={0,0,0,0};
      int ra = rp*2, rbw = rp*2+1;
      #pragma unroll
      for (int i=0;i<6;++i){
        float fa = fsh[ra][i], fb = fsh[rbw][i];
        float4 wv = *(const float4*)&W1s[i][c0];
        y0[0]=fmaf(fa,wv.x,y0[0]); y0[1]=fmaf(fa,wv.y,y0[1]);
        y0[2]=fmaf(fa,wv.z,y0[2]); y0[3]=fmaf(fa,wv.w,y0[3]);
        y1[0]=fmaf(fb,wv.x,y1[0]); y1[1]=fmaf(fb,wv.y,y1[1]);
        y1[2]=fmaf(fb,wv.z,y1[2]); y1[3]=fmaf(fb,wv.w,y1[3]);
      }
      #pragma unroll
      for (int k=0;k<4;++k){
        float va = fmaxf(fmaf(y0[k],sca[k],sha[k]),0.f);
        float vb = fmaxf(fmaf(y1[k],sca[k],sha[k]),0.f);
        cs[k] += va; cs[k] += vb;
        unsigned int pk = f2bu(va) | ((unsigned)f2bu(vb)<<16);
        *(unsigned int*)&H1T[(c0+k)*68 + ra] = pk;
      }
    }
    __syncthreads();
    {
      int kc = kh*32;
      #pragma unroll
      for (int s=0;s<2;++s){
        Frag a, b;
        const short* ap = &H1T[arow + kc + s*16 + ko];
        const short* bp = &H1T[brow + kc + s*16 + ko];
        a.u2[0] = *(const uint2*)ap;  a.u2[1] = *(const uint2*)(ap+4);
        b.u2[0] = *(const uint2*)bp;  b.u2[1] = *(const uint2*)(bp+4);
        acc = __builtin_amdgcn_mfma_f32_32x32x16_bf16(a.v, b.v, acc, 0, 0, 0);
      }
    }
    __syncthreads();
  }
  int col = lane & 31, rbase = 4*(lane>>5);
  #pragma unroll
  for (int r=0;r<16;++r){
    int row = (r&3) + 8*(r>>2) + rbase;
    atomicAdd(&G2[(size_t)(mt*32+row)*64 + nt*32+col], acc[r]);
  }
  #pragma unroll
  for (int k=0;k<4;++k) atomicAdd(&csum[c0+k], cs[k]);
  __syncthreads();
  if (tid < 64) atomicAdd(&sum2[tid], csum[tid]);
}

// ---------------- fused layers 1+2 ----------------
__global__ __launch_bounds__(64) void fl12_kernel(const float* __restrict__ x,
    const int* __restrict__ idx, const float* __restrict__ W1f,
    const float* __restrict__ sc1v, const float* __restrict__ sh1v,
    const float* __restrict__ W2f, const float* __restrict__ sc2v,
    const float* __restrict__ sh2v, bf16* __restrict__ H2, bf16* __restrict__ cat){
  __shared__ float fsh[Kk][6];
  __shared__ float h1[Kk][64];
  __shared__ float mm[4][64];
  int bn = blockIdx.x, b = bn>>12, n = bn & 4095;
  int tid = threadIdx.x;
  if (tid < Kk){
    int j = idx[(size_t)bn*Kk + tid];
    const float* xb = x + b*3*Nn;
    fsh[tid][0]=xb[j]; fsh[tid][1]=xb[Nn+j]; fsh[tid][2]=xb[2*Nn+j];
    fsh[tid][3]=xb[n]; fsh[tid][4]=xb[Nn+n]; fsh[tid][5]=xb[2*Nn+n];
  }
  __syncthreads();
  {
    float sc=sc1v[tid], sh=sh1v[tid];
    float w[6];
    #pragma unroll
    for (int i=0;i<6;++i) w[i]=W1f[i*64+tid];
    float mx = 0.f;
    #pragma unroll
    for (int r=0;r<Kk;++r){
      float y=0.f;
      #pragma unroll
      for (int i=0;i<6;++i) y = fmaf(fsh[r][i], w[i], y);
      float v = fmaxf(fmaf(y,sc,sh),0.f);
      h1[r][tid]=v;
      mx = fmaxf(mx,v);
    }
    cat[(size_t)bn*512 + tid] = f2b(mx);
  }
  __syncthreads();
  int q = tid >> 4, c0 = (tid & 15)*4;
  float acc[5][4]={};
  for (int i0=0;i0<64;i0+=4){
    float hv[5][4];
    #pragma unroll
    for (int l=0;l<5;++l){
      float4 t4 = *(const float4*)&h1[q*5+l][i0];
      hv[l][0]=t4.x; hv[l][1]=t4.y; hv[l][2]=t4.z; hv[l][3]=t4.w;
    }
    #pragma unroll
    for (int ii=0;ii<4;++ii){
      const float* wp = W2f + (i0+ii)*64 + c0;
      float w0=wp[0],w1=wp[1],w2=wp[2],w3=wp[3];
      #pragma unroll
      for (int l=0;l<5;++l){
        float hvv=hv[l][ii];
        acc[l][0]=fmaf(hvv,w0,acc[l][0]);
        acc[l][1]=fmaf(hvv,w1,acc[l][1]);
        acc[l][2]=fmaf(hvv,w2,acc[l][2]);
        acc[l][3]=fmaf(hvv,w3,acc[l][3]);
      }
    }
  }
  float sc[4],sh[4];
  #pragma unroll
  for (int cb=0;cb<4;++cb){ sc[cb]=sc2v[c0+cb]; sh[cb]=sh2v[c0+cb]; }
  float mx[4]={0,0,0,0};
  #pragma unroll
  for (int l=0;l<5;++l){
    unsigned short us[4];
    #pragma unroll
    for (int cb=0;cb<4;++cb){
      float v=fmaxf(fmaf(acc[l][cb],sc[cb],sh[cb]),0.f);
      mx[cb]=fmaxf(mx[cb],v);
      us[cb]=f2bu(v);
    }
    uint2 v2; v2.x = us[0]|((unsigned)us[1]<<16); v2.y=us[2]|((unsigned)us[3]<<16);
    *(uint2*)(H2 + ((size_t)bn*Kk + q*5+l)*64 + c0) = v2;
  }
  #pragma unroll
  for (int cb=0;cb<4;++cb) mm[q][c0+cb]=mx[cb];
  __syncthreads();
  {
    float M0 = fmaxf(fmaxf(mm[0][tid],mm[1][tid]),fmaxf(mm[2][tid],mm[3][tid]));
    cat[(size_t)bn*512 + 64 + tid] = f2b(M0);
  }
}

// ---------------- layer-4 stats: MFMA produce + MFMA Gram ----------------
__global__ __launch_bounds__(512) void stats4_kernel(const bf16* __restrict__ H2,
    const bf16* __restrict__ W3T, const float* __restrict__ sc3v, const float* __restrict__ sh3v,
    float* __restrict__ G4, float* __restrict__ sum4){
  __shared__ short h2s[64*68];
  __shared__ short H3T[128*68];
  __shared__ float csum[128];
  int tid = threadIdx.x, lane = tid & 63, w = tid >> 6;   // 8 waves
  if (tid < 128) csum[tid] = 0.f;
  int trow = tid >> 3, tc0 = (tid & 7)*8;
  int pl  = lane & 31;
  int ko  = (lane >> 5)*8;
  int pmt = w >> 2, pnt = w & 3;
  int parow = (pmt*32 + pl)*68;
  int pcol  = pnt*32 + pl;
  float psc = sc3v[pcol], psh = sh3v[pcol];
  int prbase = 4*(lane>>5);
  FragQ bfr[4];
  #pragma unroll
  for (int kq=0;kq<4;++kq)
    bfr[kq].q = *(const uint4*)&W3T[(size_t)pcol*64 + kq*16 + ko];
  int gmt = w>>1, gnt0 = (w&1)*2, gnt1 = gnt0+1;
  int garow  = (gmt*32 + pl)*68;
  int gbrow0 = (gnt0*32 + pl)*68;
  int gbrow1 = (gnt1*32 + pl)*68;
  floatx16 acc0, acc1;
  #pragma unroll
  for (int q=0;q<16;++q){ acc0[q]=0.f; acc1[q]=0.f; }
  float cs = 0.f;
  int rpc = Mrows / gridDim.x;
  int r0 = blockIdx.x * rpc;
  uint4 hreg = *(const uint4*)&H2[(size_t)(r0+trow)*64 + tc0];
  for (int rb=r0; rb<r0+rpc; rb+=64){
    {
      short* dst = &h2s[trow*68 + tc0];
      *(uint2*)dst       = make_uint2(hreg.x, hreg.y);
      *(uint2*)(dst + 4) = make_uint2(hreg.z, hreg.w);
    }
    if (rb + 64 < r0 + rpc)
      hreg = *(const uint4*)&H2[(size_t)(rb+64+trow)*64 + tc0];
    __syncthreads();
    {
      floatx16 pacc;
      #pragma unroll
      for (int q=0;q<16;++q) pacc[q]=0.f;
      #pragma unroll
      for (int kq=0;kq<4;++kq){
        Frag a;
        const short* ap = &h2s[parow + kq*16 + ko];
        a.u2[0] = *(const uint2*)ap;  a.u2[1] = *(const uint2*)(ap+4);
        pacc = __builtin_amdgcn_mfma_f32_32x32x16_bf16(a.v, bfr[kq].v, pacc, 0, 0, 0);
      }
      #pragma unroll
      for (int g=0; g<4; ++g){
        unsigned short p[4];
        #pragma unroll
        for (int r=0;r<4;++r){
          float v = fmaxf(fmaf(pacc[g*4+r], psc, psh), 0.f);
          cs += v;
          p[r] = f2bu(v);
        }
        uint2 pk; pk.x = p[0] | ((unsigned)p[1]<<16); pk.y = p[2] | ((unsigned)p[3]<<16);
        *(uint2*)&H3T[pcol*68 + pmt*32 + 8*g + prbase] = pk;
      }
    }
    __syncthreads();
    #pragma unroll
    for (int kc=0;kc<64;kc+=16){
      Frag a, b0, b1;
      const short* ap  = &H3T[garow  + kc + ko];
      const short* bp0 = &H3T[gbrow0 + kc + ko];
      const short* bp1 = &H3T[gbrow1 + kc + ko];
      a.u2[0]  = *(const uint2*)ap;   a.u2[1]  = *(const uint2*)(ap+4);
      b0.u2[0] = *(const uint2*)bp0;  b0.u2[1] = *(const uint2*)(bp0+4);
      b1.u2[0] = *(const uint2*)bp1;  b1.u2[1] = *(const uint2*)(bp1+4);
      acc0 = __builtin_amdgcn_mfma_f32_32x32x16_bf16(a.v, b0.v, acc0, 0, 0, 0);
      acc1 = __builtin_amdgcn_mfma_f32_32x32x16_bf16(a.v, b1.v, acc1, 0, 0, 0);
    }
  }
  int col = pl;
  #pragma unroll
  for (int r=0;r<16;++r){
    int row = (r&3) + 8*(r>>2) + prbase;
    atomicAdd(&G4[(size_t)(gmt*32+row)*128 + gnt0*32+col], acc0[r]);
    atomicAdd(&G4[(size_t)(gmt*32+row)*128 + gnt1*32+col], acc1[r]);
  }
  atomicAdd(&csum[pcol], cs);
  __syncthreads();
  if (tid < 128) atomicAdd(&sum4[tid], csum[tid]);
}

// ---------------- fused layers 3+4: MFMA produce chain + col-owner maxpool ----------------
__global__ __launch_bounds__(512,4) void fl34_kernel(const bf16* __restrict__ H2,
    const bf16* __restrict__ W3T, const float* __restrict__ sc3v, const float* __restrict__ sh3v,
    const bf16* __restrict__ W4T, const float* __restrict__ sc4v, const float* __restrict__ sh4v,
    bf16* __restrict__ cat){
  __shared__ short h2s[64*68];             // 8.5 KB
  __shared__ short h3s[64*132];            // 16.5 KB
  __shared__ unsigned short h4s[64*256];   // 32 KB
  __shared__ unsigned short mx3u[16*128];  // 4 KB
  __shared__ unsigned short mx4u[16*256];  // 8 KB
  int tid = threadIdx.x, lane = tid & 63, w = tid >> 6;
  int pl = lane & 31;
  int ko = (lane >> 5)*8;
  int rbase = 4*(lane>>5);
  {
    unsigned* p4 = (unsigned*)mx4u;
    for (int u=tid; u<2048; u+=512) p4[u]=0u;
    unsigned* p3 = (unsigned*)mx3u;
    for (int u=tid; u<1024; u+=512) p3[u]=0u;
  }
  int mt3 = w >> 2, ct3 = w & 3;
  int c3 = ct3*32 + pl;
  float sc3 = sc3v[c3], sh3 = sh3v[c3];
  int a3row = (mt3*32 + pl)*68;
  int c4 = w*32 + pl;
  float sc4 = sc4v[c4], sh4 = sh4v[c4];
  int trow = tid >> 3, tc0 = (tid & 7)*8;
  int r0 = blockIdx.x * 320;
  uint4 hreg = *(const uint4*)&H2[(size_t)(r0+trow)*64 + tc0];
  {
    short* dst = &h2s[trow*68 + tc0];
    *(uint2*)dst       = make_uint2(hreg.x, hreg.y);
    *(uint2*)(dst + 4) = make_uint2(hreg.z, hreg.w);
  }
  hreg = *(const uint4*)&H2[(size_t)(r0 + 64 + trow)*64 + tc0];
  __syncthreads();
  for (int t=0; t<5; ++t){
    {
      floatx16 pa;
      #pragma unroll
      for (int q=0;q<16;++q) pa[q]=0.f;
      #pragma unroll
      for (int kq=0;kq<4;++kq){
        Frag a; FragQ b;
        const short* ap = &h2s[a3row + kq*16 + ko];
        a.u2[0] = *(const uint2*)ap;  a.u2[1] = *(const uint2*)(ap+4);
        b.q = *(const uint4*)&W3T[(size_t)c3*64 + kq*16 + ko];
        pa = __builtin_amdgcn_mfma_f32_32x32x16_bf16(a.v, b.v, pa, 0, 0, 0);
      }
      #pragma unroll
      for (int r=0;r<16;++r){
        int m = mt3*32 + (r&3) + 8*(r>>2) + rbase;
        float v = fmaxf(fmaf(pa[r], sc3, sh3), 0.f);
        h3s[m*132 + c3] = (short)f2bu(v);
      }
    }
    __syncthreads();
    #pragma unroll
    for (int mt4=0; mt4<2; ++mt4){
      floatx16 acc;
      #pragma unroll
      for (int q=0;q<16;++q) acc[q]=0.f;
      int a4row = (mt4*32 + pl)*132;
      #pragma unroll
      for (int kq=0;kq<8;++kq){
        Frag a; FragQ b;
        const short* ap = &h3s[a4row + kq*16 + ko];
        a.u2[0] = *(const uint2*)ap;  a.u2[1] = *(const uint2*)(ap+4);
        b.q = *(const uint4*)&W4T[(size_t)c4*128 + kq*16 + ko];
        acc = __builtin_amdgcn_mfma_f32_32x32x16_bf16(a.v, b.v, acc, 0, 0, 0);
      }
      #pragma unroll
      for (int r=0;r<16;++r){
        int m = mt4*32 + (r&3) + 8*(r>>2) + rbase;
        float v = fmaxf(fmaf(acc[r], sc4, sh4), 0.f);
        h4s[m*256 + c4] = f2bu(v);
      }
    }
    __syncthreads();
    if (t < 4){
      short* dst = &h2s[trow*68 + tc0];
      *(uint2*)dst       = make_uint2(hreg.x, hreg.y);
      *(uint2*)(dst + 4) = make_uint2(hreg.z, hreg.w);
      if (t < 3) hreg = *(const uint4*)&H2[(size_t)(r0 + (t+2)*64 + trow)*64 + tc0];
    }
    {
      int lr0 = t*64;
      if (tid < 256){
        int c = tid;
        int p = lr0/20;
        int nb = (p+1)*20 - lr0;
        unsigned ml = 0;
        for (int r=0;r<64;++r){
          unsigned v = h4s[r*256 + c];
          ml = v > ml ? v : ml;
          if (--nb == 0){
            unsigned short* mp = &mx4u[p*256 + c];
            unsigned cur = *mp;
            if (ml > cur) *mp = (unsigned short)ml;
            ml = 0; ++p; nb = 20;
          }
        }
        if (nb != 20){
          unsigned short* mp = &mx4u[p*256 + c];
          unsigned cur = *mp;
          if (ml > cur) *mp = (unsigned short)ml;
        }
      } else if (tid < 384){
        int c = tid - 256;
        int p = lr0/20;
        int nb = (p+1)*20 - lr0;
        unsigned ml = 0;
        for (int r=0;r<64;++r){
          unsigned v = (unsigned)(unsigned short)h3s[r*132 + c];
          ml = v > ml ? v : ml;
          if (--nb == 0){
            unsigned short* mp = &mx3u[p*128 + c];
            unsigned cur = *mp;
            if (ml > cur) *mp = (unsigned short)ml;
            ml = 0; ++p; nb = 20;
          }
        }
        if (nb != 20){
          unsigned short* mp = &mx3u[p*128 + c];
          unsigned cur = *mp;
          if (ml > cur) *mp = (unsigned short)ml;
        }
      }
    }
    __syncthreads();
  }
  int bn0 = blockIdx.x*16;
  {
    int p = tid >> 5, c0 = (tid & 31)*8;
    uint4 v = *(const uint4*)&mx4u[p*256 + c0];
    *(uint4*)&cat[(size_t)(bn0+p)*512 + 256 + c0] = v;
  }
  if (tid < 256){
    int p = tid >> 4, c0 = (tid & 15)*8;
    uint4 v = *(const uint4*)&mx3u[p*128 + c0];
    *(uint4*)&cat[(size_t)(bn0+p)*512 + 128 + c0] = v;
  }
}

// ---------------- layer 5 v3: MFMA GEMM + LDS-staged coalesced epilogue ----------------
// K-loop unchanged. Epilogue: per s-chunk (128 cols x 64 rows) stage bn+relu results
// to ob[64][129] (pad => 2-way-free reads), then 4 threads/col write 64B contiguous
// each => full 64B-line writes (was 16B scattered stores at ~25% write efficiency).
__global__ __launch_bounds__(512) void l5_kernel(const bf16* __restrict__ cat,
                                                const bf16* __restrict__ W5T,
                                                const float* __restrict__ scale,
                                                const float* __restrict__ shift,
                                                float* __restrict__ out){
  __shared__ short cs[64*68];
  __shared__ float ob[64*129];
  int tid = threadIdx.x, lane = tid & 63, w = tid >> 6;
  int pl = lane & 31;
  int ko = (lane >> 5)*8;
  int rbase = 4*(lane>>5);
  int mt = w & 1, ntb = w >> 1;          // nt = ntb + 4*s, s=0..3
  int arow = (mt*32 + pl)*68;
  int trow = tid >> 3, tc0 = (tid & 7)*8;
  int r0 = blockIdx.x*64;
  floatx16 acc[4];
  #pragma unroll
  for (int s=0;s<4;++s)
    #pragma unroll
    for (int q=0;q<16;++q) acc[s][q]=0.f;
  const bf16* arow_g = cat + (size_t)(r0+trow)*512 + tc0;
  uint4 hreg = *(const uint4*)arow_g;
  for (int kc8=0; kc8<8; ++kc8){
    {
      short* dst = &cs[trow*68 + tc0];
      *(uint2*)dst       = make_uint2(hreg.x, hreg.y);
      *(uint2*)(dst + 4) = make_uint2(hreg.z, hreg.w);
    }
    if (kc8 < 7) hreg = *(const uint4*)(arow_g + (kc8+1)*64);
    __syncthreads();
    #pragma unroll
    for (int kq=0;kq<4;++kq){
      Frag a;
      const short* ap = &cs[arow + kq*16 + ko];
      a.u2[0] = *(const uint2*)ap;  a.u2[1] = *(const uint2*)(ap+4);
      #pragma unroll
      for (int s=0;s<4;++s){
        FragQ b;
        int col = (ntb + 4*s)*32 + pl;
        b.q = *(const uint4*)&W5T[(size_t)col*512 + kc8*64 + kq*16 + ko];
        acc[s] = __builtin_amdgcn_mfma_f32_32x32x16_bf16(a.v, b.v, acc[s], 0, 0, 0);
      }
    }
    __syncthreads();
  }
  int b = r0 >> 12, n0 = r0 & 4095;
  int colL = ntb*32 + pl;                // 0..127 within chunk
  int colc = tid >> 2, sub = tid & 3;    // writer mapping: 4 threads per col
  for (int s=0;s<4;++s){
    float sc = scale[128*s + colL], sh = shift[128*s + colL];
    #pragma unroll
    for (int q=0;q<16;++q){
      int m = mt*32 + (q&3) + 8*(q>>2) + rbase;
      ob[m*129 + colL] = fmaxf(fmaf(acc[s][q], sc, sh), 0.f);
    }
    __syncthreads();
    float* op = out + ((size_t)b*512 + 128*s + colc)*4096 + n0 + sub*16;
    #pragma unroll
    for (int j=0;j<4;++j){
      int rr = sub*16 + j*4;
      float4 v = make_float4(ob[(rr+0)*129 + colc], ob[(rr+1)*129 + colc],
                             ob[(rr+2)*129 + colc], ob[(rr+3)*129 + colc]);
      *(float4*)(op + j*4) = v;
    }
    __syncthreads();
  }
}

extern "C" void kernel_launch(void* const* d_in, const int* in_sizes, int n_in,
                              void* d_out, int out_size, void* d_ws, size_t ws_size,
                              hipStream_t stream){
  const float* x   = (const float*)d_in[0];
  const float* W1f = (const float*)d_in[1];
  const float* W2f = (const float*)d_in[2];
  const float* W3f = (const float*)d_in[3];
  const float* W4f = (const float*)d_in[4];
  const float* W5f = (const float*)d_in[5];
  const float* g1=(const float*)d_in[6],  *b1=(const float*)d_in[7];
  const float* g2=(const float*)d_in[8],  *b2=(const float*)d_in[9];
  const float* g3=(const float*)d_in[10], *b3=(const float*)d_in[11];
  const float* g4=(const float*)d_in[12], *b4=(const float*)d_in[13];
  const float* g5=(const float*)d_in[14], *b5=(const float*)d_in[15];
  float* out = (float*)d_out;

  char* w = (char*)d_ws;
  size_t off = 0;
  auto alloc = [&](size_t bytes)->void*{
    void* p = w + off;
    off = (off + bytes + 255) & ~(size_t)255;
    return p;
  };

  int*  idxb = (int*) alloc((size_t)BN*Kk*4);
  bf16* H2   = (bf16*)alloc((size_t)Mrows*64*2);
  bf16* catb = (bf16*)alloc((size_t)BN*512*2);
  bf16* W3T  = (bf16*)alloc((size_t)128*64*2);
  bf16* W4T  = (bf16*)alloc((size_t)256*128*2);
  bf16* W5T  = (bf16*)alloc((size_t)512*512*2);
  float* pv  = (float*)H2;
  int*   pib = (int*)((char*)H2 + (size_t)BN*8*Kk*4);

  size_t statsStart = off;
  float* partf=(float*)alloc(256*48*4);
  float* Gf=(float*)alloc(36*4);
  float* sumf=(float*)alloc(8*4);
  float* G2=(float*)alloc(4096*4);   float* sum2=(float*)alloc(64*4);
  float* G3=(float*)alloc(4096*4);   float* sum3=(float*)alloc(64*4);
  float* G4=(float*)alloc(16384*4);  float* sum4=(float*)alloc(128*4);
  float* G5=(float*)alloc(262144*4); float* sum5=(float*)alloc(512*4);
  float* P1=(float*)alloc(384*4);
  float* P2=(float*)alloc(4096*4);
  float* P3=(float*)alloc(8192*4);
  float* P4=(float*)alloc(32768*4);
  float* P5=(float*)alloc(262144*4);
  float* sc1=(float*)alloc(64*4);   float* sh1=(float*)alloc(64*4);
  float* sc2=(float*)alloc(64*4);   float* sh2=(float*)alloc(64*4);
  float* sc3=(float*)alloc(128*4);  float* sh3=(float*)alloc(128*4);
  float* sc4=(float*)alloc(256*4);  float* sh4=(float*)alloc(256*4);
  float* sc5=(float*)alloc(512*4);  float* sh5=(float*)alloc(512*4);
  size_t statsEnd = off;

  int statsFloats = (int)((statsEnd - statsStart)/4);
  zero_kernel<<<(statsFloats+255)/256,256,0,stream>>>((float*)(w+statsStart), statsFloats);
  w3t_kernel<<<32,256,0,stream>>>(W3f, W3T);
  w4t_kernel<<<128,256,0,stream>>>(W4f, W4T);
  w5t_kernel<<<1024,256,0,stream>>>(W5f, W5T);

  knnA_kernel<<<1024,256,0,stream>>>(x, pv, pib);
  knnB_kernel<<<BN/256,256,0,stream>>>(pv, pib, idxb);

  const float invM  = 1.0f/(float)Mrows;
  const float invM5 = 1.0f/(float)BN;

  gramf_kernel<<<256,256,0,stream>>>(x, idxb, partf);
  reducef_kernel<<<1,64,0,stream>>>(partf, Gf, sumf);
  kP_kernel<<<2,256,0,stream>>>(Gf, W1f, P1, 6, 64);
  kFinal_kernel<<<1,256,0,stream>>>(P1, sumf, W1f, g1, b1, sc1, sh1, 6, 64, invM);

  stats2_kernel<<<512,512,0,stream>>>(x, idxb, W1f, sc1, sh1, G2, sum2);
  kP_kernel<<<16,256,0,stream>>>(G2, W2f, P2, 64, 64);
  kFinal_kernel<<<1,256,0,stream>>>(P2, sum2, W2f, g2, b2, sc2, sh2, 64, 64, invM);

  fl12_kernel<<<BN,64,0,stream>>>(x, idxb, W1f, sc1, sh1, W2f, sc2, sh2, H2, catb);

  colsum_kernel<64,bf16><<<512,256,0,stream>>>(H2, Mrows, sum3);
  gramM_kernel<64><<<512,256,0,stream>>>(H2, Mrows, G3);
  kP_kernel<<<32,256,0,stream>>>(G3, W3f, P3, 64, 128);
  kFinal_kernel<<<1,256,0,stream>>>(P3, sum3, W3f, g3, b3, sc3, sh3, 64, 128, invM);

  stats4_kernel<<<512,512,0,stream>>>(H2, W3T, sc3, sh3, G4, sum4);
  kP_kernel<<<128,256,0,stream>>>(G4, W4f, P4, 128, 256);
  kFinal_kernel<<<1,256,0,stream>>>(P4, sum4, W4f, g4, b4, sc4, sh4, 128, 256, invM);

  fl34_kernel<<<Mrows/320,512,0,stream>>>(H2, W3T, sc3, sh3, W4T, sc4, sh4, catb);

  colsum_kernel<512,bf16><<<512,256,0,stream>>>(catb, BN, sum5);
  gramM_kernel<512><<<512,256,0,stream>>>(catb, BN, G5);
  kP_kernel<<<1024,256,0,stream>>>(G5, W5f, P5, 512, 512);
  kFinal_kernel<<<2,256,0,stream>>>(P5, sum5, W5f, g5, b5, sc5, sh5, 512, 512, invM5);
  l5_kernel<<<BN/64,512,0,stream>>>(catb, W5T, sc5, sh5, out);
}

// Round 8
// 1447.530 us; speedup vs baseline: 1.0761x; 1.0761x over previous
//
#include <hip/hip_runtime.h>
#include <hip/hip_bf16.h>
#include <cfloat>

using bf16 = __hip_bfloat16;

typedef short short8 __attribute__((ext_vector_type(8)));
typedef float floatx16 __attribute__((ext_vector_type(16)));
union Frag { short8 v; uint2 u2[2]; };
union FragQ { short8 v; uint4 q; uint2 u2[2]; };
union U4b { uint4 q; unsigned short s[8]; };

constexpr int Bb = 8, Nn = 4096, Kk = 20;
constexpr int BN = Bb * Nn;                     // 32768
constexpr int Mrows = BN * Kk;                  // 655360
constexpr float EPSf = 1e-5f;

static __device__ __forceinline__ float b2f(bf16 v){ return __bfloat162float(v); }
static __device__ __forceinline__ bf16 f2b(float v){ return __float2bfloat16(v); }
static __device__ __forceinline__ unsigned short f2bu(float v){
  union { bf16 b; unsigned short u; } cv; cv.b = __float2bfloat16(v); return cv.u;
}
static __device__ __forceinline__ float bits2f(unsigned short u){
  union { unsigned int i; float f; } c; c.i = ((unsigned)u)<<16; return c.f;
}
static __device__ __forceinline__ float ldf(bf16 v){ return b2f(v); }
static __device__ __forceinline__ float ldf(float v){ return v; }

// ---------------- zero workspace region ----------------
__global__ void zero_kernel(float* __restrict__ p, int n){
  int i = blockIdx.x*256 + threadIdx.x;
  if (i < n) p[i] = 0.f;
}

// ---------------- W3^T bf16 pack ----------------
__global__ void w3t_kernel(const float* __restrict__ W3f, bf16* __restrict__ W3T){
  int id = blockIdx.x*256 + threadIdx.x;   // 128*64 = 8192 elems
  if (id >= 128*64) return;
  int n = id >> 6, k = id & 63;
  W3T[id] = f2b(W3f[(size_t)k*128 + n]);
}

// ---------------- W4^T bf16 pack ----------------
__global__ void w4t_kernel(const float* __restrict__ W4f, bf16* __restrict__ W4T){
  int id = blockIdx.x*256 + threadIdx.x;   // 128*256 = 32768 elems
  if (id >= 128*256) return;
  int k = id >> 8, c = id & 255;           // coalesced read of W4f
  W4T[(size_t)c*128 + k] = f2b(W4f[id]);
}

// ---------------- W5^T bf16 pack ----------------
__global__ void w5t_kernel(const float* __restrict__ W5f, bf16* __restrict__ W5T){
  int id = blockIdx.x*256 + threadIdx.x;   // 512*512 = 262144 elems
  if (id >= 512*512) return;
  int k = id >> 9, c = id & 511;           // coalesced read of W5f
  W5T[(size_t)c*512 + k] = f2b(W5f[id]);
}

// ---------------- KNN phase A v5: v4 + CAP=64 / margin 1e-5 (fallback-tail fix) ----
// v4 regression root cause: groups-of-16 raised E[admits] to ~31 (sigma 5.4); CAP=48
// was only 3.2 sigma => ~4% of waves took the 512-iter exact fallback, creating
// low-occupancy serial tails (VALUBusy 91->45%). CAP=64 is 6.2 sigma (P~3e-10) and
// margin 1e-5 (still >> few-ulp fast-vs-exact discrepancy) trims excess admits.
__global__ __launch_bounds__(256) void knnA_kernel(const float* __restrict__ x,
                                                   float* __restrict__ pv, int* __restrict__ pi){
#pragma clang fp contract(off)
  __shared__ float4 p4[512];
  __shared__ unsigned short lst[256*64];
  int blk = blockIdx.x;
  int stripe = blk & 7;
  int chunk  = (blk >> 3) & 15;
  int b      = blk >> 7;
  const float* xb = x + b*3*Nn;
  int j0 = stripe*512;
  for (int u = threadIdx.x; u < 512; u += 256){
    int j = j0 + u;
    float a0 = xb[j];
    float a1 = xb[Nn + j];
    float a2 = xb[2*Nn + j];
    float s = a0*a0; s = s + a1*a1; s = s + a2*a2;
    p4[u] = make_float4(a0, a1, a2, s);
  }
  __syncthreads();
  int i = chunk*256 + threadIdx.x;
  float xi = xb[i], yi = xb[Nn+i], zi = xb[2*Nn+i];
  float ni = xi*xi; ni = ni + yi*yi; ni = ni + zi*zi;
  float mni = -ni;
  float xi2 = xi + xi, yi2 = yi + yi, zi2 = zi + zi;
  // ---- pass A: 32 group-maxes (groups of 16, fast nd) -> top-20 min/max network ----
  float tv[Kk];
  #pragma unroll
  for (int s=0;s<Kk;++s) tv[s] = -FLT_MAX;
  for (int g=0; g<32; ++g){
    float gm = -FLT_MAX;
    #pragma unroll
    for (int e=0;e<16;++e){
      float4 p = p4[g*16+e];
      float base = mni - p.w;
      float nd = fmaf(xi2, p.x, fmaf(yi2, p.y, fmaf(zi2, p.z, base)));
      gm = fmaxf(gm, nd);
    }
    #pragma unroll
    for (int s=Kk-1; s>=1; --s)
      tv[s] = fmaxf(tv[s], fminf(tv[s-1], gm));
    tv[0] = fmaxf(tv[0], gm);
  }
  float thr = tv[Kk-1];
  thr = thr - (fabsf(thr)*1e-5f + 1e-6f);   // margin >> fast-vs-exact fp discrepancy
  // ---- pass B: fast compare, collect indices (ascending u => stable) ----
  unsigned short* ml = &lst[threadIdx.x*64];
  int cnt = 0;
  for (int u=0; u<512; ++u){
    float4 p = p4[u];
    float base = mni - p.w;
    float nd = fmaf(xi2, p.x, fmaf(yi2, p.y, fmaf(zi2, p.z, base)));
    if (nd >= thr && cnt < 64){ ml[cnt] = (unsigned short)u; ++cnt; }
  }
  // ---- final: EXACT (val,idx) insertion sort ----
  float av[Kk]; int ai[Kk];
  #pragma unroll
  for (int s=0;s<Kk;++s){ av[s] = -FLT_MAX; ai[s] = 0; }
  if (cnt >= 64){
    // exact fallback: full branchy scan (statistically never; correctness guarantee)
    for (int u=0; u<512; ++u){
      float4 p = p4[u];
      float dot = xi*p.x; dot = dot + yi*p.y; dot = dot + zi*p.z;
      float inner = -2.0f*dot;
      float nd = mni - inner; nd = nd - p.w;
      if (nd > av[Kk-1]){
        #pragma unroll
        for (int s=Kk-1; s>=1; --s){
          bool cs = nd > av[s];
          bool cp = nd > av[s-1];
          av[s] = cs ? (cp ? av[s-1] : nd) : av[s];
          ai[s] = cs ? (cp ? ai[s-1] : (j0+u)) : ai[s];
        }
        if (nd > av[0]){ av[0] = nd; ai[0] = j0+u; }
      }
    }
  } else {
    for (int t=0; t<cnt; ++t){
      int lj = ml[t];
      float4 p = p4[lj];
      float dot = xi*p.x; dot = dot + yi*p.y; dot = dot + zi*p.z;
      float inner = -2.0f*dot;
      float nd = mni - inner; nd = nd - p.w;
      if (nd > av[Kk-1]){
        #pragma unroll
        for (int s=Kk-1; s>=1; --s){
          bool cs = nd > av[s];
          bool cp = nd > av[s-1];
          av[s] = cs ? (cp ? av[s-1] : nd) : av[s];
          ai[s] = cs ? (cp ? ai[s-1] : (j0+lj)) : ai[s];
        }
        if (nd > av[0]){ av[0] = nd; ai[0] = j0+lj; }
      }
    }
  }
  long long base = ((long long)(b*Nn + i)*8 + stripe)*Kk;
  #pragma unroll
  for (int s=0;s<Kk;++s){ pv[base+s] = av[s]; pi[base+s] = ai[s]; }
}

// ---------------- KNN phase B: merge 8 stripes ----------------
__global__ __launch_bounds__(256) void knnB_kernel(const float* __restrict__ pv,
                                                   const int* __restrict__ pi,
                                                   int* __restrict__ idx){
  int p = blockIdx.x*256 + threadIdx.x;
  if (p >= BN) return;
  long long base = (long long)p*8*Kk;
  float av[Kk]; int ai[Kk];
  #pragma unroll
  for (int s=0;s<Kk;++s){ av[s]=pv[base+s]; ai[s]=pi[base+s]; }
  for (int t=Kk; t<8*Kk; ++t){
    float nd = pv[base+t]; int j = pi[base+t];
    if (nd > av[Kk-1]){
      #pragma unroll
      for (int s=Kk-1;s>=1;--s){
        bool cs = nd > av[s];
        bool cp = nd > av[s-1];
        av[s] = cs ? (cp?av[s-1]:nd) : av[s];
        ai[s] = cs ? (cp?ai[s-1]:j) : ai[s];
      }
      if (nd > av[0]){ av[0]=nd; ai[0]=j; }
    }
  }
  #pragma unroll
  for (int s=0;s<Kk;++s) idx[(long long)p*Kk+s] = ai[s];
}

// ---------------- layer-1 feature stats ----------------
__global__ __launch_bounds__(256) void gramf_kernel(const float* __restrict__ x,
                                                    const int* __restrict__ idx,
                                                    float* __restrict__ part){
  float acc[36]; float s6[6];
  #pragma unroll
  for (int a=0;a<36;++a) acc[a]=0.f;
  #pragma unroll
  for (int a=0;a<6;++a) s6[a]=0.f;
  for (long long row = blockIdx.x*256 + threadIdx.x; row < Mrows; row += (long long)gridDim.x*256){
    int bn = (int)(row / Kk);
    int b = bn >> 12, n = bn & 4095;
    int j = idx[row];
    const float* xb = x + b*3*Nn;
    float f[6];
    f[0]=xb[j];  f[1]=xb[Nn+j];  f[2]=xb[2*Nn+j];
    f[3]=xb[n];  f[4]=xb[Nn+n];  f[5]=xb[2*Nn+n];
    #pragma unroll
    for (int a=0;a<6;++a){
      s6[a] += f[a];
      #pragma unroll
      for (int c=0;c<6;++c) acc[a*6+c] = fmaf(f[a], f[c], acc[a*6+c]);
    }
  }
  __shared__ float red[256];
  for (int v=0; v<42; ++v){
    red[threadIdx.x] = (v<36)? acc[v] : s6[v-36];
    __syncthreads();
    for (int s=128; s>0; s>>=1){
      if (threadIdx.x < s) red[threadIdx.x] += red[threadIdx.x+s];
      __syncthreads();
    }
    if (threadIdx.x==0) part[blockIdx.x*48 + v] = red[0];
    __syncthreads();
  }
}

__global__ void reducef_kernel(const float* __restrict__ part, float* __restrict__ Gf,
                               float* __restrict__ sumf){
  int t = threadIdx.x;
  if (t < 42){
    float s = 0.f;
    for (int i=0;i<256;++i) s += part[i*48 + t];
    if (t<36) Gf[t]=s; else sumf[t-36]=s;
  }
}

// ---------------- MFMA Gram: G = H^T H over bf16 H ----------------
template<int CIN>
__global__ __launch_bounds__(256) void gramM_kernel(const bf16* __restrict__ H, int M,
                                                    float* __restrict__ G){
  constexpr int Tt = CIN/64;
  int tile = blockIdx.x % (Tt*Tt);
  int chunk = blockIdx.x / (Tt*Tt);
  int nchunks = gridDim.x / (Tt*Tt);
  int tr = tile / Tt, tc = tile % Tt;
  bool diag = (tr == tc);
  __shared__ short HTa[64*68];
  __shared__ short HTb[64*68];
  int rpc = M / nchunks;
  int r0 = chunk*rpc;
  int tid = threadIdx.x, lane = tid & 63, w = tid >> 6;
  int mt = w >> 1, nt = w & 1;
  floatx16 acc;
  #pragma unroll
  for (int q=0;q<16;++q) acc[q]=0.f;
  const short* Bbase = diag ? HTa : HTb;
  int arow = (mt*32 + (lane&31))*68;
  int brow = (nt*32 + (lane&31))*68;
  int ko = (lane>>5)*8;
  for (int rb=r0; rb<r0+rpc; rb+=64){
    #pragma unroll
    for (int s=0;s<2;++s){
      int e = tid + s*256;
      int row = e >> 3, c0 = (e & 7)*8;
      U4b va; va.q = *(const uint4*)&H[(size_t)(rb+row)*CIN + tr*64 + c0];
      #pragma unroll
      for (int j=0;j<8;++j) HTa[(c0+j)*68 + row] = (short)va.s[j];
      if (!diag){
        U4b vb; vb.q = *(const uint4*)&H[(size_t)(rb+row)*CIN + tc*64 + c0];
        #pragma unroll
        for (int j=0;j<8;++j) HTb[(c0+j)*68 + row] = (short)vb.s[j];
      }
    }
    __syncthreads();
    #pragma unroll
    for (int kc=0;kc<64;kc+=16){
      Frag a, b;
      const short* ap = &HTa[arow + kc + ko];
      const short* bp = &Bbase[brow + kc + ko];
      a.u2[0] = *(const uint2*)ap;  a.u2[1] = *(const uint2*)(ap+4);
      b.u2[0] = *(const uint2*)bp;  b.u2[1] = *(const uint2*)(bp+4);
      acc = __builtin_amdgcn_mfma_f32_32x32x16_bf16(a.v, b.v, acc, 0, 0, 0);
    }
    __syncthreads();
  }
  int col = lane & 31, rbase = 4*(lane>>5);
  #pragma unroll
  for (int r=0;r<16;++r){
    int row = (r&3) + 8*(r>>2) + rbase;
    atomicAdd(&G[(size_t)(tr*64 + mt*32 + row)*CIN + tc*64 + nt*32 + col], acc[r]);
  }
}

// ---------------- column sums of H ----------------
template<int CIN, typename T>
__global__ __launch_bounds__(256) void colsum_kernel(const T* __restrict__ H, int M,
                                                     float* __restrict__ sumh){
  int rpb = (M + gridDim.x - 1)/gridDim.x;
  int r0 = blockIdx.x*rpb, r1 = min(M, r0+rpb);
  if constexpr (CIN <= 256){
    constexpr int RP = 256/CIN;
    int c = threadIdx.x % CIN;
    int sub = threadIdx.x / CIN;
    float a = 0.f;
    for (int r=r0+sub; r<r1; r+=RP) a += ldf(H[(size_t)r*CIN + c]);
    atomicAdd(&sumh[c], a);
  } else {
    float a0=0.f, a1=0.f;
    for (int r=r0;r<r1;++r){
      a0 += ldf(H[(size_t)r*CIN + threadIdx.x]);
      a1 += ldf(H[(size_t)r*CIN + threadIdx.x + 256]);
    }
    atomicAdd(&sumh[threadIdx.x], a0);
    atomicAdd(&sumh[threadIdx.x+256], a1);
  }
}

// ---------------- P = G @ W ----------------
__global__ void kP_kernel(const float* __restrict__ G, const float* __restrict__ Wf,
                          float* __restrict__ P, int Cin, int Cout){
  int id = blockIdx.x*256 + threadIdx.x;
  if (id >= Cin*Cout) return;
  int i = id / Cout, j = id - i*Cout;
  float s = 0.f;
  for (int k=0;k<Cin;++k) s = fmaf(G[(size_t)i*Cin+k], Wf[(size_t)k*Cout+j], s);
  P[id] = s;
}

// ---------------- scale/shift from Gram-derived BN stats ----------------
__global__ void kFinal_kernel(const float* __restrict__ P, const float* __restrict__ sumh,
                              const float* __restrict__ Wf, const float* __restrict__ g,
                              const float* __restrict__ bb, float* __restrict__ scale,
                              float* __restrict__ shift, int Cin, int Cout, float invM){
  int j = blockIdx.x*256 + threadIdx.x;
  if (j >= Cout) return;
  float mean=0.f, e2=0.f;
  for (int i=0;i<Cin;++i){
    float w = Wf[(size_t)i*Cout + j];
    mean = fmaf(sumh[i], w, mean);
    e2   = fmaf(w, P[(size_t)i*Cout + j], e2);
  }
  mean *= invM; e2 *= invM;
  float var = e2 - mean*mean;
  float inv = rsqrtf(var + EPSf);
  float sc = g[j]*inv;
  scale[j]=sc;
  shift[j]=bb[j] - mean*sc;
}

// ---------------- layer-2 stats ----------------
__global__ __launch_bounds__(512) void stats2_kernel(const float* __restrict__ x,
    const int* __restrict__ idx, const float* __restrict__ W1f,
    const float* __restrict__ sc1v, const float* __restrict__ sh1v,
    float* __restrict__ G2, float* __restrict__ sum2){
  __shared__ float W1s[6][64];
  __shared__ float fsh[64][8];
  __shared__ short H1T[64*68];
  __shared__ float csum[64];
  int tid = threadIdx.x, lane = tid & 63, w = tid >> 6;   // 8 waves
  if (tid < 384) W1s[tid>>6][tid&63] = W1f[tid];
  if (tid < 64) csum[tid] = 0.f;
  int rp = tid >> 4, cq = tid & 15, c0 = cq*4;
  float sca[4], sha[4];
  #pragma unroll
  for (int k=0;k<4;++k){ sca[k]=sc1v[c0+k]; sha[k]=sh1v[c0+k]; }
  int mt = w & 1, nt = (w>>1) & 1, kh = w >> 2;
  int arow = (mt*32 + (lane&31))*68;
  int brow = (nt*32 + (lane&31))*68;
  int ko = (lane>>5)*8;
  floatx16 acc;
  #pragma unroll
  for (int q=0;q<16;++q) acc[q]=0.f;
  float cs[4] = {0.f,0.f,0.f,0.f};
  int rpc = Mrows / gridDim.x;
  int r0 = blockIdx.x * rpc;
  __syncthreads();
  for (int rb=r0; rb<r0+rpc; rb+=64){
    {
      int r = tid>>3, e = tid&7;
      if (e < 6){
        int grow = rb + r;
        int bn = grow / Kk;
        int b = bn >> 12, n = bn & 4095;
        int j = idx[grow];
        const float* xb = x + b*3*Nn;
        fsh[r][e] = (e<3) ? xb[e*Nn + j] : xb[(e-3)*Nn + n];
      }
    }
    __syncthreads();
    {
      float y0[4]={0,0,0,0}, y1[4]={0,0,0,0};
      int ra = rp*2, rbw = rp*2+1;
      #pragma unroll
      for (int i=0;i<6;++i){
        float fa = fsh[ra][i], fb = fsh[rbw][i];
        float4 wv = *(const float4*)&W1s[i][c0];
        y0[0]=fmaf(fa,wv.x,y0[0]); y0[1]=fmaf(fa,wv.y,y0[1]);
        y0[2]=fmaf(fa,wv.z,y0[2]); y0[3]=fmaf(fa,wv.w,y0[3]);
        y1[0]=fmaf(fb,wv.x,y1[0]); y1[1]=fmaf(fb,wv.y,y1[1]);
        y1[2]=fmaf(fb,wv.z,y1[2]); y1[3]=fmaf(fb,wv.w,y1[3]);
      }
      #pragma unroll
      for (int k=0;k<4;++k){
        float va = fmaxf(fmaf(y0[k],sca[k],sha[k]),0.f);
        float vb = fmaxf(fmaf(y1[k],sca[k],sha[k]),0.f);
        cs[k] += va; cs[k] += vb;
        unsigned int pk = f2bu(va) | ((unsigned)f2bu(vb)<<16);
        *(unsigned int*)&H1T[(c0+k)*68 + ra] = pk;
      }
    }
    __syncthreads();
    {
      int kc = kh*32;
      #pragma unroll
      for (int s=0;s<2;++s){
        Frag a, b;
        const short* ap = &H1T[arow + kc + s*16 + ko];
        const short* bp = &H1T[brow + kc + s*16 + ko];
        a.u2[0] = *(const uint2*)ap;  a.u2[1] = *(const uint2*)(ap+4);
        b.u2[0] = *(const uint2*)bp;  b.u2[1] = *(const uint2*)(bp+4);
        acc = __builtin_amdgcn_mfma_f32_32x32x16_bf16(a.v, b.v, acc, 0, 0, 0);
      }
    }
    __syncthreads();
  }
  int col = lane & 31, rbase = 4*(lane>>5);
  #pragma unroll
  for (int r=0;r<16;++r){
    int row = (r&3) + 8*(r>>2) + rbase;
    atomicAdd(&G2[(size_t)(mt*32+row)*64 + nt*32+col], acc[r]);
  }
  #pragma unroll
  for (int k=0;k<4;++k) atomicAdd(&csum[c0+k], cs[k]);
  __syncthreads();
  if (tid < 64) atomicAdd(&sum2[tid], csum[tid]);
}

// ---------------- fused layers 1+2 ----------------
__global__ __launch_bounds__(64) void fl12_kernel(const float* __restrict__ x,
    const int* __restrict__ idx, const float* __restrict__ W1f,
    const float* __restrict__ sc1v, const float* __restrict__ sh1v,
    const float* __restrict__ W2f, const float* __restrict__ sc2v,
    const float* __restrict__ sh2v, bf16* __restrict__ H2, bf16* __restrict__ cat){
  __shared__ float fsh[Kk][6];
  __shared__ float h1[Kk][64];
  __shared__ float mm[4][64];
  int bn = blockIdx.x, b = bn>>12, n = bn & 4095;
  int tid = threadIdx.x;
  if (tid < Kk){
    int j = idx[(size_t)bn*Kk + tid];
    const float* xb = x + b*3*Nn;
    fsh[tid][0]=xb[j]; fsh[tid][1]=xb[Nn+j]; fsh[tid][2]=xb[2*Nn+j];
    fsh[tid][3]=xb[n]; fsh[tid][4]=xb[Nn+n]; fsh[tid][5]=xb[2*Nn+n];
  }
  __syncthreads();
  {
    float sc=sc1v[tid], sh=sh1v[tid];
    float w[6];
    #pragma unroll
    for (int i=0;i<6;++i) w[i]=W1f[i*64+tid];
    float mx = 0.f;
    #pragma unroll
    for (int r=0;r<Kk;++r){
      float y=0.f;
      #pragma unroll
      for (int i=0;i<6;++i) y = fmaf(fsh[r][i], w[i], y);
      float v = fmaxf(fmaf(y,sc,sh),0.f);
      h1[r][tid]=v;
      mx = fmaxf(mx,v);
    }
    cat[(size_t)bn*512 + tid] = f2b(mx);
  }
  __syncthreads();
  int q = tid >> 4, c0 = (tid & 15)*4;
  float acc[5][4]={};
  for (int i0=0;i0<64;i0+=4){
    float hv[5][4];
    #pragma unroll
    for (int l=0;l<5;++l){
      float4 t4 = *(const float4*)&h1[q*5+l][i0];
      hv[l][0]=t4.x; hv[l][1]=t4.y; hv[l][2]=t4.z; hv[l][3]=t4.w;
    }
    #pragma unroll
    for (int ii=0;ii<4;++ii){
      const float* wp = W2f + (i0+ii)*64 + c0;
      float w0=wp[0],w1=wp[1],w2=wp[2],w3=wp[3];
      #pragma unroll
      for (int l=0;l<5;++l){
        float hvv=hv[l][ii];
        acc[l][0]=fmaf(hvv,w0,acc[l][0]);
        acc[l][1]=fmaf(hvv,w1,acc[l][1]);
        acc[l][2]=fmaf(hvv,w2,acc[l][2]);
        acc[l][3]=fmaf(hvv,w3,acc[l][3]);
      }
    }
  }
  float sc[4],sh[4];
  #pragma unroll
  for (int cb=0;cb<4;++cb){ sc[cb]=sc2v[c0+cb]; sh[cb]=sh2v[c0+cb]; }
  float mx[4]={0,0,0,0};
  #pragma unroll
  for (int l=0;l<5;++l){
    unsigned short us[4];
    #pragma unroll
    for (int cb=0;cb<4;++cb){
      float v=fmaxf(fmaf(acc[l][cb],sc[cb],sh[cb]),0.f);
      mx[cb]=fmaxf(mx[cb],v);
      us[cb]=f2bu(v);
    }
    uint2 v2; v2.x = us[0]|((unsigned)us[1]<<16); v2.y=us[2]|((unsigned)us[3]<<16);
    *(uint2*)(H2 + ((size_t)bn*Kk + q*5+l)*64 + c0) = v2;
  }
  #pragma unroll
  for (int cb=0;cb<4;++cb) mm[q][c0+cb]=mx[cb];
  __syncthreads();
  {
    float M0 = fmaxf(fmaxf(mm[0][tid],mm[1][tid]),fmaxf(mm[2][tid],mm[3][tid]));
    cat[(size_t)bn*512 + 64 + tid] = f2b(M0);
  }
}

// ---------------- layer-4 stats: MFMA produce + MFMA Gram ----------------
__global__ __launch_bounds__(512) void stats4_kernel(const bf16* __restrict__ H2,
    const bf16* __restrict__ W3T, const float* __restrict__ sc3v, const float* __restrict__ sh3v,
    float* __restrict__ G4, float* __restrict__ sum4){
  __shared__ short h2s[64*68];
  __shared__ short H3T[128*68];
  __shared__ float csum[128];
  int tid = threadIdx.x, lane = tid & 63, w = tid >> 6;   // 8 waves
  if (tid < 128) csum[tid] = 0.f;
  int trow = tid >> 3, tc0 = (tid & 7)*8;
  int pl  = lane & 31;
  int ko  = (lane >> 5)*8;
  int pmt = w >> 2, pnt = w & 3;
  int parow = (pmt*32 + pl)*68;
  int pcol  = pnt*32 + pl;
  float psc = sc3v[pcol], psh = sh3v[pcol];
  int prbase = 4*(lane>>5);
  FragQ bfr[4];
  #pragma unroll
  for (int kq=0;kq<4;++kq)
    bfr[kq].q = *(const uint4*)&W3T[(size_t)pcol*64 + kq*16 + ko];
  int gmt = w>>1, gnt0 = (w&1)*2, gnt1 = gnt0+1;
  int garow  = (gmt*32 + pl)*68;
  int gbrow0 = (gnt0*32 + pl)*68;
  int gbrow1 = (gnt1*32 + pl)*68;
  floatx16 acc0, acc1;
  #pragma unroll
  for (int q=0;q<16;++q){ acc0[q]=0.f; acc1[q]=0.f; }
  float cs = 0.f;
  int rpc = Mrows / gridDim.x;
  int r0 = blockIdx.x * rpc;
  uint4 hreg = *(const uint4*)&H2[(size_t)(r0+trow)*64 + tc0];
  for (int rb=r0; rb<r0+rpc; rb+=64){
    {
      short* dst = &h2s[trow*68 + tc0];
      *(uint2*)dst       = make_uint2(hreg.x, hreg.y);
      *(uint2*)(dst + 4) = make_uint2(hreg.z, hreg.w);
    }
    if (rb + 64 < r0 + rpc)
      hreg = *(const uint4*)&H2[(size_t)(rb+64+trow)*64 + tc0];
    __syncthreads();
    {
      floatx16 pacc;
      #pragma unroll
      for (int q=0;q<16;++q) pacc[q]=0.f;
      #pragma unroll
      for (int kq=0;kq<4;++kq){
        Frag a;
        const short* ap = &h2s[parow + kq*16 + ko];
        a.u2[0] = *(const uint2*)ap;  a.u2[1] = *(const uint2*)(ap+4);
        pacc = __builtin_amdgcn_mfma_f32_32x32x16_bf16(a.v, bfr[kq].v, pacc, 0, 0, 0);
      }
      #pragma unroll
      for (int g=0; g<4; ++g){
        unsigned short p[4];
        #pragma unroll
        for (int r=0;r<4;++r){
          float v = fmaxf(fmaf(pacc[g*4+r], psc, psh), 0.f);
          cs += v;
          p[r] = f2bu(v);
        }
        uint2 pk; pk.x = p[0] | ((unsigned)p[1]<<16); pk.y = p[2] | ((unsigned)p[3]<<16);
        *(uint2*)&H3T[pcol*68 + pmt*32 + 8*g + prbase] = pk;
      }
    }
    __syncthreads();
    #pragma unroll
    for (int kc=0;kc<64;kc+=16){
      Frag a, b0, b1;
      const short* ap  = &H3T[garow  + kc + ko];
      const short* bp0 = &H3T[gbrow0 + kc + ko];
      const short* bp1 = &H3T[gbrow1 + kc + ko];
      a.u2[0]  = *(const uint2*)ap;   a.u2[1]  = *(const uint2*)(ap+4);
      b0.u2[0] = *(const uint2*)bp0;  b0.u2[1] = *(const uint2*)(bp0+4);
      b1.u2[0] = *(const uint2*)bp1;  b1.u2[1] = *(const uint2*)(bp1+4);
      acc0 = __builtin_amdgcn_mfma_f32_32x32x16_bf16(a.v, b0.v, acc0, 0, 0, 0);
      acc1 = __builtin_amdgcn_mfma_f32_32x32x16_bf16(a.v, b1.v, acc1, 0, 0, 0);
    }
  }
  int col = pl;
  #pragma unroll
  for (int r=0;r<16;++r){
    int row = (r&3) + 8*(r>>2) + prbase;
    atomicAdd(&G4[(size_t)(gmt*32+row)*128 + gnt0*32+col], acc0[r]);
    atomicAdd(&G4[(size_t)(gmt*32+row)*128 + gnt1*32+col], acc1[r]);
  }
  atomicAdd(&csum[pcol], cs);
  __syncthreads();
  if (tid < 128) atomicAdd(&sum4[tid], csum[tid]);
}

// ---------------- fused layers 3+4: MFMA produce chain + col-owner maxpool ----------------
__global__ __launch_bounds__(512,4) void fl34_kernel(const bf16* __restrict__ H2,
    const bf16* __restrict__ W3T, const float* __restrict__ sc3v, const float* __restrict__ sh3v,
    const bf16* __restrict__ W4T, const float* __restrict__ sc4v, const float* __restrict__ sh4v,
    bf16* __restrict__ cat){
  __shared__ short h2s[64*68];             // 8.5 KB
  __shared__ short h3s[64*132];            // 16.5 KB
  __shared__ unsigned short h4s[64*256];   // 32 KB
  __shared__ unsigned short mx3u[16*128];  // 4 KB
  __shared__ unsigned short mx4u[16*256];  // 8 KB
  int tid = threadIdx.x, lane = tid & 63, w = tid >> 6;
  int pl = lane & 31;
  int ko = (lane >> 5)*8;
  int rbase = 4*(lane>>5);
  {
    unsigned* p4 = (unsigned*)mx4u;
    for (int u=tid; u<2048; u+=512) p4[u]=0u;
    unsigned* p3 = (unsigned*)mx3u;
    for (int u=tid; u<1024; u+=512) p3[u]=0u;
  }
  int mt3 = w >> 2, ct3 = w & 3;
  int c3 = ct3*32 + pl;
  float sc3 = sc3v[c3], sh3 = sh3v[c3];
  int a3row = (mt3*32 + pl)*68;
  int c4 = w*32 + pl;
  float sc4 = sc4v[c4], sh4 = sh4v[c4];
  int trow = tid >> 3, tc0 = (tid & 7)*8;
  int r0 = blockIdx.x * 320;
  uint4 hreg = *(const uint4*)&H2[(size_t)(r0+trow)*64 + tc0];
  {
    short* dst = &h2s[trow*68 + tc0];
    *(uint2*)dst       = make_uint2(hreg.x, hreg.y);
    *(uint2*)(dst + 4) = make_uint2(hreg.z, hreg.w);
  }
  hreg = *(const uint4*)&H2[(size_t)(r0 + 64 + trow)*64 + tc0];
  __syncthreads();
  for (int t=0; t<5; ++t){
    {
      floatx16 pa;
      #pragma unroll
      for (int q=0;q<16;++q) pa[q]=0.f;
      #pragma unroll
      for (int kq=0;kq<4;++kq){
        Frag a; FragQ b;
        const short* ap = &h2s[a3row + kq*16 + ko];
        a.u2[0] = *(const uint2*)ap;  a.u2[1] = *(const uint2*)(ap+4);
        b.q = *(const uint4*)&W3T[(size_t)c3*64 + kq*16 + ko];
        pa = __builtin_amdgcn_mfma_f32_32x32x16_bf16(a.v, b.v, pa, 0, 0, 0);
      }
      #pragma unroll
      for (int r=0;r<16;++r){
        int m = mt3*32 + (r&3) + 8*(r>>2) + rbase;
        float v = fmaxf(fmaf(pa[r], sc3, sh3), 0.f);
        h3s[m*132 + c3] = (short)f2bu(v);
      }
    }
    __syncthreads();
    #pragma unroll
    for (int mt4=0; mt4<2; ++mt4){
      floatx16 acc;
      #pragma unroll
      for (int q=0;q<16;++q) acc[q]=0.f;
      int a4row = (mt4*32 + pl)*132;
      #pragma unroll
      for (int kq=0;kq<8;++kq){
        Frag a; FragQ b;
        const short* ap = &h3s[a4row + kq*16 + ko];
        a.u2[0] = *(const uint2*)ap;  a.u2[1] = *(const uint2*)(ap+4);
        b.q = *(const uint4*)&W4T[(size_t)c4*128 + kq*16 + ko];
        acc = __builtin_amdgcn_mfma_f32_32x32x16_bf16(a.v, b.v, acc, 0, 0, 0);
      }
      #pragma unroll
      for (int r=0;r<16;++r){
        int m = mt4*32 + (r&3) + 8*(r>>2) + rbase;
        float v = fmaxf(fmaf(acc[r], sc4, sh4), 0.f);
        h4s[m*256 + c4] = f2bu(v);
      }
    }
    __syncthreads();
    if (t < 4){
      short* dst = &h2s[trow*68 + tc0];
      *(uint2*)dst       = make_uint2(hreg.x, hreg.y);
      *(uint2*)(dst + 4) = make_uint2(hreg.z, hreg.w);
      if (t < 3) hreg = *(const uint4*)&H2[(size_t)(r0 + (t+2)*64 + trow)*64 + tc0];
    }
    {
      int lr0 = t*64;
      if (tid < 256){
        int c = tid;
        int p = lr0/20;
        int nb = (p+1)*20 - lr0;
        unsigned ml = 0;
        for (int r=0;r<64;++r){
          unsigned v = h4s[r*256 + c];
          ml = v > ml ? v : ml;
          if (--nb == 0){
            unsigned short* mp = &mx4u[p*256 + c];
            unsigned cur = *mp;
            if (ml > cur) *mp = (unsigned short)ml;
            ml = 0; ++p; nb = 20;
          }
        }
        if (nb != 20){
          unsigned short* mp = &mx4u[p*256 + c];
          unsigned cur = *mp;
          if (ml > cur) *mp = (unsigned short)ml;
        }
      } else if (tid < 384){
        int c = tid - 256;
        int p = lr0/20;
        int nb = (p+1)*20 - lr0;
        unsigned ml = 0;
        for (int r=0;r<64;++r){
          unsigned v = (unsigned)(unsigned short)h3s[r*132 + c];
          ml = v > ml ? v : ml;
          if (--nb == 0){
            unsigned short* mp = &mx3u[p*128 + c];
            unsigned cur = *mp;
            if (ml > cur) *mp = (unsigned short)ml;
            ml = 0; ++p; nb = 20;
          }
        }
        if (nb != 20){
          unsigned short* mp = &mx3u[p*128 + c];
          unsigned cur = *mp;
          if (ml > cur) *mp = (unsigned short)ml;
        }
      }
    }
    __syncthreads();
  }
  int bn0 = blockIdx.x*16;
  {
    int p = tid >> 5, c0 = (tid & 31)*8;
    uint4 v = *(const uint4*)&mx4u[p*256 + c0];
    *(uint4*)&cat[(size_t)(bn0+p)*512 + 256 + c0] = v;
  }
  if (tid < 256){
    int p = tid >> 4, c0 = (tid & 15)*8;
    uint4 v = *(const uint4*)&mx3u[p*128 + c0];
    *(uint4*)&cat[(size_t)(bn0+p)*512 + 128 + c0] = v;
  }
}

// ---------------- layer 5: MFMA GEMM + LDS-staged coalesced epilogue ----------------
__global__ __launch_bounds__(512) void l5_kernel(const bf16* __restrict__ cat,
                                                const bf16* __restrict__ W5T,
                                                const float* __restrict__ scale,
                                                const float* __restrict__ shift,
                                                float* __restrict__ out){
  __shared__ short cs[64*68];
  __shared__ float ob[64*129];
  int tid = threadIdx.x, lane = tid & 63, w = tid >> 6;
  int pl = lane & 31;
  int ko = (lane >> 5)*8;
  int rbase = 4*(lane>>5);
  int mt = w & 1, ntb = w >> 1;          // nt = ntb + 4*s, s=0..3
  int arow = (mt*32 + pl)*68;
  int trow = tid >> 3, tc0 = (tid & 7)*8;
  int r0 = blockIdx.x*64;
  floatx16 acc[4];
  #pragma unroll
  for (int s=0;s<4;++s)
    #pragma unroll
    for (int q=0;q<16;++q) acc[s][q]=0.f;
  const bf16* arow_g = cat + (size_t)(r0+trow)*512 + tc0;
  uint4 hreg = *(const uint4*)arow_g;
  for (int kc8=0; kc8<8; ++kc8){
    {
      short* dst = &cs[trow*68 + tc0];
      *(uint2*)dst       = make_uint2(hreg.x, hreg.y);
      *(uint2*)(dst + 4) = make_uint2(hreg.z, hreg.w);
    }
    if (kc8 < 7) hreg = *(const uint4*)(arow_g + (kc8+1)*64);
    __syncthreads();
    #pragma unroll
    for (int kq=0;kq<4;++kq){
      Frag a;
      const short* ap = &cs[arow + kq*16 + ko];
      a.u2[0] = *(const uint2*)ap;  a.u2[1] = *(const uint2*)(ap+4);
      #pragma unroll
      for (int s=0;s<4;++s){
        FragQ b;
        int col = (ntb + 4*s)*32 + pl;
        b.q = *(const uint4*)&W5T[(size_t)col*512 + kc8*64 + kq*16 + ko];
        acc[s] = __builtin_amdgcn_mfma_f32_32x32x16_bf16(a.v, b.v, acc[s], 0, 0, 0);
      }
    }
    __syncthreads();
  }
  int b = r0 >> 12, n0 = r0 & 4095;
  int colL = ntb*32 + pl;                // 0..127 within chunk
  int colc = tid >> 2, sub = tid & 3;    // writer mapping: 4 threads per col
  for (int s=0;s<4;++s){
    float sc = scale[128*s + colL], sh = shift[128*s + colL];
    #pragma unroll
    for (int q=0;q<16;++q){
      int m = mt*32 + (q&3) + 8*(q>>2) + rbase;
      ob[m*129 + colL] = fmaxf(fmaf(acc[s][q], sc, sh), 0.f);
    }
    __syncthreads();
    float* op = out + ((size_t)b*512 + 128*s + colc)*4096 + n0 + sub*16;
    #pragma unroll
    for (int j=0;j<4;++j){
      int rr = sub*16 + j*4;
      float4 v = make_float4(ob[(rr+0)*129 + colc], ob[(rr+1)*129 + colc],
                             ob[(rr+2)*129 + colc], ob[(rr+3)*129 + colc]);
      *(float4*)(op + j*4) = v;
    }
    __syncthreads();
  }
}

extern "C" void kernel_launch(void* const* d_in, const int* in_sizes, int n_in,
                              void* d_out, int out_size, void* d_ws, size_t ws_size,
                              hipStream_t stream){
  const float* x   = (const float*)d_in[0];
  const float* W1f = (const float*)d_in[1];
  const float* W2f = (const float*)d_in[2];
  const float* W3f = (const float*)d_in[3];
  const float* W4f = (const float*)d_in[4];
  const float* W5f = (const float*)d_in[5];
  const float* g1=(const float*)d_in[6],  *b1=(const float*)d_in[7];
  const float* g2=(const float*)d_in[8],  *b2=(const float*)d_in[9];
  const float* g3=(const float*)d_in[10], *b3=(const float*)d_in[11];
  const float* g4=(const float*)d_in[12], *b4=(const float*)d_in[13];
  const float* g5=(const float*)d_in[14], *b5=(const float*)d_in[15];
  float* out = (float*)d_out;

  char* w = (char*)d_ws;
  size_t off = 0;
  auto alloc = [&](size_t bytes)->void*{
    void* p = w + off;
    off = (off + bytes + 255) & ~(size_t)255;
    return p;
  };

  int*  idxb = (int*) alloc((size_t)BN*Kk*4);
  bf16* H2   = (bf16*)alloc((size_t)Mrows*64*2);
  bf16* catb = (bf16*)alloc((size_t)BN*512*2);
  bf16* W3T  = (bf16*)alloc((size_t)128*64*2);
  bf16* W4T  = (bf16*)alloc((size_t)256*128*2);
  bf16* W5T  = (bf16*)alloc((size_t)512*512*2);
  float* pv  = (float*)H2;
  int*   pib = (int*)((char*)H2 + (size_t)BN*8*Kk*4);

  size_t statsStart = off;
  float* partf=(float*)alloc(256*48*4);
  float* Gf=(float*)alloc(36*4);
  float* sumf=(float*)alloc(8*4);
  float* G2=(float*)alloc(4096*4);   float* sum2=(float*)alloc(64*4);
  float* G3=(float*)alloc(4096*4);   float* sum3=(float*)alloc(64*4);
  float* G4=(float*)alloc(16384*4);  float* sum4=(float*)alloc(128*4);
  float* G5=(float*)alloc(262144*4); float* sum5=(float*)alloc(512*4);
  float* P1=(float*)alloc(384*4);
  float* P2=(float*)alloc(4096*4);
  float* P3=(float*)alloc(8192*4);
  float* P4=(float*)alloc(32768*4);
  float* P5=(float*)alloc(262144*4);
  float* sc1=(float*)alloc(64*4);   float* sh1=(float*)alloc(64*4);
  float* sc2=(float*)alloc(64*4);   float* sh2=(float*)alloc(64*4);
  float* sc3=(float*)alloc(128*4);  float* sh3=(float*)alloc(128*4);
  float* sc4=(float*)alloc(256*4);  float* sh4=(float*)alloc(256*4);
  float* sc5=(float*)alloc(512*4);  float* sh5=(float*)alloc(512*4);
  size_t statsEnd = off;

  int statsFloats = (int)((statsEnd - statsStart)/4);
  zero_kernel<<<(statsFloats+255)/256,256,0,stream>>>((float*)(w+statsStart), statsFloats);
  w3t_kernel<<<32,256,0,stream>>>(W3f, W3T);
  w4t_kernel<<<128,256,0,stream>>>(W4f, W4T);
  w5t_kernel<<<1024,256,0,stream>>>(W5f, W5T);

  knnA_kernel<<<1024,256,0,stream>>>(x, pv, pib);
  knnB_kernel<<<BN/256,256,0,stream>>>(pv, pib, idxb);

  const float invM  = 1.0f/(float)Mrows;
  const float invM5 = 1.0f/(float)BN;

  gramf_kernel<<<256,256,0,stream>>>(x, idxb, partf);
  reducef_kernel<<<1,64,0,stream>>>(partf, Gf, sumf);
  kP_kernel<<<2,256,0,stream>>>(Gf, W1f, P1, 6, 64);
  kFinal_kernel<<<1,256,0,stream>>>(P1, sumf, W1f, g1, b1, sc1, sh1, 6, 64, invM);

  stats2_kernel<<<512,512,0,stream>>>(x, idxb, W1f, sc1, sh1, G2, sum2);
  kP_kernel<<<16,256,0,stream>>>(G2, W2f, P2, 64, 64);
  kFinal_kernel<<<1,256,0,stream>>>(P2, sum2, W2f, g2, b2, sc2, sh2, 64, 64, invM);

  fl12_kernel<<<BN,64,0,stream>>>(x, idxb, W1f, sc1, sh1, W2f, sc2, sh2, H2, catb);

  colsum_kernel<64,bf16><<<512,256,0,stream>>>(H2, Mrows, sum3);
  gramM_kernel<64><<<512,256,0,stream>>>(H2, Mrows, G3);
  kP_kernel<<<32,256,0,stream>>>(G3, W3f, P3, 64, 128);
  kFinal_kernel<<<1,256,0,stream>>>(P3, sum3, W3f, g3, b3, sc3, sh3, 64, 128, invM);

  stats4_kernel<<<512,512,0,stream>>>(H2, W3T, sc3, sh3, G4, sum4);
  kP_kernel<<<128,256,0,stream>>>(G4, W4f, P4, 128, 256);
  kFinal_kernel<<<1,256,0,stream>>>(P4, sum4, W4f, g4, b4, sc4, sh4, 128, 256, invM);

  fl34_kernel<<<Mrows/320,512,0,stream>>>(H2, W3T, sc3, sh3, W4T, sc4, sh4, catb);

  colsum_kernel<512,bf16><<<512,256,0,stream>>>(catb, BN, sum5);
  gramM_kernel<512><<<512,256,0,stream>>>(catb, BN, G5);
  kP_kernel<<<1024,256,0,stream>>>(G5, W5f, P5, 512, 512);
  kFinal_kernel<<<2,256,0,stream>>>(P5, sum5, W5f, g5, b5, sc5, sh5, 512, 512, invM5);
  l5_kernel<<<BN/64,512,0,stream>>>(catb, W5T, sc5, sh5, out);
}

// Round 9
// 1384.397 us; speedup vs baseline: 1.1252x; 1.0456x over previous
//
#include <hip/hip_runtime.h>
#include <hip/hip_bf16.h>
#include <cfloat>

using bf16 = __hip_bfloat16;

typedef short short8 __attribute__((ext_vector_type(8)));
typedef float floatx16 __attribute__((ext_vector_type(16)));
union Frag { short8 v; uint2 u2[2]; };
union FragQ { short8 v; uint4 q; uint2 u2[2]; };
union U4b { uint4 q; unsigned short s[8]; };

constexpr int Bb = 8, Nn = 4096, Kk = 20;
constexpr int BN = Bb * Nn;                     // 32768
constexpr int Mrows = BN * Kk;                  // 655360
constexpr float EPSf = 1e-5f;

static __device__ __forceinline__ float b2f(bf16 v){ return __bfloat162float(v); }
static __device__ __forceinline__ bf16 f2b(float v){ return __float2bfloat16(v); }
static __device__ __forceinline__ unsigned short f2bu(float v){
  union { bf16 b; unsigned short u; } cv; cv.b = __float2bfloat16(v); return cv.u;
}
static __device__ __forceinline__ float bits2f(unsigned short u){
  union { unsigned int i; float f; } c; c.i = ((unsigned)u)<<16; return c.f;
}

// ---------------- zero workspace region ----------------
__global__ void zero_kernel(float* __restrict__ p, int n){
  int i = blockIdx.x*256 + threadIdx.x;
  if (i < n) p[i] = 0.f;
}

// ---------------- W3^T bf16 pack ----------------
__global__ void w3t_kernel(const float* __restrict__ W3f, bf16* __restrict__ W3T){
  int id = blockIdx.x*256 + threadIdx.x;   // 128*64 = 8192 elems
  if (id >= 128*64) return;
  int n = id >> 6, k = id & 63;
  W3T[id] = f2b(W3f[(size_t)k*128 + n]);
}

// ---------------- W4^T bf16 pack ----------------
__global__ void w4t_kernel(const float* __restrict__ W4f, bf16* __restrict__ W4T){
  int id = blockIdx.x*256 + threadIdx.x;   // 128*256 = 32768 elems
  if (id >= 128*256) return;
  int k = id >> 8, c = id & 255;           // coalesced read of W4f
  W4T[(size_t)c*128 + k] = f2b(W4f[id]);
}

// ---------------- W5^T bf16 pack ----------------
__global__ void w5t_kernel(const float* __restrict__ W5f, bf16* __restrict__ W5T){
  int id = blockIdx.x*256 + threadIdx.x;   // 512*512 = 262144 elems
  if (id >= 512*512) return;
  int k = id >> 9, c = id & 511;           // coalesced read of W5f
  W5T[(size_t)c*512 + k] = f2b(W5f[id]);
}

// ---------------- KNN phase A v6: 256-cand stripes, groups of 8, u8 index list ----
// 16 stripes of 256 candidates (grid 2048). Pass A: fast-fma nd, thr = 20th-largest
// of 32 group-maxes (groups of 8) minus margin. E[admits] ~29.5, sigma 5.1; CAP=64
// = 6.7 sigma (exact full-scan fallback kept for correctness, ~never fires).
// u8 index list @ stride 68B (odd*17 bank spread): LDS 22KB -> 7 blocks/CU (28 waves).
// Final selection recomputes nd with the EXACT contract-off formula => reference-exact.
__global__ __launch_bounds__(256) void knnA_kernel(const float* __restrict__ x,
                                                   float* __restrict__ pv, int* __restrict__ pi){
#pragma clang fp contract(off)
  __shared__ float4 p4[256];
  __shared__ unsigned char lst[256*68];
  int blk = blockIdx.x;
  int stripe = blk & 15;
  int chunk  = (blk >> 4) & 15;
  int b      = blk >> 8;
  const float* xb = x + b*3*Nn;
  int j0 = stripe*256;
  {
    int j = j0 + threadIdx.x;
    float a0 = xb[j];
    float a1 = xb[Nn + j];
    float a2 = xb[2*Nn + j];
    float s = a0*a0; s = s + a1*a1; s = s + a2*a2;
    p4[threadIdx.x] = make_float4(a0, a1, a2, s);
  }
  __syncthreads();
  int i = chunk*256 + threadIdx.x;
  float xi = xb[i], yi = xb[Nn+i], zi = xb[2*Nn+i];
  float ni = xi*xi; ni = ni + yi*yi; ni = ni + zi*zi;
  float mni = -ni;
  float xi2 = xi + xi, yi2 = yi + yi, zi2 = zi + zi;
  // ---- pass A: 32 group-maxes (groups of 8, fast nd) -> top-20 min/max network ----
  float tv[Kk];
  #pragma unroll
  for (int s=0;s<Kk;++s) tv[s] = -FLT_MAX;
  for (int g=0; g<32; ++g){
    float gm = -FLT_MAX;
    #pragma unroll
    for (int e=0;e<8;++e){
      float4 p = p4[g*8+e];
      float base = mni - p.w;
      float nd = fmaf(xi2, p.x, fmaf(yi2, p.y, fmaf(zi2, p.z, base)));
      gm = fmaxf(gm, nd);
    }
    #pragma unroll
    for (int s=Kk-1; s>=1; --s)
      tv[s] = fmaxf(tv[s], fminf(tv[s-1], gm));
    tv[0] = fmaxf(tv[0], gm);
  }
  float thr = tv[Kk-1];
  thr = thr - (fabsf(thr)*1e-5f + 1e-6f);   // margin >> fast-vs-exact fp discrepancy
  // ---- pass B: fast compare, collect u8 indices (ascending u => stable) ----
  unsigned char* ml = &lst[threadIdx.x*68];
  int cnt = 0;
  for (int u=0; u<256; ++u){
    float4 p = p4[u];
    float base = mni - p.w;
    float nd = fmaf(xi2, p.x, fmaf(yi2, p.y, fmaf(zi2, p.z, base)));
    if (nd >= thr && cnt < 64){ ml[cnt] = (unsigned char)u; ++cnt; }
  }
  // ---- final: EXACT (val,idx) insertion sort ----
  float av[Kk]; int ai[Kk];
  #pragma unroll
  for (int s=0;s<Kk;++s){ av[s] = -FLT_MAX; ai[s] = 0; }
  if (cnt >= 64){
    // exact fallback: full branchy scan (statistically never; correctness guarantee)
    for (int u=0; u<256; ++u){
      float4 p = p4[u];
      float dot = xi*p.x; dot = dot + yi*p.y; dot = dot + zi*p.z;
      float inner = -2.0f*dot;
      float nd = mni - inner; nd = nd - p.w;
      if (nd > av[Kk-1]){
        #pragma unroll
        for (int s=Kk-1; s>=1; --s){
          bool cs = nd > av[s];
          bool cp = nd > av[s-1];
          av[s] = cs ? (cp ? av[s-1] : nd) : av[s];
          ai[s] = cs ? (cp ? ai[s-1] : (j0+u)) : ai[s];
        }
        if (nd > av[0]){ av[0] = nd; ai[0] = j0+u; }
      }
    }
  } else {
    for (int t=0; t<cnt; ++t){
      int lj = ml[t];
      float4 p = p4[lj];
      float dot = xi*p.x; dot = dot + yi*p.y; dot = dot + zi*p.z;
      float inner = -2.0f*dot;
      float nd = mni - inner; nd = nd - p.w;
      if (nd > av[Kk-1]){
        #pragma unroll
        for (int s=Kk-1; s>=1; --s){
          bool cs = nd > av[s];
          bool cp = nd > av[s-1];
          av[s] = cs ? (cp ? av[s-1] : nd) : av[s];
          ai[s] = cs ? (cp ? ai[s-1] : (j0+lj)) : ai[s];
        }
        if (nd > av[0]){ av[0] = nd; ai[0] = j0+lj; }
      }
    }
  }
  long long base = ((long long)(b*Nn + i)*16 + stripe)*Kk;
  #pragma unroll
  for (int s=0;s<Kk;++s){ pv[base+s] = av[s]; pi[base+s] = ai[s]; }
}

// ---------------- KNN phase B: merge 16 stripes ----------------
__global__ __launch_bounds__(256) void knnB_kernel(const float* __restrict__ pv,
                                                   const int* __restrict__ pi,
                                                   int* __restrict__ idx){
  int p = blockIdx.x*256 + threadIdx.x;
  if (p >= BN) return;
  long long base = (long long)p*16*Kk;
  float av[Kk]; int ai[Kk];
  #pragma unroll
  for (int s=0;s<Kk;++s){ av[s]=pv[base+s]; ai[s]=pi[base+s]; }
  for (int t=Kk; t<16*Kk; ++t){
    float nd = pv[base+t]; int j = pi[base+t];
    if (nd > av[Kk-1]){
      #pragma unroll
      for (int s=Kk-1;s>=1;--s){
        bool cs = nd > av[s];
        bool cp = nd > av[s-1];
        av[s] = cs ? (cp?av[s-1]:nd) : av[s];
        ai[s] = cs ? (cp?ai[s-1]:j) : ai[s];
      }
      if (nd > av[0]){ av[0]=nd; ai[0]=j; }
    }
  }
  #pragma unroll
  for (int s=0;s<Kk;++s) idx[(long long)p*Kk+s] = ai[s];
}

// ---------------- layer-1 feature stats ----------------
__global__ __launch_bounds__(256) void gramf_kernel(const float* __restrict__ x,
                                                    const int* __restrict__ idx,
                                                    float* __restrict__ part){
  float acc[36]; float s6[6];
  #pragma unroll
  for (int a=0;a<36;++a) acc[a]=0.f;
  #pragma unroll
  for (int a=0;a<6;++a) s6[a]=0.f;
  for (long long row = blockIdx.x*256 + threadIdx.x; row < Mrows; row += (long long)gridDim.x*256){
    int bn = (int)(row / Kk);
    int b = bn >> 12, n = bn & 4095;
    int j = idx[row];
    const float* xb = x + b*3*Nn;
    float f[6];
    f[0]=xb[j];  f[1]=xb[Nn+j];  f[2]=xb[2*Nn+j];
    f[3]=xb[n];  f[4]=xb[Nn+n];  f[5]=xb[2*Nn+n];
    #pragma unroll
    for (int a=0;a<6;++a){
      s6[a] += f[a];
      #pragma unroll
      for (int c=0;c<6;++c) acc[a*6+c] = fmaf(f[a], f[c], acc[a*6+c]);
    }
  }
  __shared__ float red[256];
  for (int v=0; v<42; ++v){
    red[threadIdx.x] = (v<36)? acc[v] : s6[v-36];
    __syncthreads();
    for (int s=128; s>0; s>>=1){
      if (threadIdx.x < s) red[threadIdx.x] += red[threadIdx.x+s];
      __syncthreads();
    }
    if (threadIdx.x==0) part[blockIdx.x*48 + v] = red[0];
    __syncthreads();
  }
}

__global__ void reducef_kernel(const float* __restrict__ part, float* __restrict__ Gf,
                               float* __restrict__ sumf){
  int t = threadIdx.x;
  if (t < 42){
    float s = 0.f;
    for (int i=0;i<256;++i) s += part[i*48 + t];
    if (t<36) Gf[t]=s; else sumf[t-36]=s;
  }
}

// ---------------- G3 gram (CIN=64) with fused column sums ----------------
// Each block stages its row-chunk of H2 once; column sums accumulated during
// staging (c0 invariant across s), LDS-reduced, 64 global atomics/block.
__global__ __launch_bounds__(256) void gram3_kernel(const bf16* __restrict__ H, int M,
                                                    float* __restrict__ G,
                                                    float* __restrict__ sumh){
  __shared__ short HTa[64*68];
  __shared__ float csum[64];
  int tid = threadIdx.x, lane = tid & 63, w = tid >> 6;
  if (tid < 64) csum[tid] = 0.f;
  int nchunks = gridDim.x;
  int rpc = M / nchunks;
  int r0 = blockIdx.x*rpc;
  int mt = w >> 1, nt = w & 1;
  floatx16 acc;
  #pragma unroll
  for (int q=0;q<16;++q) acc[q]=0.f;
  int arow = (mt*32 + (lane&31))*68;
  int brow = (nt*32 + (lane&31))*68;
  int ko = (lane>>5)*8;
  int c0s = (tid & 7)*8;          // staged cols, invariant across s
  float cs[8];
  #pragma unroll
  for (int j=0;j<8;++j) cs[j]=0.f;
  for (int rb=r0; rb<r0+rpc; rb+=64){
    #pragma unroll
    for (int s=0;s<2;++s){
      int e = tid + s*256;
      int row = e >> 3;
      U4b va; va.q = *(const uint4*)&H[(size_t)(rb+row)*64 + c0s];
      #pragma unroll
      for (int j=0;j<8;++j){
        HTa[(c0s+j)*68 + row] = (short)va.s[j];
        cs[j] += bits2f(va.s[j]);
      }
    }
    __syncthreads();
    #pragma unroll
    for (int kc=0;kc<64;kc+=16){
      Frag a, b;
      const short* ap = &HTa[arow + kc + ko];
      const short* bp = &HTa[brow + kc + ko];
      a.u2[0] = *(const uint2*)ap;  a.u2[1] = *(const uint2*)(ap+4);
      b.u2[0] = *(const uint2*)bp;  b.u2[1] = *(const uint2*)(bp+4);
      acc = __builtin_amdgcn_mfma_f32_32x32x16_bf16(a.v, b.v, acc, 0, 0, 0);
    }
    __syncthreads();
  }
  int col = lane & 31, rbase = 4*(lane>>5);
  #pragma unroll
  for (int r=0;r<16;++r){
    int row = (r&3) + 8*(r>>2) + rbase;
    atomicAdd(&G[(size_t)(mt*32 + row)*64 + nt*32 + col], acc[r]);
  }
  #pragma unroll
  for (int j=0;j<8;++j) atomicAdd(&csum[c0s+j], cs[j]);
  __syncthreads();
  if (tid < 64) atomicAdd(&sumh[tid], csum[tid]);
}

// ---------------- G5 gram (CIN=512): 128-wide tiles + fused column sums ----------------
// 16 ordered 128x128 tile-pairs x 32 chunks (grid 512). ~235 MB L3 traffic vs ~950 MB
// for 64-wide tiles. Diag blocks accumulate column sums during staging (colsum<512>
// eliminated). 4 waves; wave w owns output row-tile mt=w, nt looped (acc 4x16 f32).
__global__ __launch_bounds__(256) void gram5_kernel(const bf16* __restrict__ H,
                                                    float* __restrict__ G,
                                                    float* __restrict__ sumh){
  __shared__ short HTa[128*68];
  __shared__ short HTb[128*68];
  __shared__ float csum[128];
  int blk = blockIdx.x;
  int pair = blk & 15;
  int chunk = blk >> 4;            // 0..31
  int tr = pair >> 2, tc = pair & 3;
  bool diag = (tr == tc);
  int tid = threadIdx.x, lane = tid & 63, w = tid >> 6;   // 4 waves
  if (tid < 128) csum[tid] = 0.f;
  int rpc = BN / 32;               // 1024
  int r0 = chunk*rpc;
  int pl = lane & 31, ko = (lane>>5)*8, rbase = 4*(lane>>5);
  int mt = w;
  int arow = (mt*32 + pl)*68;
  floatx16 acc[4];
  #pragma unroll
  for (int nt=0;nt<4;++nt)
    #pragma unroll
    for (int q=0;q<16;++q) acc[nt][q]=0.f;
  int c0s = (tid & 15)*8;          // staged cols (within 128), invariant across s
  float cs[8];
  #pragma unroll
  for (int j=0;j<8;++j) cs[j]=0.f;
  const short* Bbase = diag ? HTa : HTb;
  for (int rb=r0; rb<r0+rpc; rb+=64){
    #pragma unroll
    for (int s=0;s<4;++s){
      int e = tid + s*256;
      int row = e >> 4;
      U4b va; va.q = *(const uint4*)&H[(size_t)(rb+row)*512 + tr*128 + c0s];
      #pragma unroll
      for (int j=0;j<8;++j) HTa[(c0s+j)*68 + row] = (short)va.s[j];
      if (diag){
        #pragma unroll
        for (int j=0;j<8;++j) cs[j] += bits2f(va.s[j]);
      } else {
        U4b vb; vb.q = *(const uint4*)&H[(size_t)(rb+row)*512 + tc*128 + c0s];
        #pragma unroll
        for (int j=0;j<8;++j) HTb[(c0s+j)*68 + row] = (short)vb.s[j];
      }
    }
    __syncthreads();
    #pragma unroll
    for (int kc=0;kc<64;kc+=16){
      Frag a;
      const short* ap = &HTa[arow + kc + ko];
      a.u2[0] = *(const uint2*)ap;  a.u2[1] = *(const uint2*)(ap+4);
      #pragma unroll
      for (int nt=0;nt<4;++nt){
        Frag b;
        const short* bp = &Bbase[(nt*32 + pl)*68 + kc + ko];
        b.u2[0] = *(const uint2*)bp;  b.u2[1] = *(const uint2*)(bp+4);
        acc[nt] = __builtin_amdgcn_mfma_f32_32x32x16_bf16(a.v, b.v, acc[nt], 0, 0, 0);
      }
    }
    __syncthreads();
  }
  #pragma unroll
  for (int nt=0;nt<4;++nt){
    #pragma unroll
    for (int r=0;r<16;++r){
      int row = (r&3) + 8*(r>>2) + rbase;
      atomicAdd(&G[(size_t)(tr*128 + mt*32 + row)*512 + tc*128 + nt*32 + pl], acc[nt][r]);
    }
  }
  if (diag){
    #pragma unroll
    for (int j=0;j<8;++j) atomicAdd(&csum[c0s+j], cs[j]);
    __syncthreads();
    if (tid < 128) atomicAdd(&sumh[tr*128 + tid], csum[tid]);
  }
}

// ---------------- P = G @ W ----------------
__global__ void kP_kernel(const float* __restrict__ G, const float* __restrict__ Wf,
                          float* __restrict__ P, int Cin, int Cout){
  int id = blockIdx.x*256 + threadIdx.x;
  if (id >= Cin*Cout) return;
  int i = id / Cout, j = id - i*Cout;
  float s = 0.f;
  for (int k=0;k<Cin;++k) s = fmaf(G[(size_t)i*Cin+k], Wf[(size_t)k*Cout+j], s);
  P[id] = s;
}

// ---------------- scale/shift from Gram-derived BN stats ----------------
__global__ void kFinal_kernel(const float* __restrict__ P, const float* __restrict__ sumh,
                              const float* __restrict__ Wf, const float* __restrict__ g,
                              const float* __restrict__ bb, float* __restrict__ scale,
                              float* __restrict__ shift, int Cin, int Cout, float invM){
  int j = blockIdx.x*256 + threadIdx.x;
  if (j >= Cout) return;
  float mean=0.f, e2=0.f;
  for (int i=0;i<Cin;++i){
    float w = Wf[(size_t)i*Cout + j];
    mean = fmaf(sumh[i], w, mean);
    e2   = fmaf(w, P[(size_t)i*Cout + j], e2);
  }
  mean *= invM; e2 *= invM;
  float var = e2 - mean*mean;
  float inv = rsqrtf(var + EPSf);
  float sc = g[j]*inv;
  scale[j]=sc;
  shift[j]=bb[j] - mean*sc;
}

// ---------------- layer-2 stats ----------------
__global__ __launch_bounds__(512) void stats2_kernel(const float* __restrict__ x,
    const int* __restrict__ idx, const float* __restrict__ W1f,
    const float* __restrict__ sc1v, const float* __restrict__ sh1v,
    float* __restrict__ G2, float* __restrict__ sum2){
  __shared__ float W1s[6][64];
  __shared__ float fsh[64][8];
  __shared__ short H1T[64*68];
  __shared__ float csum[64];
  int tid = threadIdx.x, lane = tid & 63, w = tid >> 6;   // 8 waves
  if (tid < 384) W1s[tid>>6][tid&63] = W1f[tid];
  if (tid < 64) csum[tid] = 0.f;
  int rp = tid >> 4, cq = tid & 15, c0 = cq*4;
  float sca[4], sha[4];
  #pragma unroll
  for (int k=0;k<4;++k){ sca[k]=sc1v[c0+k]; sha[k]=sh1v[c0+k]; }
  int mt = w & 1, nt = (w>>1) & 1, kh = w >> 2;
  int arow = (mt*32 + (lane&31))*68;
  int brow = (nt*32 + (lane&31))*68;
  int ko = (lane>>5)*8;
  floatx16 acc;
  #pragma unroll
  for (int q=0;q<16;++q) acc[q]=0.f;
  float cs[4] = {0.f,0.f,0.f,0.f};
  int rpc = Mrows / gridDim.x;
  int r0 = blockIdx.x * rpc;
  __syncthreads();
  for (int rb=r0; rb<r0+rpc; rb+=64){
    {
      int r = tid>>3, e = tid&7;
      if (e < 6){
        int grow = rb + r;
        int bn = grow / Kk;
        int b = bn >> 12, n = bn & 4095;
        int j = idx[grow];
        const float* xb = x + b*3*Nn;
        fsh[r][e] = (e<3) ? xb[e*Nn + j] : xb[(e-3)*Nn + n];
      }
    }
    __syncthreads();
    {
      float y0[4]={0,0,0,0}, y1[4]={0,0,0,0};
      int ra = rp*2, rbw = rp*2+1;
      #pragma unroll
      for (int i=0;i<6;++i){
        float fa = fsh[ra][i], fb = fsh[rbw][i];
        float4 wv = *(const float4*)&W1s[i][c0];
        y0[0]=fmaf(fa,wv.x,y0[0]); y0[1]=fmaf(fa,wv.y,y0[1]);
        y0[2]=fmaf(fa,wv.z,y0[2]); y0[3]=fmaf(fa,wv.w,y0[3]);
        y1[0]=fmaf(fb,wv.x,y1[0]); y1[1]=fmaf(fb,wv.y,y1[1]);
        y1[2]=fmaf(fb,wv.z,y1[2]); y1[3]=fmaf(fb,wv.w,y1[3]);
      }
      #pragma unroll
      for (int k=0;k<4;++k){
        float va = fmaxf(fmaf(y0[k],sca[k],sha[k]),0.f);
        float vb = fmaxf(fmaf(y1[k],sca[k],sha[k]),0.f);
        cs[k] += va; cs[k] += vb;
        unsigned int pk = f2bu(va) | ((unsigned)f2bu(vb)<<16);
        *(unsigned int*)&H1T[(c0+k)*68 + ra] = pk;
      }
    }
    __syncthreads();
    {
      int kc = kh*32;
      #pragma unroll
      for (int s=0;s<2;++s){
        Frag a, b;
        const short* ap = &H1T[arow + kc + s*16 + ko];
        const short* bp = &H1T[brow + kc + s*16 + ko];
        a.u2[0] = *(const uint2*)ap;  a.u2[1] = *(const uint2*)(ap+4);
        b.u2[0] = *(const uint2*)bp;  b.u2[1] = *(const uint2*)(bp+4);
        acc = __builtin_amdgcn_mfma_f32_32x32x16_bf16(a.v, b.v, acc, 0, 0, 0);
      }
    }
    __syncthreads();
  }
  int col = lane & 31, rbase = 4*(lane>>5);
  #pragma unroll
  for (int r=0;r<16;++r){
    int row = (r&3) + 8*(r>>2) + rbase;
    atomicAdd(&G2[(size_t)(mt*32+row)*64 + nt*32+col], acc[r]);
  }
  #pragma unroll
  for (int k=0;k<4;++k) atomicAdd(&csum[c0+k], cs[k]);
  __syncthreads();
  if (tid < 64) atomicAdd(&sum2[tid], csum[tid]);
}

// ---------------- fused layers 1+2 ----------------
__global__ __launch_bounds__(64) void fl12_kernel(const float* __restrict__ x,
    const int* __restrict__ idx, const float* __restrict__ W1f,
    const float* __restrict__ sc1v, const float* __restrict__ sh1v,
    const float* __restrict__ W2f, const float* __restrict__ sc2v,
    const float* __restrict__ sh2v, bf16* __restrict__ H2, bf16* __restrict__ cat){
  __shared__ float fsh[Kk][6];
  __shared__ float h1[Kk][64];
  __shared__ float mm[4][64];
  int bn = blockIdx.x, b = bn>>12, n = bn & 4095;
  int tid = threadIdx.x;
  if (tid < Kk){
    int j = idx[(size_t)bn*Kk + tid];
    const float* xb = x + b*3*Nn;
    fsh[tid][0]=xb[j]; fsh[tid][1]=xb[Nn+j]; fsh[tid][2]=xb[2*Nn+j];
    fsh[tid][3]=xb[n]; fsh[tid][4]=xb[Nn+n]; fsh[tid][5]=xb[2*Nn+n];
  }
  __syncthreads();
  {
    float sc=sc1v[tid], sh=sh1v[tid];
    float w[6];
    #pragma unroll
    for (int i=0;i<6;++i) w[i]=W1f[i*64+tid];
    float mx = 0.f;
    #pragma unroll
    for (int r=0;r<Kk;++r){
      float y=0.f;
      #pragma unroll
      for (int i=0;i<6;++i) y = fmaf(fsh[r][i], w[i], y);
      float v = fmaxf(fmaf(y,sc,sh),0.f);
      h1[r][tid]=v;
      mx = fmaxf(mx,v);
    }
    cat[(size_t)bn*512 + tid] = f2b(mx);
  }
  __syncthreads();
  int q = tid >> 4, c0 = (tid & 15)*4;
  float acc[5][4]={};
  for (int i0=0;i0<64;i0+=4){
    float hv[5][4];
    #pragma unroll
    for (int l=0;l<5;++l){
      float4 t4 = *(const float4*)&h1[q*5+l][i0];
      hv[l][0]=t4.x; hv[l][1]=t4.y; hv[l][2]=t4.z; hv[l][3]=t4.w;
    }
    #pragma unroll
    for (int ii=0;ii<4;++ii){
      const float* wp = W2f + (i0+ii)*64 + c0;
      float w0=wp[0],w1=wp[1],w2=wp[2],w3=wp[3];
      #pragma unroll
      for (int l=0;l<5;++l){
        float hvv=hv[l][ii];
        acc[l][0]=fmaf(hvv,w0,acc[l][0]);
        acc[l][1]=fmaf(hvv,w1,acc[l][1]);
        acc[l][2]=fmaf(hvv,w2,acc[l][2]);
        acc[l][3]=fmaf(hvv,w3,acc[l][3]);
      }
    }
  }
  float sc[4],sh[4];
  #pragma unroll
  for (int cb=0;cb<4;++cb){ sc[cb]=sc2v[c0+cb]; sh[cb]=sh2v[c0+cb]; }
  float mx[4]={0,0,0,0};
  #pragma unroll
  for (int l=0;l<5;++l){
    unsigned short us[4];
    #pragma unroll
    for (int cb=0;cb<4;++cb){
      float v=fmaxf(fmaf(acc[l][cb],sc[cb],sh[cb]),0.f);
      mx[cb]=fmaxf(mx[cb],v);
      us[cb]=f2bu(v);
    }
    uint2 v2; v2.x = us[0]|((unsigned)us[1]<<16); v2.y=us[2]|((unsigned)us[3]<<16);
    *(uint2*)(H2 + ((size_t)bn*Kk + q*5+l)*64 + c0) = v2;
  }
  #pragma unroll
  for (int cb=0;cb<4;++cb) mm[q][c0+cb]=mx[cb];
  __syncthreads();
  {
    float M0 = fmaxf(fmaxf(mm[0][tid],mm[1][tid]),fmaxf(mm[2][tid],mm[3][tid]));
    cat[(size_t)bn*512 + 64 + tid] = f2b(M0);
  }
}

// ---------------- layer-4 stats: MFMA produce + MFMA Gram ----------------
__global__ __launch_bounds__(512) void stats4_kernel(const bf16* __restrict__ H2,
    const bf16* __restrict__ W3T, const float* __restrict__ sc3v, const float* __restrict__ sh3v,
    float* __restrict__ G4, float* __restrict__ sum4){
  __shared__ short h2s[64*68];
  __shared__ short H3T[128*68];
  __shared__ float csum[128];
  int tid = threadIdx.x, lane = tid & 63, w = tid >> 6;   // 8 waves
  if (tid < 128) csum[tid] = 0.f;
  int trow = tid >> 3, tc0 = (tid & 7)*8;
  int pl  = lane & 31;
  int ko  = (lane >> 5)*8;
  int pmt = w >> 2, pnt = w & 3;
  int parow = (pmt*32 + pl)*68;
  int pcol  = pnt*32 + pl;
  float psc = sc3v[pcol], psh = sh3v[pcol];
  int prbase = 4*(lane>>5);
  FragQ bfr[4];
  #pragma unroll
  for (int kq=0;kq<4;++kq)
    bfr[kq].q = *(const uint4*)&W3T[(size_t)pcol*64 + kq*16 + ko];
  int gmt = w>>1, gnt0 = (w&1)*2, gnt1 = gnt0+1;
  int garow  = (gmt*32 + pl)*68;
  int gbrow0 = (gnt0*32 + pl)*68;
  int gbrow1 = (gnt1*32 + pl)*68;
  floatx16 acc0, acc1;
  #pragma unroll
  for (int q=0;q<16;++q){ acc0[q]=0.f; acc1[q]=0.f; }
  float cs = 0.f;
  int rpc = Mrows / gridDim.x;
  int r0 = blockIdx.x * rpc;
  uint4 hreg = *(const uint4*)&H2[(size_t)(r0+trow)*64 + tc0];
  for (int rb=r0; rb<r0+rpc; rb+=64){
    {
      short* dst = &h2s[trow*68 + tc0];
      *(uint2*)dst       = make_uint2(hreg.x, hreg.y);
      *(uint2*)(dst + 4) = make_uint2(hreg.z, hreg.w);
    }
    if (rb + 64 < r0 + rpc)
      hreg = *(const uint4*)&H2[(size_t)(rb+64+trow)*64 + tc0];
    __syncthreads();
    {
      floatx16 pacc;
      #pragma unroll
      for (int q=0;q<16;++q) pacc[q]=0.f;
      #pragma unroll
      for (int kq=0;kq<4;++kq){
        Frag a;
        const short* ap = &h2s[parow + kq*16 + ko];
        a.u2[0] = *(const uint2*)ap;  a.u2[1] = *(const uint2*)(ap+4);
        pacc = __builtin_amdgcn_mfma_f32_32x32x16_bf16(a.v, bfr[kq].v, pacc, 0, 0, 0);
      }
      #pragma unroll
      for (int g=0; g<4; ++g){
        unsigned short p[4];
        #pragma unroll
        for (int r=0;r<4;++r){
          float v = fmaxf(fmaf(pacc[g*4+r], psc, psh), 0.f);
          cs += v;
          p[r] = f2bu(v);
        }
        uint2 pk; pk.x = p[0] | ((unsigned)p[1]<<16); pk.y = p[2] | ((unsigned)p[3]<<16);
        *(uint2*)&H3T[pcol*68 + pmt*32 + 8*g + prbase] = pk;
      }
    }
    __syncthreads();
    #pragma unroll
    for (int kc=0;kc<64;kc+=16){
      Frag a, b0, b1;
      const short* ap  = &H3T[garow  + kc + ko];
      const short* bp0 = &H3T[gbrow0 + kc + ko];
      const short* bp1 = &H3T[gbrow1 + kc + ko];
      a.u2[0]  = *(const uint2*)ap;   a.u2[1]  = *(const uint2*)(ap+4);
      b0.u2[0] = *(const uint2*)bp0;  b0.u2[1] = *(const uint2*)(bp0+4);
      b1.u2[0] = *(const uint2*)bp1;  b1.u2[1] = *(const uint2*)(bp1+4);
      acc0 = __builtin_amdgcn_mfma_f32_32x32x16_bf16(a.v, b0.v, acc0, 0, 0, 0);
      acc1 = __builtin_amdgcn_mfma_f32_32x32x16_bf16(a.v, b1.v, acc1, 0, 0, 0);
    }
  }
  int col = pl;
  #pragma unroll
  for (int r=0;r<16;++r){
    int row = (r&3) + 8*(r>>2) + prbase;
    atomicAdd(&G4[(size_t)(gmt*32+row)*128 + gnt0*32+col], acc0[r]);
    atomicAdd(&G4[(size_t)(gmt*32+row)*128 + gnt1*32+col], acc1[r]);
  }
  atomicAdd(&csum[pcol], cs);
  __syncthreads();
  if (tid < 128) atomicAdd(&sum4[tid], csum[tid]);
}

// ---------------- fused layers 3+4: MFMA produce chain + col-owner maxpool ----------------
__global__ __launch_bounds__(512,4) void fl34_kernel(const bf16* __restrict__ H2,
    const bf16* __restrict__ W3T, const float* __restrict__ sc3v, const float* __restrict__ sh3v,
    const bf16* __restrict__ W4T, const float* __restrict__ sc4v, const float* __restrict__ sh4v,
    bf16* __restrict__ cat){
  __shared__ short h2s[64*68];             // 8.5 KB
  __shared__ short h3s[64*132];            // 16.5 KB
  __shared__ unsigned short h4s[64*256];   // 32 KB
  __shared__ unsigned short mx3u[16*128];  // 4 KB
  __shared__ unsigned short mx4u[16*256];  // 8 KB
  int tid = threadIdx.x, lane = tid & 63, w = tid >> 6;
  int pl = lane & 31;
  int ko = (lane >> 5)*8;
  int rbase = 4*(lane>>5);
  {
    unsigned* p4 = (unsigned*)mx4u;
    for (int u=tid; u<2048; u+=512) p4[u]=0u;
    unsigned* p3 = (unsigned*)mx3u;
    for (int u=tid; u<1024; u+=512) p3[u]=0u;
  }
  int mt3 = w >> 2, ct3 = w & 3;
  int c3 = ct3*32 + pl;
  float sc3 = sc3v[c3], sh3 = sh3v[c3];
  int a3row = (mt3*32 + pl)*68;
  int c4 = w*32 + pl;
  float sc4 = sc4v[c4], sh4 = sh4v[c4];
  int trow = tid >> 3, tc0 = (tid & 7)*8;
  int r0 = blockIdx.x * 320;
  uint4 hreg = *(const uint4*)&H2[(size_t)(r0+trow)*64 + tc0];
  {
    short* dst = &h2s[trow*68 + tc0];
    *(uint2*)dst       = make_uint2(hreg.x, hreg.y);
    *(uint2*)(dst + 4) = make_uint2(hreg.z, hreg.w);
  }
  hreg = *(const uint4*)&H2[(size_t)(r0 + 64 + trow)*64 + tc0];
  __syncthreads();
  for (int t=0; t<5; ++t){
    {
      floatx16 pa;
      #pragma unroll
      for (int q=0;q<16;++q) pa[q]=0.f;
      #pragma unroll
      for (int kq=0;kq<4;++kq){
        Frag a; FragQ b;
        const short* ap = &h2s[a3row + kq*16 + ko];
        a.u2[0] = *(const uint2*)ap;  a.u2[1] = *(const uint2*)(ap+4);
        b.q = *(const uint4*)&W3T[(size_t)c3*64 + kq*16 + ko];
        pa = __builtin_amdgcn_mfma_f32_32x32x16_bf16(a.v, b.v, pa, 0, 0, 0);
      }
      #pragma unroll
      for (int r=0;r<16;++r){
        int m = mt3*32 + (r&3) + 8*(r>>2) + rbase;
        float v = fmaxf(fmaf(pa[r], sc3, sh3), 0.f);
        h3s[m*132 + c3] = (short)f2bu(v);
      }
    }
    __syncthreads();
    #pragma unroll
    for (int mt4=0; mt4<2; ++mt4){
      floatx16 acc;
      #pragma unroll
      for (int q=0;q<16;++q) acc[q]=0.f;
      int a4row = (mt4*32 + pl)*132;
      #pragma unroll
      for (int kq=0;kq<8;++kq){
        Frag a; FragQ b;
        const short* ap = &h3s[a4row + kq*16 + ko];
        a.u2[0] = *(const uint2*)ap;  a.u2[1] = *(const uint2*)(ap+4);
        b.q = *(const uint4*)&W4T[(size_t)c4*128 + kq*16 + ko];
        acc = __builtin_amdgcn_mfma_f32_32x32x16_bf16(a.v, b.v, acc, 0, 0, 0);
      }
      #pragma unroll
      for (int r=0;r<16;++r){
        int m = mt4*32 + (r&3) + 8*(r>>2) + rbase;
        float v = fmaxf(fmaf(acc[r], sc4, sh4), 0.f);
        h4s[m*256 + c4] = f2bu(v);
      }
    }
    __syncthreads();
    if (t < 4){
      short* dst = &h2s[trow*68 + tc0];
      *(uint2*)dst       = make_uint2(hreg.x, hreg.y);
      *(uint2*)(dst + 4) = make_uint2(hreg.z, hreg.w);
      if (t < 3) hreg = *(const uint4*)&H2[(size_t)(r0 + (t+2)*64 + trow)*64 + tc0];
    }
    {
      int lr0 = t*64;
      if (tid < 256){
        int c = tid;
        int p = lr0/20;
        int nb = (p+1)*20 - lr0;
        unsigned ml = 0;
        for (int r=0;r<64;++r){
          unsigned v = h4s[r*256 + c];
          ml = v > ml ? v : ml;
          if (--nb == 0){
            unsigned short* mp = &mx4u[p*256 + c];
            unsigned cur = *mp;
            if (ml > cur) *mp = (unsigned short)ml;
            ml = 0; ++p; nb = 20;
          }
        }
        if (nb != 20){
          unsigned short* mp = &mx4u[p*256 + c];
          unsigned cur = *mp;
          if (ml > cur) *mp = (unsigned short)ml;
        }
      } else if (tid < 384){
        int c = tid - 256;
        int p = lr0/20;
        int nb = (p+1)*20 - lr0;
        unsigned ml = 0;
        for (int r=0;r<64;++r){
          unsigned v = (unsigned)(unsigned short)h3s[r*132 + c];
          ml = v > ml ? v : ml;
          if (--nb == 0){
            unsigned short* mp = &mx3u[p*128 + c];
            unsigned cur = *mp;
            if (ml > cur) *mp = (unsigned short)ml;
            ml = 0; ++p; nb = 20;
          }
        }
        if (nb != 20){
          unsigned short* mp = &mx3u[p*128 + c];
          unsigned cur = *mp;
          if (ml > cur) *mp = (unsigned short)ml;
        }
      }
    }
    __syncthreads();
  }
  int bn0 = blockIdx.x*16;
  {
    int p = tid >> 5, c0 = (tid & 31)*8;
    uint4 v = *(const uint4*)&mx4u[p*256 + c0];
    *(uint4*)&cat[(size_t)(bn0+p)*512 + 256 + c0] = v;
  }
  if (tid < 256){
    int p = tid >> 4, c0 = (tid & 15)*8;
    uint4 v = *(const uint4*)&mx3u[p*128 + c0];
    *(uint4*)&cat[(size_t)(bn0+p)*512 + 128 + c0] = v;
  }
}

// ---------------- layer 5: MFMA GEMM + LDS-staged coalesced epilogue ----------------
__global__ __launch_bounds__(512) void l5_kernel(const bf16* __restrict__ cat,
                                                const bf16* __restrict__ W5T,
                                                const float* __restrict__ scale,
                                                const float* __restrict__ shift,
                                                float* __restrict__ out){
  __shared__ short cs[64*68];
  __shared__ float ob[64*129];
  int tid = threadIdx.x, lane = tid & 63, w = tid >> 6;
  int pl = lane & 31;
  int ko = (lane >> 5)*8;
  int rbase = 4*(lane>>5);
  int mt = w & 1, ntb = w >> 1;          // nt = ntb + 4*s, s=0..3
  int arow = (mt*32 + pl)*68;
  int trow = tid >> 3, tc0 = (tid & 7)*8;
  int r0 = blockIdx.x*64;
  floatx16 acc[4];
  #pragma unroll
  for (int s=0;s<4;++s)
    #pragma unroll
    for (int q=0;q<16;++q) acc[s][q]=0.f;
  const bf16* arow_g = cat + (size_t)(r0+trow)*512 + tc0;
  uint4 hreg = *(const uint4*)arow_g;
  for (int kc8=0; kc8<8; ++kc8){
    {
      short* dst = &cs[trow*68 + tc0];
      *(uint2*)dst       = make_uint2(hreg.x, hreg.y);
      *(uint2*)(dst + 4) = make_uint2(hreg.z, hreg.w);
    }
    if (kc8 < 7) hreg = *(const uint4*)(arow_g + (kc8+1)*64);
    __syncthreads();
    #pragma unroll
    for (int kq=0;kq<4;++kq){
      Frag a;
      const short* ap = &cs[arow + kq*16 + ko];
      a.u2[0] = *(const uint2*)ap;  a.u2[1] = *(const uint2*)(ap+4);
      #pragma unroll
      for (int s=0;s<4;++s){
        FragQ b;
        int col = (ntb + 4*s)*32 + pl;
        b.q = *(const uint4*)&W5T[(size_t)col*512 + kc8*64 + kq*16 + ko];
        acc[s] = __builtin_amdgcn_mfma_f32_32x32x16_bf16(a.v, b.v, acc[s], 0, 0, 0);
      }
    }
    __syncthreads();
  }
  int b = r0 >> 12, n0 = r0 & 4095;
  int colL = ntb*32 + pl;                // 0..127 within chunk
  int colc = tid >> 2, sub = tid & 3;    // writer mapping: 4 threads per col
  for (int s=0;s<4;++s){
    float sc = scale[128*s + colL], sh = shift[128*s + colL];
    #pragma unroll
    for (int q=0;q<16;++q){
      int m = mt*32 + (q&3) + 8*(q>>2) + rbase;
      ob[m*129 + colL] = fmaxf(fmaf(acc[s][q], sc, sh), 0.f);
    }
    __syncthreads();
    float* op = out + ((size_t)b*512 + 128*s + colc)*4096 + n0 + sub*16;
    #pragma unroll
    for (int j=0;j<4;++j){
      int rr = sub*16 + j*4;
      float4 v = make_float4(ob[(rr+0)*129 + colc], ob[(rr+1)*129 + colc],
                             ob[(rr+2)*129 + colc], ob[(rr+3)*129 + colc]);
      *(float4*)(op + j*4) = v;
    }
    __syncthreads();
  }
}

extern "C" void kernel_launch(void* const* d_in, const int* in_sizes, int n_in,
                              void* d_out, int out_size, void* d_ws, size_t ws_size,
                              hipStream_t stream){
  const float* x   = (const float*)d_in[0];
  const float* W1f = (const float*)d_in[1];
  const float* W2f = (const float*)d_in[2];
  const float* W3f = (const float*)d_in[3];
  const float* W4f = (const float*)d_in[4];
  const float* W5f = (const float*)d_in[5];
  const float* g1=(const float*)d_in[6],  *b1=(const float*)d_in[7];
  const float* g2=(const float*)d_in[8],  *b2=(const float*)d_in[9];
  const float* g3=(const float*)d_in[10], *b3=(const float*)d_in[11];
  const float* g4=(const float*)d_in[12], *b4=(const float*)d_in[13];
  const float* g5=(const float*)d_in[14], *b5=(const float*)d_in[15];
  float* out = (float*)d_out;

  char* w = (char*)d_ws;
  size_t off = 0;
  auto alloc = [&](size_t bytes)->void*{
    void* p = w + off;
    off = (off + bytes + 255) & ~(size_t)255;
    return p;
  };

  int*  idxb = (int*) alloc((size_t)BN*Kk*4);
  bf16* H2   = (bf16*)alloc((size_t)Mrows*64*2);
  bf16* catb = (bf16*)alloc((size_t)BN*512*2);
  bf16* W3T  = (bf16*)alloc((size_t)128*64*2);
  bf16* W4T  = (bf16*)alloc((size_t)256*128*2);
  bf16* W5T  = (bf16*)alloc((size_t)512*512*2);
  float* pv  = (float*)H2;
  int*   pib = (int*)((char*)H2 + (size_t)BN*16*Kk*4);

  size_t statsStart = off;
  float* partf=(float*)alloc(256*48*4);
  float* Gf=(float*)alloc(36*4);
  float* sumf=(float*)alloc(8*4);
  float* G2=(float*)alloc(4096*4);   float* sum2=(float*)alloc(64*4);
  float* G3=(float*)alloc(4096*4);   float* sum3=(float*)alloc(64*4);
  float* G4=(float*)alloc(16384*4);  float* sum4=(float*)alloc(128*4);
  float* G5=(float*)alloc(262144*4); float* sum5=(float*)alloc(512*4);
  float* P1=(float*)alloc(384*4);
  float* P2=(float*)alloc(4096*4);
  float* P3=(float*)alloc(8192*4);
  float* P4=(float*)alloc(32768*4);
  float* P5=(float*)alloc(262144*4);
  float* sc1=(float*)alloc(64*4);   float* sh1=(float*)alloc(64*4);
  float* sc2=(float*)alloc(64*4);   float* sh2=(float*)alloc(64*4);
  float* sc3=(float*)alloc(128*4);  float* sh3=(float*)alloc(128*4);
  float* sc4=(float*)alloc(256*4);  float* sh4=(float*)alloc(256*4);
  float* sc5=(float*)alloc(512*4);  float* sh5=(float*)alloc(512*4);
  size_t statsEnd = off;

  int statsFloats = (int)((statsEnd - statsStart)/4);
  zero_kernel<<<(statsFloats+255)/256,256,0,stream>>>((float*)(w+statsStart), statsFloats);
  w3t_kernel<<<32,256,0,stream>>>(W3f, W3T);
  w4t_kernel<<<128,256,0,stream>>>(W4f, W4T);
  w5t_kernel<<<1024,256,0,stream>>>(W5f, W5T);

  knnA_kernel<<<2048,256,0,stream>>>(x, pv, pib);
  knnB_kernel<<<BN/256,256,0,stream>>>(pv, pib, idxb);

  const float invM  = 1.0f/(float)Mrows;
  const float invM5 = 1.0f/(float)BN;

  gramf_kernel<<<256,256,0,stream>>>(x, idxb, partf);
  reducef_kernel<<<1,64,0,stream>>>(partf, Gf, sumf);
  kP_kernel<<<2,256,0,stream>>>(Gf, W1f, P1, 6, 64);
  kFinal_kernel<<<1,256,0,stream>>>(P1, sumf, W1f, g1, b1, sc1, sh1, 6, 64, invM);

  stats2_kernel<<<512,512,0,stream>>>(x, idxb, W1f, sc1, sh1, G2, sum2);
  kP_kernel<<<16,256,0,stream>>>(G2, W2f, P2, 64, 64);
  kFinal_kernel<<<1,256,0,stream>>>(P2, sum2, W2f, g2, b2, sc2, sh2, 64, 64, invM);

  fl12_kernel<<<BN,64,0,stream>>>(x, idxb, W1f, sc1, sh1, W2f, sc2, sh2, H2, catb);

  gram3_kernel<<<512,256,0,stream>>>(H2, Mrows, G3, sum3);
  kP_kernel<<<32,256,0,stream>>>(G3, W3f, P3, 64, 128);
  kFinal_kernel<<<1,256,0,stream>>>(P3, sum3, W3f, g3, b3, sc3, sh3, 64, 128, invM);

  stats4_kernel<<<512,512,0,stream>>>(H2, W3T, sc3, sh3, G4, sum4);
  kP_kernel<<<128,256,0,stream>>>(G4, W4f, P4, 128, 256);
  kFinal_kernel<<<1,256,0,stream>>>(P4, sum4, W4f, g4, b4, sc4, sh4, 128, 256, invM);

  fl34_kernel<<<Mrows/320,512,0,stream>>>(H2, W3T, sc3, sh3, W4T, sc4, sh4, catb);

  gram5_kernel<<<512,256,0,stream>>>(catb, G5, sum5);
  kP_kernel<<<1024,256,0,stream>>>(G5, W5f, P5, 512, 512);
  kFinal_kernel<<<2,256,0,stream>>>(P5, sum5, W5f, g5, b5, sc5, sh5, 512, 512, invM5);
  l5_kernel<<<BN/64,512,0,stream>>>(catb, W5T, sc5, sh5, out);
}

// Round 10
// 1329.134 us; speedup vs baseline: 1.1719x; 1.0416x over previous
//
#include <hip/hip_runtime.h>
#include <hip/hip_bf16.h>
#include <cfloat>

using bf16 = __hip_bfloat16;

typedef short short8 __attribute__((ext_vector_type(8)));
typedef float floatx16 __attribute__((ext_vector_type(16)));
union Frag { short8 v; uint2 u2[2]; };
union FragQ { short8 v; uint4 q; uint2 u2[2]; };
union U4b { uint4 q; unsigned short s[8]; };

constexpr int Bb = 8, Nn = 4096, Kk = 20;
constexpr int BN = Bb * Nn;                     // 32768
constexpr int Mrows = BN * Kk;                  // 655360
constexpr float EPSf = 1e-5f;

static __device__ __forceinline__ float b2f(bf16 v){ return __bfloat162float(v); }
static __device__ __forceinline__ bf16 f2b(float v){ return __float2bfloat16(v); }
static __device__ __forceinline__ unsigned short f2bu(float v){
  union { bf16 b; unsigned short u; } cv; cv.b = __float2bfloat16(v); return cv.u;
}
static __device__ __forceinline__ float bits2f(unsigned short u){
  union { unsigned int i; float f; } c; c.i = ((unsigned)u)<<16; return c.f;
}

// ---------------- zero workspace region ----------------
__global__ void zero_kernel(float* __restrict__ p, int n){
  int i = blockIdx.x*256 + threadIdx.x;
  if (i < n) p[i] = 0.f;
}

// ---------------- W3^T bf16 pack ----------------
__global__ void w3t_kernel(const float* __restrict__ W3f, bf16* __restrict__ W3T){
  int id = blockIdx.x*256 + threadIdx.x;   // 128*64 = 8192 elems
  if (id >= 128*64) return;
  int n = id >> 6, k = id & 63;
  W3T[id] = f2b(W3f[(size_t)k*128 + n]);
}

// ---------------- W4^T bf16 pack ----------------
__global__ void w4t_kernel(const float* __restrict__ W4f, bf16* __restrict__ W4T){
  int id = blockIdx.x*256 + threadIdx.x;   // 128*256 = 32768 elems
  if (id >= 128*256) return;
  int k = id >> 8, c = id & 255;           // coalesced read of W4f
  W4T[(size_t)c*128 + k] = f2b(W4f[id]);
}

// ---------------- W5^T bf16 pack ----------------
__global__ void w5t_kernel(const float* __restrict__ W5f, bf16* __restrict__ W5T){
  int id = blockIdx.x*256 + threadIdx.x;   // 512*512 = 262144 elems
  if (id >= 512*512) return;
  int k = id >> 9, c = id & 511;           // coalesced read of W5f
  W5T[(size_t)c*512 + k] = f2b(W5f[id]);
}

// ---------------- KNN phase A v7: v5 shape (best measured) + bank-spread list ----
// 8 stripes of 512 candidates, grid 1024 (3 blocks/CU). v6's 256-cand stripes
// REGRESSED: per-thread ops halved but threads doubled => total ops +13% (the 39-op
// network amortizes per-stripe). Reverted. Fix kept: lst stride 66 shorts (132B;
// 33=1 mod 32 => thread t's list base lands on bank t, was all-bank-0 at stride 64
// => 9.8M conflicts). thr = 20th-largest of 32 group-maxes (groups of 16), fast-fma
// nd with margin; E[admits]~31, CAP=64 (6.2 sigma; exact fallback ~never fires).
// Final selection recomputes nd with the EXACT contract-off formula.
__global__ __launch_bounds__(256) void knnA_kernel(const float* __restrict__ x,
                                                   float* __restrict__ pv, int* __restrict__ pi){
#pragma clang fp contract(off)
  __shared__ float4 p4[512];
  __shared__ unsigned short lst[256*66];
  int blk = blockIdx.x;
  int stripe = blk & 7;
  int chunk  = (blk >> 3) & 15;
  int b      = blk >> 7;
  const float* xb = x + b*3*Nn;
  int j0 = stripe*512;
  for (int u = threadIdx.x; u < 512; u += 256){
    int j = j0 + u;
    float a0 = xb[j];
    float a1 = xb[Nn + j];
    float a2 = xb[2*Nn + j];
    float s = a0*a0; s = s + a1*a1; s = s + a2*a2;
    p4[u] = make_float4(a0, a1, a2, s);
  }
  __syncthreads();
  int i = chunk*256 + threadIdx.x;
  float xi = xb[i], yi = xb[Nn+i], zi = xb[2*Nn+i];
  float ni = xi*xi; ni = ni + yi*yi; ni = ni + zi*zi;
  float mni = -ni;
  float xi2 = xi + xi, yi2 = yi + yi, zi2 = zi + zi;
  // ---- pass A: 32 group-maxes (groups of 16, fast nd) -> top-20 min/max network ----
  float tv[Kk];
  #pragma unroll
  for (int s=0;s<Kk;++s) tv[s] = -FLT_MAX;
  for (int g=0; g<32; ++g){
    float gm = -FLT_MAX;
    #pragma unroll
    for (int e=0;e<16;++e){
      float4 p = p4[g*16+e];
      float base = mni - p.w;
      float nd = fmaf(xi2, p.x, fmaf(yi2, p.y, fmaf(zi2, p.z, base)));
      gm = fmaxf(gm, nd);
    }
    #pragma unroll
    for (int s=Kk-1; s>=1; --s)
      tv[s] = fmaxf(tv[s], fminf(tv[s-1], gm));
    tv[0] = fmaxf(tv[0], gm);
  }
  float thr = tv[Kk-1];
  thr = thr - (fabsf(thr)*1e-5f + 1e-6f);   // margin >> fast-vs-exact fp discrepancy
  // ---- pass B: fast compare, collect u16 indices (ascending u => stable) ----
  unsigned short* ml = &lst[threadIdx.x*66];
  int cnt = 0;
  for (int u=0; u<512; ++u){
    float4 p = p4[u];
    float base = mni - p.w;
    float nd = fmaf(xi2, p.x, fmaf(yi2, p.y, fmaf(zi2, p.z, base)));
    if (nd >= thr && cnt < 64){ ml[cnt] = (unsigned short)u; ++cnt; }
  }
  // ---- final: EXACT (val,idx) insertion sort ----
  float av[Kk]; int ai[Kk];
  #pragma unroll
  for (int s=0;s<Kk;++s){ av[s] = -FLT_MAX; ai[s] = 0; }
  if (cnt >= 64){
    // exact fallback: full branchy scan (statistically never; correctness guarantee)
    for (int u=0; u<512; ++u){
      float4 p = p4[u];
      float dot = xi*p.x; dot = dot + yi*p.y; dot = dot + zi*p.z;
      float inner = -2.0f*dot;
      float nd = mni - inner; nd = nd - p.w;
      if (nd > av[Kk-1]){
        #pragma unroll
        for (int s=Kk-1; s>=1; --s){
          bool cs = nd > av[s];
          bool cp = nd > av[s-1];
          av[s] = cs ? (cp ? av[s-1] : nd) : av[s];
          ai[s] = cs ? (cp ? ai[s-1] : (j0+u)) : ai[s];
        }
        if (nd > av[0]){ av[0] = nd; ai[0] = j0+u; }
      }
    }
  } else {
    for (int t=0; t<cnt; ++t){
      int lj = ml[t];
      float4 p = p4[lj];
      float dot = xi*p.x; dot = dot + yi*p.y; dot = dot + zi*p.z;
      float inner = -2.0f*dot;
      float nd = mni - inner; nd = nd - p.w;
      if (nd > av[Kk-1]){
        #pragma unroll
        for (int s=Kk-1; s>=1; --s){
          bool cs = nd > av[s];
          bool cp = nd > av[s-1];
          av[s] = cs ? (cp ? av[s-1] : nd) : av[s];
          ai[s] = cs ? (cp ? ai[s-1] : (j0+lj)) : ai[s];
        }
        if (nd > av[0]){ av[0] = nd; ai[0] = j0+lj; }
      }
    }
  }
  long long base = ((long long)(b*Nn + i)*8 + stripe)*Kk;
  #pragma unroll
  for (int s=0;s<Kk;++s){ pv[base+s] = av[s]; pi[base+s] = ai[s]; }
}

// ---------------- KNN phase B: merge 8 stripes ----------------
__global__ __launch_bounds__(256) void knnB_kernel(const float* __restrict__ pv,
                                                   const int* __restrict__ pi,
                                                   int* __restrict__ idx){
  int p = blockIdx.x*256 + threadIdx.x;
  if (p >= BN) return;
  long long base = (long long)p*8*Kk;
  float av[Kk]; int ai[Kk];
  #pragma unroll
  for (int s=0;s<Kk;++s){ av[s]=pv[base+s]; ai[s]=pi[base+s]; }
  for (int t=Kk; t<8*Kk; ++t){
    float nd = pv[base+t]; int j = pi[base+t];
    if (nd > av[Kk-1]){
      #pragma unroll
      for (int s=Kk-1;s>=1;--s){
        bool cs = nd > av[s];
        bool cp = nd > av[s-1];
        av[s] = cs ? (cp?av[s-1]:nd) : av[s];
        ai[s] = cs ? (cp?ai[s-1]:j) : ai[s];
      }
      if (nd > av[0]){ av[0]=nd; ai[0]=j; }
    }
  }
  #pragma unroll
  for (int s=0;s<Kk;++s) idx[(long long)p*Kk+s] = ai[s];
}

// ---------------- layer-1 feature stats ----------------
__global__ __launch_bounds__(256) void gramf_kernel(const float* __restrict__ x,
                                                    const int* __restrict__ idx,
                                                    float* __restrict__ part){
  float acc[36]; float s6[6];
  #pragma unroll
  for (int a=0;a<36;++a) acc[a]=0.f;
  #pragma unroll
  for (int a=0;a<6;++a) s6[a]=0.f;
  for (long long row = blockIdx.x*256 + threadIdx.x; row < Mrows; row += (long long)gridDim.x*256){
    int bn = (int)(row / Kk);
    int b = bn >> 12, n = bn & 4095;
    int j = idx[row];
    const float* xb = x + b*3*Nn;
    float f[6];
    f[0]=xb[j];  f[1]=xb[Nn+j];  f[2]=xb[2*Nn+j];
    f[3]=xb[n];  f[4]=xb[Nn+n];  f[5]=xb[2*Nn+n];
    #pragma unroll
    for (int a=0;a<6;++a){
      s6[a] += f[a];
      #pragma unroll
      for (int c=0;c<6;++c) acc[a*6+c] = fmaf(f[a], f[c], acc[a*6+c]);
    }
  }
  __shared__ float red[256];
  for (int v=0; v<42; ++v){
    red[threadIdx.x] = (v<36)? acc[v] : s6[v-36];
    __syncthreads();
    for (int s=128; s>0; s>>=1){
      if (threadIdx.x < s) red[threadIdx.x] += red[threadIdx.x+s];
      __syncthreads();
    }
    if (threadIdx.x==0) part[blockIdx.x*48 + v] = red[0];
    __syncthreads();
  }
}

__global__ void reducef_kernel(const float* __restrict__ part, float* __restrict__ Gf,
                               float* __restrict__ sumf){
  int t = threadIdx.x;
  if (t < 42){
    float s = 0.f;
    for (int i=0;i<256;++i) s += part[i*48 + t];
    if (t<36) Gf[t]=s; else sumf[t-36]=s;
  }
}

// ---------------- G3 gram (CIN=64) with fused column sums ----------------
__global__ __launch_bounds__(256) void gram3_kernel(const bf16* __restrict__ H, int M,
                                                    float* __restrict__ G,
                                                    float* __restrict__ sumh){
  __shared__ short HTa[64*68];
  __shared__ float csum[64];
  int tid = threadIdx.x, lane = tid & 63, w = tid >> 6;
  if (tid < 64) csum[tid] = 0.f;
  int nchunks = gridDim.x;
  int rpc = M / nchunks;
  int r0 = blockIdx.x*rpc;
  int mt = w >> 1, nt = w & 1;
  floatx16 acc;
  #pragma unroll
  for (int q=0;q<16;++q) acc[q]=0.f;
  int arow = (mt*32 + (lane&31))*68;
  int brow = (nt*32 + (lane&31))*68;
  int ko = (lane>>5)*8;
  int c0s = (tid & 7)*8;          // staged cols, invariant across s
  float cs[8];
  #pragma unroll
  for (int j=0;j<8;++j) cs[j]=0.f;
  for (int rb=r0; rb<r0+rpc; rb+=64){
    #pragma unroll
    for (int s=0;s<2;++s){
      int e = tid + s*256;
      int row = e >> 3;
      U4b va; va.q = *(const uint4*)&H[(size_t)(rb+row)*64 + c0s];
      #pragma unroll
      for (int j=0;j<8;++j){
        HTa[(c0s+j)*68 + row] = (short)va.s[j];
        cs[j] += bits2f(va.s[j]);
      }
    }
    __syncthreads();
    #pragma unroll
    for (int kc=0;kc<64;kc+=16){
      Frag a, b;
      const short* ap = &HTa[arow + kc + ko];
      const short* bp = &HTa[brow + kc + ko];
      a.u2[0] = *(const uint2*)ap;  a.u2[1] = *(const uint2*)(ap+4);
      b.u2[0] = *(const uint2*)bp;  b.u2[1] = *(const uint2*)(bp+4);
      acc = __builtin_amdgcn_mfma_f32_32x32x16_bf16(a.v, b.v, acc, 0, 0, 0);
    }
    __syncthreads();
  }
  int col = lane & 31, rbase = 4*(lane>>5);
  #pragma unroll
  for (int r=0;r<16;++r){
    int row = (r&3) + 8*(r>>2) + rbase;
    atomicAdd(&G[(size_t)(mt*32 + row)*64 + nt*32 + col], acc[r]);
  }
  #pragma unroll
  for (int j=0;j<8;++j) atomicAdd(&csum[c0s+j], cs[j]);
  __syncthreads();
  if (tid < 64) atomicAdd(&sumh[tid], csum[tid]);
}

// ---------------- G5 gram (CIN=512): 128-wide tiles + fused column sums ----------------
__global__ __launch_bounds__(256) void gram5_kernel(const bf16* __restrict__ H,
                                                    float* __restrict__ G,
                                                    float* __restrict__ sumh){
  __shared__ short HTa[128*68];
  __shared__ short HTb[128*68];
  __shared__ float csum[128];
  int blk = blockIdx.x;
  int pair = blk & 15;
  int chunk = blk >> 4;            // 0..31
  int tr = pair >> 2, tc = pair & 3;
  bool diag = (tr == tc);
  int tid = threadIdx.x, lane = tid & 63, w = tid >> 6;   // 4 waves
  if (tid < 128) csum[tid] = 0.f;
  int rpc = BN / 32;               // 1024
  int r0 = chunk*rpc;
  int pl = lane & 31, ko = (lane>>5)*8, rbase = 4*(lane>>5);
  int mt = w;
  int arow = (mt*32 + pl)*68;
  floatx16 acc[4];
  #pragma unroll
  for (int nt=0;nt<4;++nt)
    #pragma unroll
    for (int q=0;q<16;++q) acc[nt][q]=0.f;
  int c0s = (tid & 15)*8;          // staged cols (within 128), invariant across s
  float cs[8];
  #pragma unroll
  for (int j=0;j<8;++j) cs[j]=0.f;
  const short* Bbase = diag ? HTa : HTb;
  for (int rb=r0; rb<r0+rpc; rb+=64){
    #pragma unroll
    for (int s=0;s<4;++s){
      int e = tid + s*256;
      int row = e >> 4;
      U4b va; va.q = *(const uint4*)&H[(size_t)(rb+row)*512 + tr*128 + c0s];
      #pragma unroll
      for (int j=0;j<8;++j) HTa[(c0s+j)*68 + row] = (short)va.s[j];
      if (diag){
        #pragma unroll
        for (int j=0;j<8;++j) cs[j] += bits2f(va.s[j]);
      } else {
        U4b vb; vb.q = *(const uint4*)&H[(size_t)(rb+row)*512 + tc*128 + c0s];
        #pragma unroll
        for (int j=0;j<8;++j) HTb[(c0s+j)*68 + row] = (short)vb.s[j];
      }
    }
    __syncthreads();
    #pragma unroll
    for (int kc=0;kc<64;kc+=16){
      Frag a;
      const short* ap = &HTa[arow + kc + ko];
      a.u2[0] = *(const uint2*)ap;  a.u2[1] = *(const uint2*)(ap+4);
      #pragma unroll
      for (int nt=0;nt<4;++nt){
        Frag b;
        const short* bp = &Bbase[(nt*32 + pl)*68 + kc + ko];
        b.u2[0] = *(const uint2*)bp;  b.u2[1] = *(const uint2*)(bp+4);
        acc[nt] = __builtin_amdgcn_mfma_f32_32x32x16_bf16(a.v, b.v, acc[nt], 0, 0, 0);
      }
    }
    __syncthreads();
  }
  #pragma unroll
  for (int nt=0;nt<4;++nt){
    #pragma unroll
    for (int r=0;r<16;++r){
      int row = (r&3) + 8*(r>>2) + rbase;
      atomicAdd(&G[(size_t)(tr*128 + mt*32 + row)*512 + tc*128 + nt*32 + pl], acc[nt][r]);
    }
  }
  if (diag){
    #pragma unroll
    for (int j=0;j<8;++j) atomicAdd(&csum[c0s+j], cs[j]);
    __syncthreads();
    if (tid < 128) atomicAdd(&sumh[tr*128 + tid], csum[tid]);
  }
}

// ---------------- P = G @ W ----------------
__global__ void kP_kernel(const float* __restrict__ G, const float* __restrict__ Wf,
                          float* __restrict__ P, int Cin, int Cout){
  int id = blockIdx.x*256 + threadIdx.x;
  if (id >= Cin*Cout) return;
  int i = id / Cout, j = id - i*Cout;
  float s = 0.f;
  for (int k=0;k<Cin;++k) s = fmaf(G[(size_t)i*Cin+k], Wf[(size_t)k*Cout+j], s);
  P[id] = s;
}

// ---------------- scale/shift from Gram-derived BN stats ----------------
__global__ void kFinal_kernel(const float* __restrict__ P, const float* __restrict__ sumh,
                              const float* __restrict__ Wf, const float* __restrict__ g,
                              const float* __restrict__ bb, float* __restrict__ scale,
                              float* __restrict__ shift, int Cin, int Cout, float invM){
  int j = blockIdx.x*256 + threadIdx.x;
  if (j >= Cout) return;
  float mean=0.f, e2=0.f;
  for (int i=0;i<Cin;++i){
    float w = Wf[(size_t)i*Cout + j];
    mean = fmaf(sumh[i], w, mean);
    e2   = fmaf(w, P[(size_t)i*Cout + j], e2);
  }
  mean *= invM; e2 *= invM;
  float var = e2 - mean*mean;
  float inv = rsqrtf(var + EPSf);
  float sc = g[j]*inv;
  scale[j]=sc;
  shift[j]=bb[j] - mean*sc;
}

// ---------------- layer-2 stats ----------------
__global__ __launch_bounds__(512) void stats2_kernel(const float* __restrict__ x,
    const int* __restrict__ idx, const float* __restrict__ W1f,
    const float* __restrict__ sc1v, const float* __restrict__ sh1v,
    float* __restrict__ G2, float* __restrict__ sum2){
  __shared__ float W1s[6][64];
  __shared__ float fsh[64][8];
  __shared__ short H1T[64*68];
  __shared__ float csum[64];
  int tid = threadIdx.x, lane = tid & 63, w = tid >> 6;   // 8 waves
  if (tid < 384) W1s[tid>>6][tid&63] = W1f[tid];
  if (tid < 64) csum[tid] = 0.f;
  int rp = tid >> 4, cq = tid & 15, c0 = cq*4;
  float sca[4], sha[4];
  #pragma unroll
  for (int k=0;k<4;++k){ sca[k]=sc1v[c0+k]; sha[k]=sh1v[c0+k]; }
  int mt = w & 1, nt = (w>>1) & 1, kh = w >> 2;
  int arow = (mt*32 + (lane&31))*68;
  int brow = (nt*32 + (lane&31))*68;
  int ko = (lane>>5)*8;
  floatx16 acc;
  #pragma unroll
  for (int q=0;q<16;++q) acc[q]=0.f;
  float cs[4] = {0.f,0.f,0.f,0.f};
  int rpc = Mrows / gridDim.x;
  int r0 = blockIdx.x * rpc;
  __syncthreads();
  for (int rb=r0; rb<r0+rpc; rb+=64){
    {
      int r = tid>>3, e = tid&7;
      if (e < 6){
        int grow = rb + r;
        int bn = grow / Kk;
        int b = bn >> 12, n = bn & 4095;
        int j = idx[grow];
        const float* xb = x + b*3*Nn;
        fsh[r][e] = (e<3) ? xb[e*Nn + j] : xb[(e-3)*Nn + n];
      }
    }
    __syncthreads();
    {
      float y0[4]={0,0,0,0}, y1[4]={0,0,0,0};
      int ra = rp*2, rbw = rp*2+1;
      #pragma unroll
      for (int i=0;i<6;++i){
        float fa = fsh[ra][i], fb = fsh[rbw][i];
        float4 wv = *(const float4*)&W1s[i][c0];
        y0[0]=fmaf(fa,wv.x,y0[0]); y0[1]=fmaf(fa,wv.y,y0[1]);
        y0[2]=fmaf(fa,wv.z,y0[2]); y0[3]=fmaf(fa,wv.w,y0[3]);
        y1[0]=fmaf(fb,wv.x,y1[0]); y1[1]=fmaf(fb,wv.y,y1[1]);
        y1[2]=fmaf(fb,wv.z,y1[2]); y1[3]=fmaf(fb,wv.w,y1[3]);
      }
      #pragma unroll
      for (int k=0;k<4;++k){
        float va = fmaxf(fmaf(y0[k],sca[k],sha[k]),0.f);
        float vb = fmaxf(fmaf(y1[k],sca[k],sha[k]),0.f);
        cs[k] += va; cs[k] += vb;
        unsigned int pk = f2bu(va) | ((unsigned)f2bu(vb)<<16);
        *(unsigned int*)&H1T[(c0+k)*68 + ra] = pk;
      }
    }
    __syncthreads();
    {
      int kc = kh*32;
      #pragma unroll
      for (int s=0;s<2;++s){
        Frag a, b;
        const short* ap = &H1T[arow + kc + s*16 + ko];
        const short* bp = &H1T[brow + kc + s*16 + ko];
        a.u2[0] = *(const uint2*)ap;  a.u2[1] = *(const uint2*)(ap+4);
        b.u2[0] = *(const uint2*)bp;  b.u2[1] = *(const uint2*)(bp+4);
        acc = __builtin_amdgcn_mfma_f32_32x32x16_bf16(a.v, b.v, acc, 0, 0, 0);
      }
    }
    __syncthreads();
  }
  int col = lane & 31, rbase = 4*(lane>>5);
  #pragma unroll
  for (int r=0;r<16;++r){
    int row = (r&3) + 8*(r>>2) + rbase;
    atomicAdd(&G2[(size_t)(mt*32+row)*64 + nt*32+col], acc[r]);
  }
  #pragma unroll
  for (int k=0;k<4;++k) atomicAdd(&csum[c0+k], cs[k]);
  __syncthreads();
  if (tid < 64) atomicAdd(&sum2[tid], csum[tid]);
}

// ---------------- fused layers 1+2 ----------------
__global__ __launch_bounds__(64) void fl12_kernel(const float* __restrict__ x,
    const int* __restrict__ idx, const float* __restrict__ W1f,
    const float* __restrict__ sc1v, const float* __restrict__ sh1v,
    const float* __restrict__ W2f, const float* __restrict__ sc2v,
    const float* __restrict__ sh2v, bf16* __restrict__ H2, bf16* __restrict__ cat){
  __shared__ float fsh[Kk][6];
  __shared__ float h1[Kk][64];
  __shared__ float mm[4][64];
  int bn = blockIdx.x, b = bn>>12, n = bn & 4095;
  int tid = threadIdx.x;
  if (tid < Kk){
    int j = idx[(size_t)bn*Kk + tid];
    const float* xb = x + b*3*Nn;
    fsh[tid][0]=xb[j]; fsh[tid][1]=xb[Nn+j]; fsh[tid][2]=xb[2*Nn+j];
    fsh[tid][3]=xb[n]; fsh[tid][4]=xb[Nn+n]; fsh[tid][5]=xb[2*Nn+n];
  }
  __syncthreads();
  {
    float sc=sc1v[tid], sh=sh1v[tid];
    float w[6];
    #pragma unroll
    for (int i=0;i<6;++i) w[i]=W1f[i*64+tid];
    float mx = 0.f;
    #pragma unroll
    for (int r=0;r<Kk;++r){
      float y=0.f;
      #pragma unroll
      for (int i=0;i<6;++i) y = fmaf(fsh[r][i], w[i], y);
      float v = fmaxf(fmaf(y,sc,sh),0.f);
      h1[r][tid]=v;
      mx = fmaxf(mx,v);
    }
    cat[(size_t)bn*512 + tid] = f2b(mx);
  }
  __syncthreads();
  int q = tid >> 4, c0 = (tid & 15)*4;
  float acc[5][4]={};
  for (int i0=0;i0<64;i0+=4){
    float hv[5][4];
    #pragma unroll
    for (int l=0;l<5;++l){
      float4 t4 = *(const float4*)&h1[q*5+l][i0];
      hv[l][0]=t4.x; hv[l][1]=t4.y; hv[l][2]=t4.z; hv[l][3]=t4.w;
    }
    #pragma unroll
    for (int ii=0;ii<4;++ii){
      const float* wp = W2f + (i0+ii)*64 + c0;
      float w0=wp[0],w1=wp[1],w2=wp[2],w3=wp[3];
      #pragma unroll
      for (int l=0;l<5;++l){
        float hvv=hv[l][ii];
        acc[l][0]=fmaf(hvv,w0,acc[l][0]);
        acc[l][1]=fmaf(hvv,w1,acc[l][1]);
        acc[l][2]=fmaf(hvv,w2,acc[l][2]);
        acc[l][3]=fmaf(hvv,w3,acc[l][3]);
      }
    }
  }
  float sc[4],sh[4];
  #pragma unroll
  for (int cb=0;cb<4;++cb){ sc[cb]=sc2v[c0+cb]; sh[cb]=sh2v[c0+cb]; }
  float mx[4]={0,0,0,0};
  #pragma unroll
  for (int l=0;l<5;++l){
    unsigned short us[4];
    #pragma unroll
    for (int cb=0;cb<4;++cb){
      float v=fmaxf(fmaf(acc[l][cb],sc[cb],sh[cb]),0.f);
      mx[cb]=fmaxf(mx[cb],v);
      us[cb]=f2bu(v);
    }
    uint2 v2; v2.x = us[0]|((unsigned)us[1]<<16); v2.y=us[2]|((unsigned)us[3]<<16);
    *(uint2*)(H2 + ((size_t)bn*Kk + q*5+l)*64 + c0) = v2;
  }
  #pragma unroll
  for (int cb=0;cb<4;++cb) mm[q][c0+cb]=mx[cb];
  __syncthreads();
  {
    float M0 = fmaxf(fmaxf(mm[0][tid],mm[1][tid]),fmaxf(mm[2][tid],mm[3][tid]));
    cat[(size_t)bn*512 + 64 + tid] = f2b(M0);
  }
}

// ---------------- layer-4 stats: MFMA produce + MFMA Gram ----------------
__global__ __launch_bounds__(512) void stats4_kernel(const bf16* __restrict__ H2,
    const bf16* __restrict__ W3T, const float* __restrict__ sc3v, const float* __restrict__ sh3v,
    float* __restrict__ G4, float* __restrict__ sum4){
  __shared__ short h2s[64*68];
  __shared__ short H3T[128*68];
  __shared__ float csum[128];
  int tid = threadIdx.x, lane = tid & 63, w = tid >> 6;   // 8 waves
  if (tid < 128) csum[tid] = 0.f;
  int trow = tid >> 3, tc0 = (tid & 7)*8;
  int pl  = lane & 31;
  int ko  = (lane >> 5)*8;
  int pmt = w >> 2, pnt = w & 3;
  int parow = (pmt*32 + pl)*68;
  int pcol  = pnt*32 + pl;
  float psc = sc3v[pcol], psh = sh3v[pcol];
  int prbase = 4*(lane>>5);
  FragQ bfr[4];
  #pragma unroll
  for (int kq=0;kq<4;++kq)
    bfr[kq].q = *(const uint4*)&W3T[(size_t)pcol*64 + kq*16 + ko];
  int gmt = w>>1, gnt0 = (w&1)*2, gnt1 = gnt0+1;
  int garow  = (gmt*32 + pl)*68;
  int gbrow0 = (gnt0*32 + pl)*68;
  int gbrow1 = (gnt1*32 + pl)*68;
  floatx16 acc0, acc1;
  #pragma unroll
  for (int q=0;q<16;++q){ acc0[q]=0.f; acc1[q]=0.f; }
  float cs = 0.f;
  int rpc = Mrows / gridDim.x;
  int r0 = blockIdx.x * rpc;
  uint4 hreg = *(const uint4*)&H2[(size_t)(r0+trow)*64 + tc0];
  for (int rb=r0; rb<r0+rpc; rb+=64){
    {
      short* dst = &h2s[trow*68 + tc0];
      *(uint2*)dst       = make_uint2(hreg.x, hreg.y);
      *(uint2*)(dst + 4) = make_uint2(hreg.z, hreg.w);
    }
    if (rb + 64 < r0 + rpc)
      hreg = *(const uint4*)&H2[(size_t)(rb+64+trow)*64 + tc0];
    __syncthreads();
    {
      floatx16 pacc;
      #pragma unroll
      for (int q=0;q<16;++q) pacc[q]=0.f;
      #pragma unroll
      for (int kq=0;kq<4;++kq){
        Frag a;
        const short* ap = &h2s[parow + kq*16 + ko];
        a.u2[0] = *(const uint2*)ap;  a.u2[1] = *(const uint2*)(ap+4);
        pacc = __builtin_amdgcn_mfma_f32_32x32x16_bf16(a.v, bfr[kq].v, pacc, 0, 0, 0);
      }
      #pragma unroll
      for (int g=0; g<4; ++g){
        unsigned short p[4];
        #pragma unroll
        for (int r=0;r<4;++r){
          float v = fmaxf(fmaf(pacc[g*4+r], psc, psh), 0.f);
          cs += v;
          p[r] = f2bu(v);
        }
        uint2 pk; pk.x = p[0] | ((unsigned)p[1]<<16); pk.y = p[2] | ((unsigned)p[3]<<16);
        *(uint2*)&H3T[pcol*68 + pmt*32 + 8*g + prbase] = pk;
      }
    }
    __syncthreads();
    #pragma unroll
    for (int kc=0;kc<64;kc+=16){
      Frag a, b0, b1;
      const short* ap  = &H3T[garow  + kc + ko];
      const short* bp0 = &H3T[gbrow0 + kc + ko];
      const short* bp1 = &H3T[gbrow1 + kc + ko];
      a.u2[0]  = *(const uint2*)ap;   a.u2[1]  = *(const uint2*)(ap+4);
      b0.u2[0] = *(const uint2*)bp0;  b0.u2[1] = *(const uint2*)(bp0+4);
      b1.u2[0] = *(const uint2*)bp1;  b1.u2[1] = *(const uint2*)(bp1+4);
      acc0 = __builtin_amdgcn_mfma_f32_32x32x16_bf16(a.v, b0.v, acc0, 0, 0, 0);
      acc1 = __builtin_amdgcn_mfma_f32_32x32x16_bf16(a.v, b1.v, acc1, 0, 0, 0);
    }
  }
  int col = pl;
  #pragma unroll
  for (int r=0;r<16;++r){
    int row = (r&3) + 8*(r>>2) + prbase;
    atomicAdd(&G4[(size_t)(gmt*32+row)*128 + gnt0*32+col], acc0[r]);
    atomicAdd(&G4[(size_t)(gmt*32+row)*128 + gnt1*32+col], acc1[r]);
  }
  atomicAdd(&csum[pcol], cs);
  __syncthreads();
  if (tid < 128) atomicAdd(&sum4[tid], csum[tid]);
}

// ---------------- fused layers 3+4: MFMA produce chain + col-owner maxpool ----------------
__global__ __launch_bounds__(512,4) void fl34_kernel(const bf16* __restrict__ H2,
    const bf16* __restrict__ W3T, const float* __restrict__ sc3v, const float* __restrict__ sh3v,
    const bf16* __restrict__ W4T, const float* __restrict__ sc4v, const float* __restrict__ sh4v,
    bf16* __restrict__ cat){
  __shared__ short h2s[64*68];             // 8.5 KB
  __shared__ short h3s[64*132];            // 16.5 KB
  __shared__ unsigned short h4s[64*256];   // 32 KB
  __shared__ unsigned short mx3u[16*128];  // 4 KB
  __shared__ unsigned short mx4u[16*256];  // 8 KB
  int tid = threadIdx.x, lane = tid & 63, w = tid >> 6;
  int pl = lane & 31;
  int ko = (lane >> 5)*8;
  int rbase = 4*(lane>>5);
  {
    unsigned* p4 = (unsigned*)mx4u;
    for (int u=tid; u<2048; u+=512) p4[u]=0u;
    unsigned* p3 = (unsigned*)mx3u;
    for (int u=tid; u<1024; u+=512) p3[u]=0u;
  }
  int mt3 = w >> 2, ct3 = w & 3;
  int c3 = ct3*32 + pl;
  float sc3 = sc3v[c3], sh3 = sh3v[c3];
  int a3row = (mt3*32 + pl)*68;
  int c4 = w*32 + pl;
  float sc4 = sc4v[c4], sh4 = sh4v[c4];
  int trow = tid >> 3, tc0 = (tid & 7)*8;
  int r0 = blockIdx.x * 320;
  uint4 hreg = *(const uint4*)&H2[(size_t)(r0+trow)*64 + tc0];
  {
    short* dst = &h2s[trow*68 + tc0];
    *(uint2*)dst       = make_uint2(hreg.x, hreg.y);
    *(uint2*)(dst + 4) = make_uint2(hreg.z, hreg.w);
  }
  hreg = *(const uint4*)&H2[(size_t)(r0 + 64 + trow)*64 + tc0];
  __syncthreads();
  for (int t=0; t<5; ++t){
    {
      floatx16 pa;
      #pragma unroll
      for (int q=0;q<16;++q) pa[q]=0.f;
      #pragma unroll
      for (int kq=0;kq<4;++kq){
        Frag a; FragQ b;
        const short* ap = &h2s[a3row + kq*16 + ko];
        a.u2[0] = *(const uint2*)ap;  a.u2[1] = *(const uint2*)(ap+4);
        b.q = *(const uint4*)&W3T[(size_t)c3*64 + kq*16 + ko];
        pa = __builtin_amdgcn_mfma_f32_32x32x16_bf16(a.v, b.v, pa, 0, 0, 0);
      }
      #pragma unroll
      for (int r=0;r<16;++r){
        int m = mt3*32 + (r&3) + 8*(r>>2) + rbase;
        float v = fmaxf(fmaf(pa[r], sc3, sh3), 0.f);
        h3s[m*132 + c3] = (short)f2bu(v);
      }
    }
    __syncthreads();
    #pragma unroll
    for (int mt4=0; mt4<2; ++mt4){
      floatx16 acc;
      #pragma unroll
      for (int q=0;q<16;++q) acc[q]=0.f;
      int a4row = (mt4*32 + pl)*132;
      #pragma unroll
      for (int kq=0;kq<8;++kq){
        Frag a; FragQ b;
        const short* ap = &h3s[a4row + kq*16 + ko];
        a.u2[0] = *(const uint2*)ap;  a.u2[1] = *(const uint2*)(ap+4);
        b.q = *(const uint4*)&W4T[(size_t)c4*128 + kq*16 + ko];
        acc = __builtin_amdgcn_mfma_f32_32x32x16_bf16(a.v, b.v, acc, 0, 0, 0);
      }
      #pragma unroll
      for (int r=0;r<16;++r){
        int m = mt4*32 + (r&3) + 8*(r>>2) + rbase;
        float v = fmaxf(fmaf(acc[r], sc4, sh4), 0.f);
        h4s[m*256 + c4] = f2bu(v);
      }
    }
    __syncthreads();
    if (t < 4){
      short* dst = &h2s[trow*68 + tc0];
      *(uint2*)dst       = make_uint2(hreg.x, hreg.y);
      *(uint2*)(dst + 4) = make_uint2(hreg.z, hreg.w);
      if (t < 3) hreg = *(const uint4*)&H2[(size_t)(r0 + (t+2)*64 + trow)*64 + tc0];
    }
    {
      int lr0 = t*64;
      if (tid < 256){
        int c = tid;
        int p = lr0/20;
        int nb = (p+1)*20 - lr0;
        unsigned ml = 0;
        for (int r=0;r<64;++r){
          unsigned v = h4s[r*256 + c];
          ml = v > ml ? v : ml;
          if (--nb == 0){
            unsigned short* mp = &mx4u[p*256 + c];
            unsigned cur = *mp;
            if (ml > cur) *mp = (unsigned short)ml;
            ml = 0; ++p; nb = 20;
          }
        }
        if (nb != 20){
          unsigned short* mp = &mx4u[p*256 + c];
          unsigned cur = *mp;
          if (ml > cur) *mp = (unsigned short)ml;
        }
      } else if (tid < 384){
        int c = tid - 256;
        int p = lr0/20;
        int nb = (p+1)*20 - lr0;
        unsigned ml = 0;
        for (int r=0;r<64;++r){
          unsigned v = (unsigned)(unsigned short)h3s[r*132 + c];
          ml = v > ml ? v : ml;
          if (--nb == 0){
            unsigned short* mp = &mx3u[p*128 + c];
            unsigned cur = *mp;
            if (ml > cur) *mp = (unsigned short)ml;
            ml = 0; ++p; nb = 20;
          }
        }
        if (nb != 20){
          unsigned short* mp = &mx3u[p*128 + c];
          unsigned cur = *mp;
          if (ml > cur) *mp = (unsigned short)ml;
        }
      }
    }
    __syncthreads();
  }
  int bn0 = blockIdx.x*16;
  {
    int p = tid >> 5, c0 = (tid & 31)*8;
    uint4 v = *(const uint4*)&mx4u[p*256 + c0];
    *(uint4*)&cat[(size_t)(bn0+p)*512 + 256 + c0] = v;
  }
  if (tid < 256){
    int p = tid >> 4, c0 = (tid & 15)*8;
    uint4 v = *(const uint4*)&mx3u[p*128 + c0];
    *(uint4*)&cat[(size_t)(bn0+p)*512 + 128 + c0] = v;
  }
}

// ---------------- layer 5: MFMA GEMM + LDS-staged coalesced epilogue ----------------
__global__ __launch_bounds__(512) void l5_kernel(const bf16* __restrict__ cat,
                                                const bf16* __restrict__ W5T,
                                                const float* __restrict__ scale,
                                                const float* __restrict__ shift,
                                                float* __restrict__ out){
  __shared__ short cs[64*68];
  __shared__ float ob[64*129];
  int tid = threadIdx.x, lane = tid & 63, w = tid >> 6;
  int pl = lane & 31;
  int ko = (lane >> 5)*8;
  int rbase = 4*(lane>>5);
  int mt = w & 1, ntb = w >> 1;          // nt = ntb + 4*s, s=0..3
  int arow = (mt*32 + pl)*68;
  int trow = tid >> 3, tc0 = (tid & 7)*8;
  int r0 = blockIdx.x*64;
  floatx16 acc[4];
  #pragma unroll
  for (int s=0;s<4;++s)
    #pragma unroll
    for (int q=0;q<16;++q) acc[s][q]=0.f;
  const bf16* arow_g = cat + (size_t)(r0+trow)*512 + tc0;
  uint4 hreg = *(const uint4*)arow_g;
  for (int kc8=0; kc8<8; ++kc8){
    {
      short* dst = &cs[trow*68 + tc0];
      *(uint2*)dst       = make_uint2(hreg.x, hreg.y);
      *(uint2*)(dst + 4) = make_uint2(hreg.z, hreg.w);
    }
    if (kc8 < 7) hreg = *(const uint4*)(arow_g + (kc8+1)*64);
    __syncthreads();
    #pragma unroll
    for (int kq=0;kq<4;++kq){
      Frag a;
      const short* ap = &cs[arow + kq*16 + ko];
      a.u2[0] = *(const uint2*)ap;  a.u2[1] = *(const uint2*)(ap+4);
      #pragma unroll
      for (int s=0;s<4;++s){
        FragQ b;
        int col = (ntb + 4*s)*32 + pl;
        b.q = *(const uint4*)&W5T[(size_t)col*512 + kc8*64 + kq*16 + ko];
        acc[s] = __builtin_amdgcn_mfma_f32_32x32x16_bf16(a.v, b.v, acc[s], 0, 0, 0);
      }
    }
    __syncthreads();
  }
  int b = r0 >> 12, n0 = r0 & 4095;
  int colL = ntb*32 + pl;                // 0..127 within chunk
  int colc = tid >> 2, sub = tid & 3;    // writer mapping: 4 threads per col
  for (int s=0;s<4;++s){
    float sc = scale[128*s + colL], sh = shift[128*s + colL];
    #pragma unroll
    for (int q=0;q<16;++q){
      int m = mt*32 + (q&3) + 8*(q>>2) + rbase;
      ob[m*129 + colL] = fmaxf(fmaf(acc[s][q], sc, sh), 0.f);
    }
    __syncthreads();
    float* op = out + ((size_t)b*512 + 128*s + colc)*4096 + n0 + sub*16;
    #pragma unroll
    for (int j=0;j<4;++j){
      int rr = sub*16 + j*4;
      float4 v = make_float4(ob[(rr+0)*129 + colc], ob[(rr+1)*129 + colc],
                             ob[(rr+2)*129 + colc], ob[(rr+3)*129 + colc]);
      *(float4*)(op + j*4) = v;
    }
    __syncthreads();
  }
}

extern "C" void kernel_launch(void* const* d_in, const int* in_sizes, int n_in,
                              void* d_out, int out_size, void* d_ws, size_t ws_size,
                              hipStream_t stream){
  const float* x   = (const float*)d_in[0];
  const float* W1f = (const float*)d_in[1];
  const float* W2f = (const float*)d_in[2];
  const float* W3f = (const float*)d_in[3];
  const float* W4f = (const float*)d_in[4];
  const float* W5f = (const float*)d_in[5];
  const float* g1=(const float*)d_in[6],  *b1=(const float*)d_in[7];
  const float* g2=(const float*)d_in[8],  *b2=(const float*)d_in[9];
  const float* g3=(const float*)d_in[10], *b3=(const float*)d_in[11];
  const float* g4=(const float*)d_in[12], *b4=(const float*)d_in[13];
  const float* g5=(const float*)d_in[14], *b5=(const float*)d_in[15];
  float* out = (float*)d_out;

  char* w = (char*)d_ws;
  size_t off = 0;
  auto alloc = [&](size_t bytes)->void*{
    void* p = w + off;
    off = (off + bytes + 255) & ~(size_t)255;
    return p;
  };

  int*  idxb = (int*) alloc((size_t)BN*Kk*4);
  bf16* H2   = (bf16*)alloc((size_t)Mrows*64*2);
  bf16* catb = (bf16*)alloc((size_t)BN*512*2);
  bf16* W3T  = (bf16*)alloc((size_t)128*64*2);
  bf16* W4T  = (bf16*)alloc((size_t)256*128*2);
  bf16* W5T  = (bf16*)alloc((size_t)512*512*2);
  float* pv  = (float*)H2;
  int*   pib = (int*)((char*)H2 + (size_t)BN*8*Kk*4);

  size_t statsStart = off;
  float* partf=(float*)alloc(256*48*4);
  float* Gf=(float*)alloc(36*4);
  float* sumf=(float*)alloc(8*4);
  float* G2=(float*)alloc(4096*4);   float* sum2=(float*)alloc(64*4);
  float* G3=(float*)alloc(4096*4);   float* sum3=(float*)alloc(64*4);
  float* G4=(float*)alloc(16384*4);  float* sum4=(float*)alloc(128*4);
  float* G5=(float*)alloc(262144*4); float* sum5=(float*)alloc(512*4);
  float* P1=(float*)alloc(384*4);
  float* P2=(float*)alloc(4096*4);
  float* P3=(float*)alloc(8192*4);
  float* P4=(float*)alloc(32768*4);
  float* P5=(float*)alloc(262144*4);
  float* sc1=(float*)alloc(64*4);   float* sh1=(float*)alloc(64*4);
  float* sc2=(float*)alloc(64*4);   float* sh2=(float*)alloc(64*4);
  float* sc3=(float*)alloc(128*4);  float* sh3=(float*)alloc(128*4);
  float* sc4=(float*)alloc(256*4);  float* sh4=(float*)alloc(256*4);
  float* sc5=(float*)alloc(512*4);  float* sh5=(float*)alloc(512*4);
  size_t statsEnd = off;

  int statsFloats = (int)((statsEnd - statsStart)/4);
  zero_kernel<<<(statsFloats+255)/256,256,0,stream>>>((float*)(w+statsStart), statsFloats);
  w3t_kernel<<<32,256,0,stream>>>(W3f, W3T);
  w4t_kernel<<<128,256,0,stream>>>(W4f, W4T);
  w5t_kernel<<<1024,256,0,stream>>>(W5f, W5T);

  knnA_kernel<<<1024,256,0,stream>>>(x, pv, pib);
  knnB_kernel<<<BN/256,256,0,stream>>>(pv, pib, idxb);

  const float invM  = 1.0f/(float)Mrows;
  const float invM5 = 1.0f/(float)BN;

  gramf_kernel<<<256,256,0,stream>>>(x, idxb, partf);
  reducef_kernel<<<1,64,0,stream>>>(partf, Gf, sumf);
  kP_kernel<<<2,256,0,stream>>>(Gf, W1f, P1, 6, 64);
  kFinal_kernel<<<1,256,0,stream>>>(P1, sumf, W1f, g1, b1, sc1, sh1, 6, 64, invM);

  stats2_kernel<<<512,512,0,stream>>>(x, idxb, W1f, sc1, sh1, G2, sum2);
  kP_kernel<<<16,256,0,stream>>>(G2, W2f, P2, 64, 64);
  kFinal_kernel<<<1,256,0,stream>>>(P2, sum2, W2f, g2, b2, sc2, sh2, 64, 64, invM);

  fl12_kernel<<<BN,64,0,stream>>>(x, idxb, W1f, sc1, sh1, W2f, sc2, sh2, H2, catb);

  gram3_kernel<<<512,256,0,stream>>>(H2, Mrows, G3, sum3);
  kP_kernel<<<32,256,0,stream>>>(G3, W3f, P3, 64, 128);
  kFinal_kernel<<<1,256,0,stream>>>(P3, sum3, W3f, g3, b3, sc3, sh3, 64, 128, invM);

  stats4_kernel<<<512,512,0,stream>>>(H2, W3T, sc3, sh3, G4, sum4);
  kP_kernel<<<128,256,0,stream>>>(G4, W4f, P4, 128, 256);
  kFinal_kernel<<<1,256,0,stream>>>(P4, sum4, W4f, g4, b4, sc4, sh4, 128, 256, invM);

  fl34_kernel<<<Mrows/320,512,0,stream>>>(H2, W3T, sc3, sh3, W4T, sc4, sh4, catb);

  gram5_kernel<<<512,256,0,stream>>>(catb, G5, sum5);
  kP_kernel<<<1024,256,0,stream>>>(G5, W5f, P5, 512, 512);
  kFinal_kernel<<<2,256,0,stream>>>(P5, sum5, W5f, g5, b5, sc5, sh5, 512, 512, invM5);
  l5_kernel<<<BN/64,512,0,stream>>>(catb, W5T, sc5, sh5, out);
}

// Round 11
// 1273.748 us; speedup vs baseline: 1.2229x; 1.0435x over previous
//
#include <hip/hip_runtime.h>
#include <hip/hip_bf16.h>
#include <cfloat>

using bf16 = __hip_bfloat16;

typedef short short8 __attribute__((ext_vector_type(8)));
typedef float floatx16 __attribute__((ext_vector_type(16)));
union Frag { short8 v; uint2 u2[2]; };
union FragQ { short8 v; uint4 q; uint2 u2[2]; };
union U4b { uint4 q; unsigned short s[8]; };

constexpr int Bb = 8, Nn = 4096, Kk = 20;
constexpr int BN = Bb * Nn;                     // 32768
constexpr int Mrows = BN * Kk;                  // 655360
constexpr float EPSf = 1e-5f;

static __device__ __forceinline__ float b2f(bf16 v){ return __bfloat162float(v); }
static __device__ __forceinline__ bf16 f2b(float v){ return __float2bfloat16(v); }
static __device__ __forceinline__ unsigned short f2bu(float v){
  union { bf16 b; unsigned short u; } cv; cv.b = __float2bfloat16(v); return cv.u;
}
static __device__ __forceinline__ float bits2f(unsigned short u){
  union { unsigned int i; float f; } c; c.i = ((unsigned)u)<<16; return c.f;
}

// ---------------- zero workspace region ----------------
__global__ void zero_kernel(float* __restrict__ p, int n){
  int i = blockIdx.x*256 + threadIdx.x;
  if (i < n) p[i] = 0.f;
}

// ---------------- W3^T bf16 pack ----------------
__global__ void w3t_kernel(const float* __restrict__ W3f, bf16* __restrict__ W3T){
  int id = blockIdx.x*256 + threadIdx.x;   // 128*64 = 8192 elems
  if (id >= 128*64) return;
  int n = id >> 6, k = id & 63;
  W3T[id] = f2b(W3f[(size_t)k*128 + n]);
}

// ---------------- W4^T bf16 pack ----------------
__global__ void w4t_kernel(const float* __restrict__ W4f, bf16* __restrict__ W4T){
  int id = blockIdx.x*256 + threadIdx.x;   // 128*256 = 32768 elems
  if (id >= 128*256) return;
  int k = id >> 8, c = id & 255;           // coalesced read of W4f
  W4T[(size_t)c*128 + k] = f2b(W4f[id]);
}

// ---------------- W5^T bf16 pack ----------------
__global__ void w5t_kernel(const float* __restrict__ W5f, bf16* __restrict__ W5T){
  int id = blockIdx.x*256 + threadIdx.x;   // 512*512 = 262144 elems
  if (id >= 512*512) return;
  int k = id >> 9, c = id & 511;           // coalesced read of W5f
  W5T[(size_t)c*512 + k] = f2b(W5f[id]);
}

// ---------------- KNN phase A v8: v5 shape + CAP=60 / stride-62 list ----------------
// v7 post-mortem: stride-66 list pushed LDS to 41984B, crossing the 4-blocks/CU
// boundary (160KiB/40960 = exactly 4) down to 3 => occupancy 35->22.5%, VALUBusy
// 81->57.5% (same total VALU work, worse issue efficiency). Fix: CAP=60, stride 62
// shorts (124B = 31 dwords; 31 = -1 mod 32 => thread t's list base on bank -t:
// perfect spread, keeps v7's conflict fix). LDS = 8192 + 31744 = 39936 < 40960 =>
// 4 blocks/CU restored. CAP 60 = 5.4 sigma over E[admits]~31 (fallback ~8e-3 per
// dispatch; exact full-scan fallback retained for correctness).
__global__ __launch_bounds__(256) void knnA_kernel(const float* __restrict__ x,
                                                   float* __restrict__ pv, int* __restrict__ pi){
#pragma clang fp contract(off)
  __shared__ float4 p4[512];
  __shared__ unsigned short lst[256*62];
  int blk = blockIdx.x;
  int stripe = blk & 7;
  int chunk  = (blk >> 3) & 15;
  int b      = blk >> 7;
  const float* xb = x + b*3*Nn;
  int j0 = stripe*512;
  for (int u = threadIdx.x; u < 512; u += 256){
    int j = j0 + u;
    float a0 = xb[j];
    float a1 = xb[Nn + j];
    float a2 = xb[2*Nn + j];
    float s = a0*a0; s = s + a1*a1; s = s + a2*a2;
    p4[u] = make_float4(a0, a1, a2, s);
  }
  __syncthreads();
  int i = chunk*256 + threadIdx.x;
  float xi = xb[i], yi = xb[Nn+i], zi = xb[2*Nn+i];
  float ni = xi*xi; ni = ni + yi*yi; ni = ni + zi*zi;
  float mni = -ni;
  float xi2 = xi + xi, yi2 = yi + yi, zi2 = zi + zi;
  // ---- pass A: 32 group-maxes (groups of 16, fast nd) -> top-20 min/max network ----
  float tv[Kk];
  #pragma unroll
  for (int s=0;s<Kk;++s) tv[s] = -FLT_MAX;
  for (int g=0; g<32; ++g){
    float gm = -FLT_MAX;
    #pragma unroll
    for (int e=0;e<16;++e){
      float4 p = p4[g*16+e];
      float base = mni - p.w;
      float nd = fmaf(xi2, p.x, fmaf(yi2, p.y, fmaf(zi2, p.z, base)));
      gm = fmaxf(gm, nd);
    }
    #pragma unroll
    for (int s=Kk-1; s>=1; --s)
      tv[s] = fmaxf(tv[s], fminf(tv[s-1], gm));
    tv[0] = fmaxf(tv[0], gm);
  }
  float thr = tv[Kk-1];
  thr = thr - (fabsf(thr)*1e-5f + 1e-6f);   // margin >> fast-vs-exact fp discrepancy
  // ---- pass B: fast compare, collect u16 indices (ascending u => stable) ----
  unsigned short* ml = &lst[threadIdx.x*62];
  int cnt = 0;
  for (int u=0; u<512; ++u){
    float4 p = p4[u];
    float base = mni - p.w;
    float nd = fmaf(xi2, p.x, fmaf(yi2, p.y, fmaf(zi2, p.z, base)));
    if (nd >= thr && cnt < 60){ ml[cnt] = (unsigned short)u; ++cnt; }
  }
  // ---- final: EXACT (val,idx) insertion sort ----
  float av[Kk]; int ai[Kk];
  #pragma unroll
  for (int s=0;s<Kk;++s){ av[s] = -FLT_MAX; ai[s] = 0; }
  if (cnt >= 60){
    // exact fallback: full branchy scan (statistically never; correctness guarantee)
    for (int u=0; u<512; ++u){
      float4 p = p4[u];
      float dot = xi*p.x; dot = dot + yi*p.y; dot = dot + zi*p.z;
      float inner = -2.0f*dot;
      float nd = mni - inner; nd = nd - p.w;
      if (nd > av[Kk-1]){
        #pragma unroll
        for (int s=Kk-1; s>=1; --s){
          bool cs = nd > av[s];
          bool cp = nd > av[s-1];
          av[s] = cs ? (cp ? av[s-1] : nd) : av[s];
          ai[s] = cs ? (cp ? ai[s-1] : (j0+u)) : ai[s];
        }
        if (nd > av[0]){ av[0] = nd; ai[0] = j0+u; }
      }
    }
  } else {
    for (int t=0; t<cnt; ++t){
      int lj = ml[t];
      float4 p = p4[lj];
      float dot = xi*p.x; dot = dot + yi*p.y; dot = dot + zi*p.z;
      float inner = -2.0f*dot;
      float nd = mni - inner; nd = nd - p.w;
      if (nd > av[Kk-1]){
        #pragma unroll
        for (int s=Kk-1; s>=1; --s){
          bool cs = nd > av[s];
          bool cp = nd > av[s-1];
          av[s] = cs ? (cp ? av[s-1] : nd) : av[s];
          ai[s] = cs ? (cp ? ai[s-1] : (j0+lj)) : ai[s];
        }
        if (nd > av[0]){ av[0] = nd; ai[0] = j0+lj; }
      }
    }
  }
  long long base = ((long long)(b*Nn + i)*8 + stripe)*Kk;
  #pragma unroll
  for (int s=0;s<Kk;++s){ pv[base+s] = av[s]; pi[base+s] = ai[s]; }
}

// ---------------- KNN phase B: merge 8 stripes ----------------
__global__ __launch_bounds__(256) void knnB_kernel(const float* __restrict__ pv,
                                                   const int* __restrict__ pi,
                                                   int* __restrict__ idx){
  int p = blockIdx.x*256 + threadIdx.x;
  if (p >= BN) return;
  long long base = (long long)p*8*Kk;
  float av[Kk]; int ai[Kk];
  #pragma unroll
  for (int s=0;s<Kk;++s){ av[s]=pv[base+s]; ai[s]=pi[base+s]; }
  for (int t=Kk; t<8*Kk; ++t){
    float nd = pv[base+t]; int j = pi[base+t];
    if (nd > av[Kk-1]){
      #pragma unroll
      for (int s=Kk-1;s>=1;--s){
        bool cs = nd > av[s];
        bool cp = nd > av[s-1];
        av[s] = cs ? (cp?av[s-1]:nd) : av[s];
        ai[s] = cs ? (cp?ai[s-1]:j) : ai[s];
      }
      if (nd > av[0]){ av[0]=nd; ai[0]=j; }
    }
  }
  #pragma unroll
  for (int s=0;s<Kk;++s) idx[(long long)p*Kk+s] = ai[s];
}

// ---------------- layer-1 feature stats ----------------
__global__ __launch_bounds__(256) void gramf_kernel(const float* __restrict__ x,
                                                    const int* __restrict__ idx,
                                                    float* __restrict__ part){
  float acc[36]; float s6[6];
  #pragma unroll
  for (int a=0;a<36;++a) acc[a]=0.f;
  #pragma unroll
  for (int a=0;a<6;++a) s6[a]=0.f;
  for (long long row = blockIdx.x*256 + threadIdx.x; row < Mrows; row += (long long)gridDim.x*256){
    int bn = (int)(row / Kk);
    int b = bn >> 12, n = bn & 4095;
    int j = idx[row];
    const float* xb = x + b*3*Nn;
    float f[6];
    f[0]=xb[j];  f[1]=xb[Nn+j];  f[2]=xb[2*Nn+j];
    f[3]=xb[n];  f[4]=xb[Nn+n];  f[5]=xb[2*Nn+n];
    #pragma unroll
    for (int a=0;a<6;++a){
      s6[a] += f[a];
      #pragma unroll
      for (int c=0;c<6;++c) acc[a*6+c] = fmaf(f[a], f[c], acc[a*6+c]);
    }
  }
  __shared__ float red[256];
  for (int v=0; v<42; ++v){
    red[threadIdx.x] = (v<36)? acc[v] : s6[v-36];
    __syncthreads();
    for (int s=128; s>0; s>>=1){
      if (threadIdx.x < s) red[threadIdx.x] += red[threadIdx.x+s];
      __syncthreads();
    }
    if (threadIdx.x==0) part[blockIdx.x*48 + v] = red[0];
    __syncthreads();
  }
}

__global__ void reducef_kernel(const float* __restrict__ part, float* __restrict__ Gf,
                               float* __restrict__ sumf){
  int t = threadIdx.x;
  if (t < 42){
    float s = 0.f;
    for (int i=0;i<256;++i) s += part[i*48 + t];
    if (t<36) Gf[t]=s; else sumf[t-36]=s;
  }
}

// ---------------- G3 gram (CIN=64) with fused column sums ----------------
__global__ __launch_bounds__(256) void gram3_kernel(const bf16* __restrict__ H, int M,
                                                    float* __restrict__ G,
                                                    float* __restrict__ sumh){
  __shared__ short HTa[64*68];
  __shared__ float csum[64];
  int tid = threadIdx.x, lane = tid & 63, w = tid >> 6;
  if (tid < 64) csum[tid] = 0.f;
  int nchunks = gridDim.x;
  int rpc = M / nchunks;
  int r0 = blockIdx.x*rpc;
  int mt = w >> 1, nt = w & 1;
  floatx16 acc;
  #pragma unroll
  for (int q=0;q<16;++q) acc[q]=0.f;
  int arow = (mt*32 + (lane&31))*68;
  int brow = (nt*32 + (lane&31))*68;
  int ko = (lane>>5)*8;
  int c0s = (tid & 7)*8;          // staged cols, invariant across s
  float cs[8];
  #pragma unroll
  for (int j=0;j<8;++j) cs[j]=0.f;
  for (int rb=r0; rb<r0+rpc; rb+=64){
    #pragma unroll
    for (int s=0;s<2;++s){
      int e = tid + s*256;
      int row = e >> 3;
      U4b va; va.q = *(const uint4*)&H[(size_t)(rb+row)*64 + c0s];
      #pragma unroll
      for (int j=0;j<8;++j){
        HTa[(c0s+j)*68 + row] = (short)va.s[j];
        cs[j] += bits2f(va.s[j]);
      }
    }
    __syncthreads();
    #pragma unroll
    for (int kc=0;kc<64;kc+=16){
      Frag a, b;
      const short* ap = &HTa[arow + kc + ko];
      const short* bp = &HTa[brow + kc + ko];
      a.u2[0] = *(const uint2*)ap;  a.u2[1] = *(const uint2*)(ap+4);
      b.u2[0] = *(const uint2*)bp;  b.u2[1] = *(const uint2*)(bp+4);
      acc = __builtin_amdgcn_mfma_f32_32x32x16_bf16(a.v, b.v, acc, 0, 0, 0);
    }
    __syncthreads();
  }
  int col = lane & 31, rbase = 4*(lane>>5);
  #pragma unroll
  for (int r=0;r<16;++r){
    int row = (r&3) + 8*(r>>2) + rbase;
    atomicAdd(&G[(size_t)(mt*32 + row)*64 + nt*32 + col], acc[r]);
  }
  #pragma unroll
  for (int j=0;j<8;++j) atomicAdd(&csum[c0s+j], cs[j]);
  __syncthreads();
  if (tid < 64) atomicAdd(&sumh[tid], csum[tid]);
}

// ---------------- G5 gram (CIN=512): 128-wide tiles + fused column sums ----------------
__global__ __launch_bounds__(256) void gram5_kernel(const bf16* __restrict__ H,
                                                    float* __restrict__ G,
                                                    float* __restrict__ sumh){
  __shared__ short HTa[128*68];
  __shared__ short HTb[128*68];
  __shared__ float csum[128];
  int blk = blockIdx.x;
  int pair = blk & 15;
  int chunk = blk >> 4;            // 0..31
  int tr = pair >> 2, tc = pair & 3;
  bool diag = (tr == tc);
  int tid = threadIdx.x, lane = tid & 63, w = tid >> 6;   // 4 waves
  if (tid < 128) csum[tid] = 0.f;
  int rpc = BN / 32;               // 1024
  int r0 = chunk*rpc;
  int pl = lane & 31, ko = (lane>>5)*8, rbase = 4*(lane>>5);
  int mt = w;
  int arow = (mt*32 + pl)*68;
  floatx16 acc[4];
  #pragma unroll
  for (int nt=0;nt<4;++nt)
    #pragma unroll
    for (int q=0;q<16;++q) acc[nt][q]=0.f;
  int c0s = (tid & 15)*8;          // staged cols (within 128), invariant across s
  float cs[8];
  #pragma unroll
  for (int j=0;j<8;++j) cs[j]=0.f;
  const short* Bbase = diag ? HTa : HTb;
  for (int rb=r0; rb<r0+rpc; rb+=64){
    #pragma unroll
    for (int s=0;s<4;++s){
      int e = tid + s*256;
      int row = e >> 4;
      U4b va; va.q = *(const uint4*)&H[(size_t)(rb+row)*512 + tr*128 + c0s];
      #pragma unroll
      for (int j=0;j<8;++j) HTa[(c0s+j)*68 + row] = (short)va.s[j];
      if (diag){
        #pragma unroll
        for (int j=0;j<8;++j) cs[j] += bits2f(va.s[j]);
      } else {
        U4b vb; vb.q = *(const uint4*)&H[(size_t)(rb+row)*512 + tc*128 + c0s];
        #pragma unroll
        for (int j=0;j<8;++j) HTb[(c0s+j)*68 + row] = (short)vb.s[j];
      }
    }
    __syncthreads();
    #pragma unroll
    for (int kc=0;kc<64;kc+=16){
      Frag a;
      const short* ap = &HTa[arow + kc + ko];
      a.u2[0] = *(const uint2*)ap;  a.u2[1] = *(const uint2*)(ap+4);
      #pragma unroll
      for (int nt=0;nt<4;++nt){
        Frag b;
        const short* bp = &Bbase[(nt*32 + pl)*68 + kc + ko];
        b.u2[0] = *(const uint2*)bp;  b.u2[1] = *(const uint2*)(bp+4);
        acc[nt] = __builtin_amdgcn_mfma_f32_32x32x16_bf16(a.v, b.v, acc[nt], 0, 0, 0);
      }
    }
    __syncthreads();
  }
  #pragma unroll
  for (int nt=0;nt<4;++nt){
    #pragma unroll
    for (int r=0;r<16;++r){
      int row = (r&3) + 8*(r>>2) + rbase;
      atomicAdd(&G[(size_t)(tr*128 + mt*32 + row)*512 + tc*128 + nt*32 + pl], acc[nt][r]);
    }
  }
  if (diag){
    #pragma unroll
    for (int j=0;j<8;++j) atomicAdd(&csum[c0s+j], cs[j]);
    __syncthreads();
    if (tid < 128) atomicAdd(&sumh[tr*128 + tid], csum[tid]);
  }
}

// ---------------- P = G @ W ----------------
__global__ void kP_kernel(const float* __restrict__ G, const float* __restrict__ Wf,
                          float* __restrict__ P, int Cin, int Cout){
  int id = blockIdx.x*256 + threadIdx.x;
  if (id >= Cin*Cout) return;
  int i = id / Cout, j = id - i*Cout;
  float s = 0.f;
  for (int k=0;k<Cin;++k) s = fmaf(G[(size_t)i*Cin+k], Wf[(size_t)k*Cout+j], s);
  P[id] = s;
}

// ---------------- scale/shift from Gram-derived BN stats ----------------
__global__ void kFinal_kernel(const float* __restrict__ P, const float* __restrict__ sumh,
                              const float* __restrict__ Wf, const float* __restrict__ g,
                              const float* __restrict__ bb, float* __restrict__ scale,
                              float* __restrict__ shift, int Cin, int Cout, float invM){
  int j = blockIdx.x*256 + threadIdx.x;
  if (j >= Cout) return;
  float mean=0.f, e2=0.f;
  for (int i=0;i<Cin;++i){
    float w = Wf[(size_t)i*Cout + j];
    mean = fmaf(sumh[i], w, mean);
    e2   = fmaf(w, P[(size_t)i*Cout + j], e2);
  }
  mean *= invM; e2 *= invM;
  float var = e2 - mean*mean;
  float inv = rsqrtf(var + EPSf);
  float sc = g[j]*inv;
  scale[j]=sc;
  shift[j]=bb[j] - mean*sc;
}

// ---------------- layer-2 stats ----------------
__global__ __launch_bounds__(512) void stats2_kernel(const float* __restrict__ x,
    const int* __restrict__ idx, const float* __restrict__ W1f,
    const float* __restrict__ sc1v, const float* __restrict__ sh1v,
    float* __restrict__ G2, float* __restrict__ sum2){
  __shared__ float W1s[6][64];
  __shared__ float fsh[64][8];
  __shared__ short H1T[64*68];
  __shared__ float csum[64];
  int tid = threadIdx.x, lane = tid & 63, w = tid >> 6;   // 8 waves
  if (tid < 384) W1s[tid>>6][tid&63] = W1f[tid];
  if (tid < 64) csum[tid] = 0.f;
  int rp = tid >> 4, cq = tid & 15, c0 = cq*4;
  float sca[4], sha[4];
  #pragma unroll
  for (int k=0;k<4;++k){ sca[k]=sc1v[c0+k]; sha[k]=sh1v[c0+k]; }
  int mt = w & 1, nt = (w>>1) & 1, kh = w >> 2;
  int arow = (mt*32 + (lane&31))*68;
  int brow = (nt*32 + (lane&31))*68;
  int ko = (lane>>5)*8;
  floatx16 acc;
  #pragma unroll
  for (int q=0;q<16;++q) acc[q]=0.f;
  float cs[4] = {0.f,0.f,0.f,0.f};
  int rpc = Mrows / gridDim.x;
  int r0 = blockIdx.x * rpc;
  __syncthreads();
  for (int rb=r0; rb<r0+rpc; rb+=64){
    {
      int r = tid>>3, e = tid&7;
      if (e < 6){
        int grow = rb + r;
        int bn = grow / Kk;
        int b = bn >> 12, n = bn & 4095;
        int j = idx[grow];
        const float* xb = x + b*3*Nn;
        fsh[r][e] = (e<3) ? xb[e*Nn + j] : xb[(e-3)*Nn + n];
      }
    }
    __syncthreads();
    {
      float y0[4]={0,0,0,0}, y1[4]={0,0,0,0};
      int ra = rp*2, rbw = rp*2+1;
      #pragma unroll
      for (int i=0;i<6;++i){
        float fa = fsh[ra][i], fb = fsh[rbw][i];
        float4 wv = *(const float4*)&W1s[i][c0];
        y0[0]=fmaf(fa,wv.x,y0[0]); y0[1]=fmaf(fa,wv.y,y0[1]);
        y0[2]=fmaf(fa,wv.z,y0[2]); y0[3]=fmaf(fa,wv.w,y0[3]);
        y1[0]=fmaf(fb,wv.x,y1[0]); y1[1]=fmaf(fb,wv.y,y1[1]);
        y1[2]=fmaf(fb,wv.z,y1[2]); y1[3]=fmaf(fb,wv.w,y1[3]);
      }
      #pragma unroll
      for (int k=0;k<4;++k){
        float va = fmaxf(fmaf(y0[k],sca[k],sha[k]),0.f);
        float vb = fmaxf(fmaf(y1[k],sca[k],sha[k]),0.f);
        cs[k] += va; cs[k] += vb;
        unsigned int pk = f2bu(va) | ((unsigned)f2bu(vb)<<16);
        *(unsigned int*)&H1T[(c0+k)*68 + ra] = pk;
      }
    }
    __syncthreads();
    {
      int kc = kh*32;
      #pragma unroll
      for (int s=0;s<2;++s){
        Frag a, b;
        const short* ap = &H1T[arow + kc + s*16 + ko];
        const short* bp = &H1T[brow + kc + s*16 + ko];
        a.u2[0] = *(const uint2*)ap;  a.u2[1] = *(const uint2*)(ap+4);
        b.u2[0] = *(const uint2*)bp;  b.u2[1] = *(const uint2*)(bp+4);
        acc = __builtin_amdgcn_mfma_f32_32x32x16_bf16(a.v, b.v, acc, 0, 0, 0);
      }
    }
    __syncthreads();
  }
  int col = lane & 31, rbase = 4*(lane>>5);
  #pragma unroll
  for (int r=0;r<16;++r){
    int row = (r&3) + 8*(r>>2) + rbase;
    atomicAdd(&G2[(size_t)(mt*32+row)*64 + nt*32+col], acc[r]);
  }
  #pragma unroll
  for (int k=0;k<4;++k) atomicAdd(&csum[c0+k], cs[k]);
  __syncthreads();
  if (tid < 64) atomicAdd(&sum2[tid], csum[tid]);
}

// ---------------- fused layers 1+2 ----------------
__global__ __launch_bounds__(64) void fl12_kernel(const float* __restrict__ x,
    const int* __restrict__ idx, const float* __restrict__ W1f,
    const float* __restrict__ sc1v, const float* __restrict__ sh1v,
    const float* __restrict__ W2f, const float* __restrict__ sc2v,
    const float* __restrict__ sh2v, bf16* __restrict__ H2, bf16* __restrict__ cat){
  __shared__ float fsh[Kk][6];
  __shared__ float h1[Kk][64];
  __shared__ float mm[4][64];
  int bn = blockIdx.x, b = bn>>12, n = bn & 4095;
  int tid = threadIdx.x;
  if (tid < Kk){
    int j = idx[(size_t)bn*Kk + tid];
    const float* xb = x + b*3*Nn;
    fsh[tid][0]=xb[j]; fsh[tid][1]=xb[Nn+j]; fsh[tid][2]=xb[2*Nn+j];
    fsh[tid][3]=xb[n]; fsh[tid][4]=xb[Nn+n]; fsh[tid][5]=xb[2*Nn+n];
  }
  __syncthreads();
  {
    float sc=sc1v[tid], sh=sh1v[tid];
    float w[6];
    #pragma unroll
    for (int i=0;i<6;++i) w[i]=W1f[i*64+tid];
    float mx = 0.f;
    #pragma unroll
    for (int r=0;r<Kk;++r){
      float y=0.f;
      #pragma unroll
      for (int i=0;i<6;++i) y = fmaf(fsh[r][i], w[i], y);
      float v = fmaxf(fmaf(y,sc,sh),0.f);
      h1[r][tid]=v;
      mx = fmaxf(mx,v);
    }
    cat[(size_t)bn*512 + tid] = f2b(mx);
  }
  __syncthreads();
  int q = tid >> 4, c0 = (tid & 15)*4;
  float acc[5][4]={};
  for (int i0=0;i0<64;i0+=4){
    float hv[5][4];
    #pragma unroll
    for (int l=0;l<5;++l){
      float4 t4 = *(const float4*)&h1[q*5+l][i0];
      hv[l][0]=t4.x; hv[l][1]=t4.y; hv[l][2]=t4.z; hv[l][3]=t4.w;
    }
    #pragma unroll
    for (int ii=0;ii<4;++ii){
      const float* wp = W2f + (i0+ii)*64 + c0;
      float w0=wp[0],w1=wp[1],w2=wp[2],w3=wp[3];
      #pragma unroll
      for (int l=0;l<5;++l){
        float hvv=hv[l][ii];
        acc[l][0]=fmaf(hvv,w0,acc[l][0]);
        acc[l][1]=fmaf(hvv,w1,acc[l][1]);
        acc[l][2]=fmaf(hvv,w2,acc[l][2]);
        acc[l][3]=fmaf(hvv,w3,acc[l][3]);
      }
    }
  }
  float sc[4],sh[4];
  #pragma unroll
  for (int cb=0;cb<4;++cb){ sc[cb]=sc2v[c0+cb]; sh[cb]=sh2v[c0+cb]; }
  float mx[4]={0,0,0,0};
  #pragma unroll
  for (int l=0;l<5;++l){
    unsigned short us[4];
    #pragma unroll
    for (int cb=0;cb<4;++cb){
      float v=fmaxf(fmaf(acc[l][cb],sc[cb],sh[cb]),0.f);
      mx[cb]=fmaxf(mx[cb],v);
      us[cb]=f2bu(v);
    }
    uint2 v2; v2.x = us[0]|((unsigned)us[1]<<16); v2.y=us[2]|((unsigned)us[3]<<16);
    *(uint2*)(H2 + ((size_t)bn*Kk + q*5+l)*64 + c0) = v2;
  }
  #pragma unroll
  for (int cb=0;cb<4;++cb) mm[q][c0+cb]=mx[cb];
  __syncthreads();
  {
    float M0 = fmaxf(fmaxf(mm[0][tid],mm[1][tid]),fmaxf(mm[2][tid],mm[3][tid]));
    cat[(size_t)bn*512 + 64 + tid] = f2b(M0);
  }
}

// ---------------- layer-4 stats: MFMA produce + MFMA Gram ----------------
__global__ __launch_bounds__(512) void stats4_kernel(const bf16* __restrict__ H2,
    const bf16* __restrict__ W3T, const float* __restrict__ sc3v, const float* __restrict__ sh3v,
    float* __restrict__ G4, float* __restrict__ sum4){
  __shared__ short h2s[64*68];
  __shared__ short H3T[128*68];
  __shared__ float csum[128];
  int tid = threadIdx.x, lane = tid & 63, w = tid >> 6;   // 8 waves
  if (tid < 128) csum[tid] = 0.f;
  int trow = tid >> 3, tc0 = (tid & 7)*8;
  int pl  = lane & 31;
  int ko  = (lane >> 5)*8;
  int pmt = w >> 2, pnt = w & 3;
  int parow = (pmt*32 + pl)*68;
  int pcol  = pnt*32 + pl;
  float psc = sc3v[pcol], psh = sh3v[pcol];
  int prbase = 4*(lane>>5);
  FragQ bfr[4];
  #pragma unroll
  for (int kq=0;kq<4;++kq)
    bfr[kq].q = *(const uint4*)&W3T[(size_t)pcol*64 + kq*16 + ko];
  int gmt = w>>1, gnt0 = (w&1)*2, gnt1 = gnt0+1;
  int garow  = (gmt*32 + pl)*68;
  int gbrow0 = (gnt0*32 + pl)*68;
  int gbrow1 = (gnt1*32 + pl)*68;
  floatx16 acc0, acc1;
  #pragma unroll
  for (int q=0;q<16;++q){ acc0[q]=0.f; acc1[q]=0.f; }
  float cs = 0.f;
  int rpc = Mrows / gridDim.x;
  int r0 = blockIdx.x * rpc;
  uint4 hreg = *(const uint4*)&H2[(size_t)(r0+trow)*64 + tc0];
  for (int rb=r0; rb<r0+rpc; rb+=64){
    {
      short* dst = &h2s[trow*68 + tc0];
      *(uint2*)dst       = make_uint2(hreg.x, hreg.y);
      *(uint2*)(dst + 4) = make_uint2(hreg.z, hreg.w);
    }
    if (rb + 64 < r0 + rpc)
      hreg = *(const uint4*)&H2[(size_t)(rb+64+trow)*64 + tc0];
    __syncthreads();
    {
      floatx16 pacc;
      #pragma unroll
      for (int q=0;q<16;++q) pacc[q]=0.f;
      #pragma unroll
      for (int kq=0;kq<4;++kq){
        Frag a;
        const short* ap = &h2s[parow + kq*16 + ko];
        a.u2[0] = *(const uint2*)ap;  a.u2[1] = *(const uint2*)(ap+4);
        pacc = __builtin_amdgcn_mfma_f32_32x32x16_bf16(a.v, bfr[kq].v, pacc, 0, 0, 0);
      }
      #pragma unroll
      for (int g=0; g<4; ++g){
        unsigned short p[4];
        #pragma unroll
        for (int r=0;r<4;++r){
          float v = fmaxf(fmaf(pacc[g*4+r], psc, psh), 0.f);
          cs += v;
          p[r] = f2bu(v);
        }
        uint2 pk; pk.x = p[0] | ((unsigned)p[1]<<16); pk.y = p[2] | ((unsigned)p[3]<<16);
        *(uint2*)&H3T[pcol*68 + pmt*32 + 8*g + prbase] = pk;
      }
    }
    __syncthreads();
    #pragma unroll
    for (int kc=0;kc<64;kc+=16){
      Frag a, b0, b1;
      const short* ap  = &H3T[garow  + kc + ko];
      const short* bp0 = &H3T[gbrow0 + kc + ko];
      const short* bp1 = &H3T[gbrow1 + kc + ko];
      a.u2[0]  = *(const uint2*)ap;   a.u2[1]  = *(const uint2*)(ap+4);
      b0.u2[0] = *(const uint2*)bp0;  b0.u2[1] = *(const uint2*)(bp0+4);
      b1.u2[0] = *(const uint2*)bp1;  b1.u2[1] = *(const uint2*)(bp1+4);
      acc0 = __builtin_amdgcn_mfma_f32_32x32x16_bf16(a.v, b0.v, acc0, 0, 0, 0);
      acc1 = __builtin_amdgcn_mfma_f32_32x32x16_bf16(a.v, b1.v, acc1, 0, 0, 0);
    }
  }
  int col = pl;
  #pragma unroll
  for (int r=0;r<16;++r){
    int row = (r&3) + 8*(r>>2) + prbase;
    atomicAdd(&G4[(size_t)(gmt*32+row)*128 + gnt0*32+col], acc0[r]);
    atomicAdd(&G4[(size_t)(gmt*32+row)*128 + gnt1*32+col], acc1[r]);
  }
  atomicAdd(&csum[pcol], cs);
  __syncthreads();
  if (tid < 128) atomicAdd(&sum4[tid], csum[tid]);
}

// ---------------- fused layers 3+4: MFMA produce chain + col-owner maxpool ----------------
__global__ __launch_bounds__(512,4) void fl34_kernel(const bf16* __restrict__ H2,
    const bf16* __restrict__ W3T, const float* __restrict__ sc3v, const float* __restrict__ sh3v,
    const bf16* __restrict__ W4T, const float* __restrict__ sc4v, const float* __restrict__ sh4v,
    bf16* __restrict__ cat){
  __shared__ short h2s[64*68];             // 8.5 KB
  __shared__ short h3s[64*132];            // 16.5 KB
  __shared__ unsigned short h4s[64*256];   // 32 KB
  __shared__ unsigned short mx3u[16*128];  // 4 KB
  __shared__ unsigned short mx4u[16*256];  // 8 KB
  int tid = threadIdx.x, lane = tid & 63, w = tid >> 6;
  int pl = lane & 31;
  int ko = (lane >> 5)*8;
  int rbase = 4*(lane>>5);
  {
    unsigned* p4 = (unsigned*)mx4u;
    for (int u=tid; u<2048; u+=512) p4[u]=0u;
    unsigned* p3 = (unsigned*)mx3u;
    for (int u=tid; u<1024; u+=512) p3[u]=0u;
  }
  int mt3 = w >> 2, ct3 = w & 3;
  int c3 = ct3*32 + pl;
  float sc3 = sc3v[c3], sh3 = sh3v[c3];
  int a3row = (mt3*32 + pl)*68;
  int c4 = w*32 + pl;
  float sc4 = sc4v[c4], sh4 = sh4v[c4];
  int trow = tid >> 3, tc0 = (tid & 7)*8;
  int r0 = blockIdx.x * 320;
  uint4 hreg = *(const uint4*)&H2[(size_t)(r0+trow)*64 + tc0];
  {
    short* dst = &h2s[trow*68 + tc0];
    *(uint2*)dst       = make_uint2(hreg.x, hreg.y);
    *(uint2*)(dst + 4) = make_uint2(hreg.z, hreg.w);
  }
  hreg = *(const uint4*)&H2[(size_t)(r0 + 64 + trow)*64 + tc0];
  __syncthreads();
  for (int t=0; t<5; ++t){
    {
      floatx16 pa;
      #pragma unroll
      for (int q=0;q<16;++q) pa[q]=0.f;
      #pragma unroll
      for (int kq=0;kq<4;++kq){
        Frag a; FragQ b;
        const short* ap = &h2s[a3row + kq*16 + ko];
        a.u2[0] = *(const uint2*)ap;  a.u2[1] = *(const uint2*)(ap+4);
        b.q = *(const uint4*)&W3T[(size_t)c3*64 + kq*16 + ko];
        pa = __builtin_amdgcn_mfma_f32_32x32x16_bf16(a.v, b.v, pa, 0, 0, 0);
      }
      #pragma unroll
      for (int r=0;r<16;++r){
        int m = mt3*32 + (r&3) + 8*(r>>2) + rbase;
        float v = fmaxf(fmaf(pa[r], sc3, sh3), 0.f);
        h3s[m*132 + c3] = (short)f2bu(v);
      }
    }
    __syncthreads();
    #pragma unroll
    for (int mt4=0; mt4<2; ++mt4){
      floatx16 acc;
      #pragma unroll
      for (int q=0;q<16;++q) acc[q]=0.f;
      int a4row = (mt4*32 + pl)*132;
      #pragma unroll
      for (int kq=0;kq<8;++kq){
        Frag a; FragQ b;
        const short* ap = &h3s[a4row + kq*16 + ko];
        a.u2[0] = *(const uint2*)ap;  a.u2[1] = *(const uint2*)(ap+4);
        b.q = *(const uint4*)&W4T[(size_t)c4*128 + kq*16 + ko];
        acc = __builtin_amdgcn_mfma_f32_32x32x16_bf16(a.v, b.v, acc, 0, 0, 0);
      }
      #pragma unroll
      for (int r=0;r<16;++r){
        int m = mt4*32 + (r&3) + 8*(r>>2) + rbase;
        float v = fmaxf(fmaf(acc[r], sc4, sh4), 0.f);
        h4s[m*256 + c4] = f2bu(v);
      }
    }
    __syncthreads();
    if (t < 4){
      short* dst = &h2s[trow*68 + tc0];
      *(uint2*)dst       = make_uint2(hreg.x, hreg.y);
      *(uint2*)(dst + 4) = make_uint2(hreg.z, hreg.w);
      if (t < 3) hreg = *(const uint4*)&H2[(size_t)(r0 + (t+2)*64 + trow)*64 + tc0];
    }
    {
      int lr0 = t*64;
      if (tid < 256){
        int c = tid;
        int p = lr0/20;
        int nb = (p+1)*20 - lr0;
        unsigned ml = 0;
        for (int r=0;r<64;++r){
          unsigned v = h4s[r*256 + c];
          ml = v > ml ? v : ml;
          if (--nb == 0){
            unsigned short* mp = &mx4u[p*256 + c];
            unsigned cur = *mp;
            if (ml > cur) *mp = (unsigned short)ml;
            ml = 0; ++p; nb = 20;
          }
        }
        if (nb != 20){
          unsigned short* mp = &mx4u[p*256 + c];
          unsigned cur = *mp;
          if (ml > cur) *mp = (unsigned short)ml;
        }
      } else if (tid < 384){
        int c = tid - 256;
        int p = lr0/20;
        int nb = (p+1)*20 - lr0;
        unsigned ml = 0;
        for (int r=0;r<64;++r){
          unsigned v = (unsigned)(unsigned short)h3s[r*132 + c];
          ml = v > ml ? v : ml;
          if (--nb == 0){
            unsigned short* mp = &mx3u[p*128 + c];
            unsigned cur = *mp;
            if (ml > cur) *mp = (unsigned short)ml;
            ml = 0; ++p; nb = 20;
          }
        }
        if (nb != 20){
          unsigned short* mp = &mx3u[p*128 + c];
          unsigned cur = *mp;
          if (ml > cur) *mp = (unsigned short)ml;
        }
      }
    }
    __syncthreads();
  }
  int bn0 = blockIdx.x*16;
  {
    int p = tid >> 5, c0 = (tid & 31)*8;
    uint4 v = *(const uint4*)&mx4u[p*256 + c0];
    *(uint4*)&cat[(size_t)(bn0+p)*512 + 256 + c0] = v;
  }
  if (tid < 256){
    int p = tid >> 4, c0 = (tid & 15)*8;
    uint4 v = *(const uint4*)&mx3u[p*128 + c0];
    *(uint4*)&cat[(size_t)(bn0+p)*512 + 128 + c0] = v;
  }
}

// ---------------- layer 5: MFMA GEMM + LDS-staged coalesced epilogue ----------------
__global__ __launch_bounds__(512) void l5_kernel(const bf16* __restrict__ cat,
                                                const bf16* __restrict__ W5T,
                                                const float* __restrict__ scale,
                                                const float* __restrict__ shift,
                                                float* __restrict__ out){
  __shared__ short cs[64*68];
  __shared__ float ob[64*129];
  int tid = threadIdx.x, lane = tid & 63, w = tid >> 6;
  int pl = lane & 31;
  int ko = (lane >> 5)*8;
  int rbase = 4*(lane>>5);
  int mt = w & 1, ntb = w >> 1;          // nt = ntb + 4*s, s=0..3
  int arow = (mt*32 + pl)*68;
  int trow = tid >> 3, tc0 = (tid & 7)*8;
  int r0 = blockIdx.x*64;
  floatx16 acc[4];
  #pragma unroll
  for (int s=0;s<4;++s)
    #pragma unroll
    for (int q=0;q<16;++q) acc[s][q]=0.f;
  const bf16* arow_g = cat + (size_t)(r0+trow)*512 + tc0;
  uint4 hreg = *(const uint4*)arow_g;
  for (int kc8=0; kc8<8; ++kc8){
    {
      short* dst = &cs[trow*68 + tc0];
      *(uint2*)dst       = make_uint2(hreg.x, hreg.y);
      *(uint2*)(dst + 4) = make_uint2(hreg.z, hreg.w);
    }
    if (kc8 < 7) hreg = *(const uint4*)(arow_g + (kc8+1)*64);
    __syncthreads();
    #pragma unroll
    for (int kq=0;kq<4;++kq){
      Frag a;
      const short* ap = &cs[arow + kq*16 + ko];
      a.u2[0] = *(const uint2*)ap;  a.u2[1] = *(const uint2*)(ap+4);
      #pragma unroll
      for (int s=0;s<4;++s){
        FragQ b;
        int col = (ntb + 4*s)*32 + pl;
        b.q = *(const uint4*)&W5T[(size_t)col*512 + kc8*64 + kq*16 + ko];
        acc[s] = __builtin_amdgcn_mfma_f32_32x32x16_bf16(a.v, b.v, acc[s], 0, 0, 0);
      }
    }
    __syncthreads();
  }
  int b = r0 >> 12, n0 = r0 & 4095;
  int colL = ntb*32 + pl;                // 0..127 within chunk
  int colc = tid >> 2, sub = tid & 3;    // writer mapping: 4 threads per col
  for (int s=0;s<4;++s){
    float sc = scale[128*s + colL], sh = shift[128*s + colL];
    #pragma unroll
    for (int q=0;q<16;++q){
      int m = mt*32 + (q&3) + 8*(q>>2) + rbase;
      ob[m*129 + colL] = fmaxf(fmaf(acc[s][q], sc, sh), 0.f);
    }
    __syncthreads();
    float* op = out + ((size_t)b*512 + 128*s + colc)*4096 + n0 + sub*16;
    #pragma unroll
    for (int j=0;j<4;++j){
      int rr = sub*16 + j*4;
      float4 v = make_float4(ob[(rr+0)*129 + colc], ob[(rr+1)*129 + colc],
                             ob[(rr+2)*129 + colc], ob[(rr+3)*129 + colc]);
      *(float4*)(op + j*4) = v;
    }
    __syncthreads();
  }
}

extern "C" void kernel_launch(void* const* d_in, const int* in_sizes, int n_in,
                              void* d_out, int out_size, void* d_ws, size_t ws_size,
                              hipStream_t stream){
  const float* x   = (const float*)d_in[0];
  const float* W1f = (const float*)d_in[1];
  const float* W2f = (const float*)d_in[2];
  const float* W3f = (const float*)d_in[3];
  const float* W4f = (const float*)d_in[4];
  const float* W5f = (const float*)d_in[5];
  const float* g1=(const float*)d_in[6],  *b1=(const float*)d_in[7];
  const float* g2=(const float*)d_in[8],  *b2=(const float*)d_in[9];
  const float* g3=(const float*)d_in[10], *b3=(const float*)d_in[11];
  const float* g4=(const float*)d_in[12], *b4=(const float*)d_in[13];
  const float* g5=(const float*)d_in[14], *b5=(const float*)d_in[15];
  float* out = (float*)d_out;

  char* w = (char*)d_ws;
  size_t off = 0;
  auto alloc = [&](size_t bytes)->void*{
    void* p = w + off;
    off = (off + bytes + 255) & ~(size_t)255;
    return p;
  };

  int*  idxb = (int*) alloc((size_t)BN*Kk*4);
  bf16* H2   = (bf16*)alloc((size_t)Mrows*64*2);
  bf16* catb = (bf16*)alloc((size_t)BN*512*2);
  bf16* W3T  = (bf16*)alloc((size_t)128*64*2);
  bf16* W4T  = (bf16*)alloc((size_t)256*128*2);
  bf16* W5T  = (bf16*)alloc((size_t)512*512*2);
  float* pv  = (float*)H2;
  int*   pib = (int*)((char*)H2 + (size_t)BN*8*Kk*4);

  size_t statsStart = off;
  float* partf=(float*)alloc(256*48*4);
  float* Gf=(float*)alloc(36*4);
  float* sumf=(float*)alloc(8*4);
  float* G2=(float*)alloc(4096*4);   float* sum2=(float*)alloc(64*4);
  float* G3=(float*)alloc(4096*4);   float* sum3=(float*)alloc(64*4);
  float* G4=(float*)alloc(16384*4);  float* sum4=(float*)alloc(128*4);
  float* G5=(float*)alloc(262144*4); float* sum5=(float*)alloc(512*4);
  float* P1=(float*)alloc(384*4);
  float* P2=(float*)alloc(4096*4);
  float* P3=(float*)alloc(8192*4);
  float* P4=(float*)alloc(32768*4);
  float* P5=(float*)alloc(262144*4);
  float* sc1=(float*)alloc(64*4);   float* sh1=(float*)alloc(64*4);
  float* sc2=(float*)alloc(64*4);   float* sh2=(float*)alloc(64*4);
  float* sc3=(float*)alloc(128*4);  float* sh3=(float*)alloc(128*4);
  float* sc4=(float*)alloc(256*4);  float* sh4=(float*)alloc(256*4);
  float* sc5=(float*)alloc(512*4);  float* sh5=(float*)alloc(512*4);
  size_t statsEnd = off;

  int statsFloats = (int)((statsEnd - statsStart)/4);
  zero_kernel<<<(statsFloats+255)/256,256,0,stream>>>((float*)(w+statsStart), statsFloats);
  w3t_kernel<<<32,256,0,stream>>>(W3f, W3T);
  w4t_kernel<<<128,256,0,stream>>>(W4f, W4T);
  w5t_kernel<<<1024,256,0,stream>>>(W5f, W5T);

  knnA_kernel<<<1024,256,0,stream>>>(x, pv, pib);
  knnB_kernel<<<BN/256,256,0,stream>>>(pv, pib, idxb);

  const float invM  = 1.0f/(float)Mrows;
  const float invM5 = 1.0f/(float)BN;

  gramf_kernel<<<256,256,0,stream>>>(x, idxb, partf);
  reducef_kernel<<<1,64,0,stream>>>(partf, Gf, sumf);
  kP_kernel<<<2,256,0,stream>>>(Gf, W1f, P1, 6, 64);
  kFinal_kernel<<<1,256,0,stream>>>(P1, sumf, W1f, g1, b1, sc1, sh1, 6, 64, invM);

  stats2_kernel<<<512,512,0,stream>>>(x, idxb, W1f, sc1, sh1, G2, sum2);
  kP_kernel<<<16,256,0,stream>>>(G2, W2f, P2, 64, 64);
  kFinal_kernel<<<1,256,0,stream>>>(P2, sum2, W2f, g2, b2, sc2, sh2, 64, 64, invM);

  fl12_kernel<<<BN,64,0,stream>>>(x, idxb, W1f, sc1, sh1, W2f, sc2, sh2, H2, catb);

  gram3_kernel<<<512,256,0,stream>>>(H2, Mrows, G3, sum3);
  kP_kernel<<<32,256,0,stream>>>(G3, W3f, P3, 64, 128);
  kFinal_kernel<<<1,256,0,stream>>>(P3, sum3, W3f, g3, b3, sc3, sh3, 64, 128, invM);

  stats4_kernel<<<512,512,0,stream>>>(H2, W3T, sc3, sh3, G4, sum4);
  kP_kernel<<<128,256,0,stream>>>(G4, W4f, P4, 128, 256);
  kFinal_kernel<<<1,256,0,stream>>>(P4, sum4, W4f, g4, b4, sc4, sh4, 128, 256, invM);

  fl34_kernel<<<Mrows/320,512,0,stream>>>(H2, W3T, sc3, sh3, W4T, sc4, sh4, catb);

  gram5_kernel<<<512,256,0,stream>>>(catb, G5, sum5);
  kP_kernel<<<1024,256,0,stream>>>(G5, W5f, P5, 512, 512);
  kFinal_kernel<<<2,256,0,stream>>>(P5, sum5, W5f, g5, b5, sc5, sh5, 512, 512, invM5);
  l5_kernel<<<BN/64,512,0,stream>>>(catb, W5T, sc5, sh5, out);
}

// Round 12
// 1245.379 us; speedup vs baseline: 1.2508x; 1.0228x over previous
//
#include <hip/hip_runtime.h>
#include <hip/hip_bf16.h>
#include <cfloat>

using bf16 = __hip_bfloat16;

typedef short short8 __attribute__((ext_vector_type(8)));
typedef float floatx16 __attribute__((ext_vector_type(16)));
union Frag { short8 v; uint2 u2[2]; };
union FragQ { short8 v; uint4 q; uint2 u2[2]; };
union U4b { uint4 q; unsigned short s[8]; };

constexpr int Bb = 8, Nn = 4096, Kk = 20;
constexpr int BN = Bb * Nn;                     // 32768
constexpr int Mrows = BN * Kk;                  // 655360
constexpr float EPSf = 1e-5f;

static __device__ __forceinline__ float b2f(bf16 v){ return __bfloat162float(v); }
static __device__ __forceinline__ bf16 f2b(float v){ return __float2bfloat16(v); }
static __device__ __forceinline__ unsigned short f2bu(float v){
  union { bf16 b; unsigned short u; } cv; cv.b = __float2bfloat16(v); return cv.u;
}
static __device__ __forceinline__ float bits2f(unsigned short u){
  union { unsigned int i; float f; } c; c.i = ((unsigned)u)<<16; return c.f;
}

// ---------------- zero workspace region ----------------
__global__ void zero_kernel(float* __restrict__ p, int n){
  int i = blockIdx.x*256 + threadIdx.x;
  if (i < n) p[i] = 0.f;
}

// ---------------- W3^T bf16 pack ----------------
__global__ void w3t_kernel(const float* __restrict__ W3f, bf16* __restrict__ W3T){
  int id = blockIdx.x*256 + threadIdx.x;   // 128*64 = 8192 elems
  if (id >= 128*64) return;
  int n = id >> 6, k = id & 63;
  W3T[id] = f2b(W3f[(size_t)k*128 + n]);
}

// ---------------- W4^T bf16 pack ----------------
__global__ void w4t_kernel(const float* __restrict__ W4f, bf16* __restrict__ W4T){
  int id = blockIdx.x*256 + threadIdx.x;   // 128*256 = 32768 elems
  if (id >= 128*256) return;
  int k = id >> 8, c = id & 255;           // coalesced read of W4f
  W4T[(size_t)c*128 + k] = f2b(W4f[id]);
}

// ---------------- W5^T bf16 pack ----------------
__global__ void w5t_kernel(const float* __restrict__ W5f, bf16* __restrict__ W5T){
  int id = blockIdx.x*256 + threadIdx.x;   // 512*512 = 262144 elems
  if (id >= 512*512) return;
  int k = id >> 9, c = id & 511;           // coalesced read of W5f
  W5T[(size_t)c*512 + k] = f2b(W5f[id]);
}

// ---------------- KNN phase A v8 (measured best: 143.6us, 81% VALUBusy) ----------
__global__ __launch_bounds__(256) void knnA_kernel(const float* __restrict__ x,
                                                   float* __restrict__ pv, int* __restrict__ pi){
#pragma clang fp contract(off)
  __shared__ float4 p4[512];
  __shared__ unsigned short lst[256*62];
  int blk = blockIdx.x;
  int stripe = blk & 7;
  int chunk  = (blk >> 3) & 15;
  int b      = blk >> 7;
  const float* xb = x + b*3*Nn;
  int j0 = stripe*512;
  for (int u = threadIdx.x; u < 512; u += 256){
    int j = j0 + u;
    float a0 = xb[j];
    float a1 = xb[Nn + j];
    float a2 = xb[2*Nn + j];
    float s = a0*a0; s = s + a1*a1; s = s + a2*a2;
    p4[u] = make_float4(a0, a1, a2, s);
  }
  __syncthreads();
  int i = chunk*256 + threadIdx.x;
  float xi = xb[i], yi = xb[Nn+i], zi = xb[2*Nn+i];
  float ni = xi*xi; ni = ni + yi*yi; ni = ni + zi*zi;
  float mni = -ni;
  float xi2 = xi + xi, yi2 = yi + yi, zi2 = zi + zi;
  float tv[Kk];
  #pragma unroll
  for (int s=0;s<Kk;++s) tv[s] = -FLT_MAX;
  for (int g=0; g<32; ++g){
    float gm = -FLT_MAX;
    #pragma unroll
    for (int e=0;e<16;++e){
      float4 p = p4[g*16+e];
      float base = mni - p.w;
      float nd = fmaf(xi2, p.x, fmaf(yi2, p.y, fmaf(zi2, p.z, base)));
      gm = fmaxf(gm, nd);
    }
    #pragma unroll
    for (int s=Kk-1; s>=1; --s)
      tv[s] = fmaxf(tv[s], fminf(tv[s-1], gm));
    tv[0] = fmaxf(tv[0], gm);
  }
  float thr = tv[Kk-1];
  thr = thr - (fabsf(thr)*1e-5f + 1e-6f);
  unsigned short* ml = &lst[threadIdx.x*62];
  int cnt = 0;
  for (int u=0; u<512; ++u){
    float4 p = p4[u];
    float base = mni - p.w;
    float nd = fmaf(xi2, p.x, fmaf(yi2, p.y, fmaf(zi2, p.z, base)));
    if (nd >= thr && cnt < 60){ ml[cnt] = (unsigned short)u; ++cnt; }
  }
  float av[Kk]; int ai[Kk];
  #pragma unroll
  for (int s=0;s<Kk;++s){ av[s] = -FLT_MAX; ai[s] = 0; }
  if (cnt >= 60){
    for (int u=0; u<512; ++u){
      float4 p = p4[u];
      float dot = xi*p.x; dot = dot + yi*p.y; dot = dot + zi*p.z;
      float inner = -2.0f*dot;
      float nd = mni - inner; nd = nd - p.w;
      if (nd > av[Kk-1]){
        #pragma unroll
        for (int s=Kk-1; s>=1; --s){
          bool cs = nd > av[s];
          bool cp = nd > av[s-1];
          av[s] = cs ? (cp ? av[s-1] : nd) : av[s];
          ai[s] = cs ? (cp ? ai[s-1] : (j0+u)) : ai[s];
        }
        if (nd > av[0]){ av[0] = nd; ai[0] = j0+u; }
      }
    }
  } else {
    for (int t=0; t<cnt; ++t){
      int lj = ml[t];
      float4 p = p4[lj];
      float dot = xi*p.x; dot = dot + yi*p.y; dot = dot + zi*p.z;
      float inner = -2.0f*dot;
      float nd = mni - inner; nd = nd - p.w;
      if (nd > av[Kk-1]){
        #pragma unroll
        for (int s=Kk-1; s>=1; --s){
          bool cs = nd > av[s];
          bool cp = nd > av[s-1];
          av[s] = cs ? (cp ? av[s-1] : nd) : av[s];
          ai[s] = cs ? (cp ? ai[s-1] : (j0+lj)) : ai[s];
        }
        if (nd > av[0]){ av[0] = nd; ai[0] = j0+lj; }
      }
    }
  }
  long long base = ((long long)(b*Nn + i)*8 + stripe)*Kk;
  #pragma unroll
  for (int s=0;s<Kk;++s){ pv[base+s] = av[s]; pi[base+s] = ai[s]; }
}

// ---------------- KNN phase B + fused layer-1 stats ----------------
// Merges 8 stripes -> idx. Then computes layer-1 feature stats using the
// in-register neighbor list (replaces gramf's 4M-row re-gather, 20x fewer ops):
// f = (nb, ctr); ctr constant per point =>
//   acc = [ Sum nb nb^T | (Sum nb) ctr^T ; ctr (Sum nb)^T | 20 ctr ctr^T ],
//   s6 = (Sum nb, 20 ctr). Block-reduced, per-block partials -> reducef.
__global__ __launch_bounds__(256) void knnB_kernel(const float* __restrict__ pv,
                                                   const int* __restrict__ pi,
                                                   const float* __restrict__ x,
                                                   int* __restrict__ idx,
                                                   float* __restrict__ part){
  int p = blockIdx.x*256 + threadIdx.x;    // grid 128 x 256 = BN exactly
  long long base = (long long)p*8*Kk;
  float av[Kk]; int ai[Kk];
  #pragma unroll
  for (int s=0;s<Kk;++s){ av[s]=pv[base+s]; ai[s]=pi[base+s]; }
  for (int t=Kk; t<8*Kk; ++t){
    float nd = pv[base+t]; int j = pi[base+t];
    if (nd > av[Kk-1]){
      #pragma unroll
      for (int s=Kk-1;s>=1;--s){
        bool cs = nd > av[s];
        bool cp = nd > av[s-1];
        av[s] = cs ? (cp?av[s-1]:nd) : av[s];
        ai[s] = cs ? (cp?ai[s-1]:j) : ai[s];
      }
      if (nd > av[0]){ av[0]=nd; ai[0]=j; }
    }
  }
  #pragma unroll
  for (int s=0;s<Kk;++s) idx[(long long)p*Kk+s] = ai[s];
  // ---- fused layer-1 stats ----
  int b = p >> 12, n = p & 4095;
  const float* xb = x + b*3*Nn;
  float cx = xb[n], cy = xb[Nn+n], cz = xb[2*Nn+n];
  float snx=0.f, sny=0.f, snz=0.f;
  float a00=0.f,a01=0.f,a02=0.f,a11=0.f,a12=0.f,a22=0.f;
  #pragma unroll
  for (int s=0;s<Kk;++s){
    int j = ai[s];
    float nx = xb[j], ny = xb[Nn+j], nz = xb[2*Nn+j];
    snx += nx; sny += ny; snz += nz;
    a00 = fmaf(nx,nx,a00); a01 = fmaf(nx,ny,a01); a02 = fmaf(nx,nz,a02);
    a11 = fmaf(ny,ny,a11); a12 = fmaf(ny,nz,a12); a22 = fmaf(nz,nz,a22);
  }
  float acc[36];
  // nb-nb block
  acc[0]=a00;  acc[1]=a01;  acc[2]=a02;
  acc[6]=a01;  acc[7]=a11;  acc[8]=a12;
  acc[12]=a02; acc[13]=a12; acc[14]=a22;
  // nb-ctr block (rows 0..2, cols 3..5): sn[a]*ctr[c]
  acc[3]=snx*cx;  acc[4]=snx*cy;  acc[5]=snx*cz;
  acc[9]=sny*cx;  acc[10]=sny*cy; acc[11]=sny*cz;
  acc[15]=snz*cx; acc[16]=snz*cy; acc[17]=snz*cz;
  // ctr-nb block (rows 3..5, cols 0..2): ctr[a]*sn[c]
  acc[18]=cx*snx; acc[19]=cx*sny; acc[20]=cx*snz;
  acc[24]=cy*snx; acc[25]=cy*sny; acc[26]=cy*snz;
  acc[30]=cz*snx; acc[31]=cz*sny; acc[32]=cz*snz;
  // ctr-ctr block: 20*ctr[a]*ctr[c]
  float k20 = (float)Kk;
  acc[21]=k20*cx*cx; acc[22]=k20*cx*cy; acc[23]=k20*cx*cz;
  acc[27]=k20*cy*cx; acc[28]=k20*cy*cy; acc[29]=k20*cy*cz;
  acc[33]=k20*cz*cx; acc[34]=k20*cz*cy; acc[35]=k20*cz*cz;
  float s6[6] = { snx, sny, snz, k20*cx, k20*cy, k20*cz };
  __shared__ float red[256];
  #pragma unroll
  for (int v=0; v<42; ++v){
    red[threadIdx.x] = (v<36)? acc[v] : s6[v-36];
    __syncthreads();
    for (int s=128; s>0; s>>=1){
      if (threadIdx.x < s) red[threadIdx.x] += red[threadIdx.x+s];
      __syncthreads();
    }
    if (threadIdx.x==0) part[blockIdx.x*48 + v] = red[0];
    __syncthreads();
  }
}

__global__ void reducef_kernel(const float* __restrict__ part, float* __restrict__ Gf,
                               float* __restrict__ sumf){
  int t = threadIdx.x;
  if (t < 42){
    float s = 0.f;
    for (int i=0;i<128;++i) s += part[i*48 + t];
    if (t<36) Gf[t]=s; else sumf[t-36]=s;
  }
}

// ---------------- G3 gram (CIN=64) with fused column sums ----------------
__global__ __launch_bounds__(256) void gram3_kernel(const bf16* __restrict__ H, int M,
                                                    float* __restrict__ G,
                                                    float* __restrict__ sumh){
  __shared__ short HTa[64*68];
  __shared__ float csum[64];
  int tid = threadIdx.x, lane = tid & 63, w = tid >> 6;
  if (tid < 64) csum[tid] = 0.f;
  int nchunks = gridDim.x;
  int rpc = M / nchunks;
  int r0 = blockIdx.x*rpc;
  int mt = w >> 1, nt = w & 1;
  floatx16 acc;
  #pragma unroll
  for (int q=0;q<16;++q) acc[q]=0.f;
  int arow = (mt*32 + (lane&31))*68;
  int brow = (nt*32 + (lane&31))*68;
  int ko = (lane>>5)*8;
  int c0s = (tid & 7)*8;
  float cs[8];
  #pragma unroll
  for (int j=0;j<8;++j) cs[j]=0.f;
  for (int rb=r0; rb<r0+rpc; rb+=64){
    #pragma unroll
    for (int s=0;s<2;++s){
      int e = tid + s*256;
      int row = e >> 3;
      U4b va; va.q = *(const uint4*)&H[(size_t)(rb+row)*64 + c0s];
      #pragma unroll
      for (int j=0;j<8;++j){
        HTa[(c0s+j)*68 + row] = (short)va.s[j];
        cs[j] += bits2f(va.s[j]);
      }
    }
    __syncthreads();
    #pragma unroll
    for (int kc=0;kc<64;kc+=16){
      Frag a, b;
      const short* ap = &HTa[arow + kc + ko];
      const short* bp = &HTa[brow + kc + ko];
      a.u2[0] = *(const uint2*)ap;  a.u2[1] = *(const uint2*)(ap+4);
      b.u2[0] = *(const uint2*)bp;  b.u2[1] = *(const uint2*)(bp+4);
      acc = __builtin_amdgcn_mfma_f32_32x32x16_bf16(a.v, b.v, acc, 0, 0, 0);
    }
    __syncthreads();
  }
  int col = lane & 31, rbase = 4*(lane>>5);
  #pragma unroll
  for (int r=0;r<16;++r){
    int row = (r&3) + 8*(r>>2) + rbase;
    atomicAdd(&G[(size_t)(mt*32 + row)*64 + nt*32 + col], acc[r]);
  }
  #pragma unroll
  for (int j=0;j<8;++j) atomicAdd(&csum[c0s+j], cs[j]);
  __syncthreads();
  if (tid < 64) atomicAdd(&sumh[tid], csum[tid]);
}

// ---------------- G5 gram (CIN=512): 128-wide tiles + fused column sums ----------------
__global__ __launch_bounds__(256) void gram5_kernel(const bf16* __restrict__ H,
                                                    float* __restrict__ G,
                                                    float* __restrict__ sumh){
  __shared__ short HTa[128*68];
  __shared__ short HTb[128*68];
  __shared__ float csum[128];
  int blk = blockIdx.x;
  int pair = blk & 15;
  int chunk = blk >> 4;            // 0..31
  int tr = pair >> 2, tc = pair & 3;
  bool diag = (tr == tc);
  int tid = threadIdx.x, lane = tid & 63, w = tid >> 6;   // 4 waves
  if (tid < 128) csum[tid] = 0.f;
  int rpc = BN / 32;               // 1024
  int r0 = chunk*rpc;
  int pl = lane & 31, ko = (lane>>5)*8, rbase = 4*(lane>>5);
  int mt = w;
  int arow = (mt*32 + pl)*68;
  floatx16 acc[4];
  #pragma unroll
  for (int nt=0;nt<4;++nt)
    #pragma unroll
    for (int q=0;q<16;++q) acc[nt][q]=0.f;
  int c0s = (tid & 15)*8;
  float cs[8];
  #pragma unroll
  for (int j=0;j<8;++j) cs[j]=0.f;
  const short* Bbase = diag ? HTa : HTb;
  for (int rb=r0; rb<r0+rpc; rb+=64){
    #pragma unroll
    for (int s=0;s<4;++s){
      int e = tid + s*256;
      int row = e >> 4;
      U4b va; va.q = *(const uint4*)&H[(size_t)(rb+row)*512 + tr*128 + c0s];
      #pragma unroll
      for (int j=0;j<8;++j) HTa[(c0s+j)*68 + row] = (short)va.s[j];
      if (diag){
        #pragma unroll
        for (int j=0;j<8;++j) cs[j] += bits2f(va.s[j]);
      } else {
        U4b vb; vb.q = *(const uint4*)&H[(size_t)(rb+row)*512 + tc*128 + c0s];
        #pragma unroll
        for (int j=0;j<8;++j) HTb[(c0s+j)*68 + row] = (short)vb.s[j];
      }
    }
    __syncthreads();
    #pragma unroll
    for (int kc=0;kc<64;kc+=16){
      Frag a;
      const short* ap = &HTa[arow + kc + ko];
      a.u2[0] = *(const uint2*)ap;  a.u2[1] = *(const uint2*)(ap+4);
      #pragma unroll
      for (int nt=0;nt<4;++nt){
        Frag b;
        const short* bp = &Bbase[(nt*32 + pl)*68 + kc + ko];
        b.u2[0] = *(const uint2*)bp;  b.u2[1] = *(const uint2*)(bp+4);
        acc[nt] = __builtin_amdgcn_mfma_f32_32x32x16_bf16(a.v, b.v, acc[nt], 0, 0, 0);
      }
    }
    __syncthreads();
  }
  #pragma unroll
  for (int nt=0;nt<4;++nt){
    #pragma unroll
    for (int r=0;r<16;++r){
      int row = (r&3) + 8*(r>>2) + rbase;
      atomicAdd(&G[(size_t)(tr*128 + mt*32 + row)*512 + tc*128 + nt*32 + pl], acc[nt][r]);
    }
  }
  if (diag){
    #pragma unroll
    for (int j=0;j<8;++j) atomicAdd(&csum[c0s+j], cs[j]);
    __syncthreads();
    if (tid < 128) atomicAdd(&sumh[tr*128 + tid], csum[tid]);
  }
}

// ---------------- P = G @ W ----------------
__global__ void kP_kernel(const float* __restrict__ G, const float* __restrict__ Wf,
                          float* __restrict__ P, int Cin, int Cout){
  int id = blockIdx.x*256 + threadIdx.x;
  if (id >= Cin*Cout) return;
  int i = id / Cout, j = id - i*Cout;
  float s = 0.f;
  for (int k=0;k<Cin;++k) s = fmaf(G[(size_t)i*Cin+k], Wf[(size_t)k*Cout+j], s);
  P[id] = s;
}

// ---------------- scale/shift from Gram-derived BN stats ----------------
__global__ void kFinal_kernel(const float* __restrict__ P, const float* __restrict__ sumh,
                              const float* __restrict__ Wf, const float* __restrict__ g,
                              const float* __restrict__ bb, float* __restrict__ scale,
                              float* __restrict__ shift, int Cin, int Cout, float invM){
  int j = blockIdx.x*256 + threadIdx.x;
  if (j >= Cout) return;
  float mean=0.f, e2=0.f;
  for (int i=0;i<Cin;++i){
    float w = Wf[(size_t)i*Cout + j];
    mean = fmaf(sumh[i], w, mean);
    e2   = fmaf(w, P[(size_t)i*Cout + j], e2);
  }
  mean *= invM; e2 *= invM;
  float var = e2 - mean*mean;
  float inv = rsqrtf(var + EPSf);
  float sc = g[j]*inv;
  scale[j]=sc;
  shift[j]=bb[j] - mean*sc;
}

// ---------------- layer-2 stats ----------------
__global__ __launch_bounds__(512) void stats2_kernel(const float* __restrict__ x,
    const int* __restrict__ idx, const float* __restrict__ W1f,
    const float* __restrict__ sc1v, const float* __restrict__ sh1v,
    float* __restrict__ G2, float* __restrict__ sum2){
  __shared__ float W1s[6][64];
  __shared__ float fsh[64][8];
  __shared__ short H1T[64*68];
  __shared__ float csum[64];
  int tid = threadIdx.x, lane = tid & 63, w = tid >> 6;   // 8 waves
  if (tid < 384) W1s[tid>>6][tid&63] = W1f[tid];
  if (tid < 64) csum[tid] = 0.f;
  int rp = tid >> 4, cq = tid & 15, c0 = cq*4;
  float sca[4], sha[4];
  #pragma unroll
  for (int k=0;k<4;++k){ sca[k]=sc1v[c0+k]; sha[k]=sh1v[c0+k]; }
  int mt = w & 1, nt = (w>>1) & 1, kh = w >> 2;
  int arow = (mt*32 + (lane&31))*68;
  int brow = (nt*32 + (lane&31))*68;
  int ko = (lane>>5)*8;
  floatx16 acc;
  #pragma unroll
  for (int q=0;q<16;++q) acc[q]=0.f;
  float cs[4] = {0.f,0.f,0.f,0.f};
  int rpc = Mrows / gridDim.x;
  int r0 = blockIdx.x * rpc;
  __syncthreads();
  for (int rb=r0; rb<r0+rpc; rb+=64){
    {
      int r = tid>>3, e = tid&7;
      if (e < 6){
        int grow = rb + r;
        int bn = grow / Kk;
        int b = bn >> 12, n = bn & 4095;
        int j = idx[grow];
        const float* xb = x + b*3*Nn;
        fsh[r][e] = (e<3) ? xb[e*Nn + j] : xb[(e-3)*Nn + n];
      }
    }
    __syncthreads();
    {
      float y0[4]={0,0,0,0}, y1[4]={0,0,0,0};
      int ra = rp*2, rbw = rp*2+1;
      #pragma unroll
      for (int i=0;i<6;++i){
        float fa = fsh[ra][i], fb = fsh[rbw][i];
        float4 wv = *(const float4*)&W1s[i][c0];
        y0[0]=fmaf(fa,wv.x,y0[0]); y0[1]=fmaf(fa,wv.y,y0[1]);
        y0[2]=fmaf(fa,wv.z,y0[2]); y0[3]=fmaf(fa,wv.w,y0[3]);
        y1[0]=fmaf(fb,wv.x,y1[0]); y1[1]=fmaf(fb,wv.y,y1[1]);
        y1[2]=fmaf(fb,wv.z,y1[2]); y1[3]=fmaf(fb,wv.w,y1[3]);
      }
      #pragma unroll
      for (int k=0;k<4;++k){
        float va = fmaxf(fmaf(y0[k],sca[k],sha[k]),0.f);
        float vb = fmaxf(fmaf(y1[k],sca[k],sha[k]),0.f);
        cs[k] += va; cs[k] += vb;
        unsigned int pk = f2bu(va) | ((unsigned)f2bu(vb)<<16);
        *(unsigned int*)&H1T[(c0+k)*68 + ra] = pk;
      }
    }
    __syncthreads();
    {
      int kc = kh*32;
      #pragma unroll
      for (int s=0;s<2;++s){
        Frag a, b;
        const short* ap = &H1T[arow + kc + s*16 + ko];
        const short* bp = &H1T[brow + kc + s*16 + ko];
        a.u2[0] = *(const uint2*)ap;  a.u2[1] = *(const uint2*)(ap+4);
        b.u2[0] = *(const uint2*)bp;  b.u2[1] = *(const uint2*)(bp+4);
        acc = __builtin_amdgcn_mfma_f32_32x32x16_bf16(a.v, b.v, acc, 0, 0, 0);
      }
    }
    __syncthreads();
  }
  int col = lane & 31, rbase = 4*(lane>>5);
  #pragma unroll
  for (int r=0;r<16;++r){
    int row = (r&3) + 8*(r>>2) + rbase;
    atomicAdd(&G2[(size_t)(mt*32+row)*64 + nt*32+col], acc[r]);
  }
  #pragma unroll
  for (int k=0;k<4;++k) atomicAdd(&csum[c0+k], cs[k]);
  __syncthreads();
  if (tid < 64) atomicAdd(&sum2[tid], csum[tid]);
}

// ---------------- fused layers 1+2 ----------------
__global__ __launch_bounds__(64) void fl12_kernel(const float* __restrict__ x,
    const int* __restrict__ idx, const float* __restrict__ W1f,
    const float* __restrict__ sc1v, const float* __restrict__ sh1v,
    const float* __restrict__ W2f, const float* __restrict__ sc2v,
    const float* __restrict__ sh2v, bf16* __restrict__ H2, bf16* __restrict__ cat){
  __shared__ float fsh[Kk][6];
  __shared__ float h1[Kk][64];
  __shared__ float mm[4][64];
  int bn = blockIdx.x, b = bn>>12, n = bn & 4095;
  int tid = threadIdx.x;
  if (tid < Kk){
    int j = idx[(size_t)bn*Kk + tid];
    const float* xb = x + b*3*Nn;
    fsh[tid][0]=xb[j]; fsh[tid][1]=xb[Nn+j]; fsh[tid][2]=xb[2*Nn+j];
    fsh[tid][3]=xb[n]; fsh[tid][4]=xb[Nn+n]; fsh[tid][5]=xb[2*Nn+n];
  }
  __syncthreads();
  {
    float sc=sc1v[tid], sh=sh1v[tid];
    float w[6];
    #pragma unroll
    for (int i=0;i<6;++i) w[i]=W1f[i*64+tid];
    float mx = 0.f;
    #pragma unroll
    for (int r=0;r<Kk;++r){
      float y=0.f;
      #pragma unroll
      for (int i=0;i<6;++i) y = fmaf(fsh[r][i], w[i], y);
      float v = fmaxf(fmaf(y,sc,sh),0.f);
      h1[r][tid]=v;
      mx = fmaxf(mx,v);
    }
    cat[(size_t)bn*512 + tid] = f2b(mx);
  }
  __syncthreads();
  int q = tid >> 4, c0 = (tid & 15)*4;
  float acc[5][4]={};
  for (int i0=0;i0<64;i0+=4){
    float hv[5][4];
    #pragma unroll
    for (int l=0;l<5;++l){
      float4 t4 = *(const float4*)&h1[q*5+l][i0];
      hv[l][0]=t4.x; hv[l][1]=t4.y; hv[l][2]=t4.z; hv[l][3]=t4.w;
    }
    #pragma unroll
    for (int ii=0;ii<4;++ii){
      const float* wp = W2f + (i0+ii)*64 + c0;
      float w0=wp[0],w1=wp[1],w2=wp[2],w3=wp[3];
      #pragma unroll
      for (int l=0;l<5;++l){
        float hvv=hv[l][ii];
        acc[l][0]=fmaf(hvv,w0,acc[l][0]);
        acc[l][1]=fmaf(hvv,w1,acc[l][1]);
        acc[l][2]=fmaf(hvv,w2,acc[l][2]);
        acc[l][3]=fmaf(hvv,w3,acc[l][3]);
      }
    }
  }
  float sc[4],sh[4];
  #pragma unroll
  for (int cb=0;cb<4;++cb){ sc[cb]=sc2v[c0+cb]; sh[cb]=sh2v[c0+cb]; }
  float mx[4]={0,0,0,0};
  #pragma unroll
  for (int l=0;l<5;++l){
    unsigned short us[4];
    #pragma unroll
    for (int cb=0;cb<4;++cb){
      float v=fmaxf(fmaf(acc[l][cb],sc[cb],sh[cb]),0.f);
      mx[cb]=fmaxf(mx[cb],v);
      us[cb]=f2bu(v);
    }
    uint2 v2; v2.x = us[0]|((unsigned)us[1]<<16); v2.y=us[2]|((unsigned)us[3]<<16);
    *(uint2*)(H2 + ((size_t)bn*Kk + q*5+l)*64 + c0) = v2;
  }
  #pragma unroll
  for (int cb=0;cb<4;++cb) mm[q][c0+cb]=mx[cb];
  __syncthreads();
  {
    float M0 = fmaxf(fmaxf(mm[0][tid],mm[1][tid]),fmaxf(mm[2][tid],mm[3][tid]));
    cat[(size_t)bn*512 + 64 + tid] = f2b(M0);
  }
}

// ---------------- layer-4 stats: MFMA produce + MFMA Gram ----------------
__global__ __launch_bounds__(512) void stats4_kernel(const bf16* __restrict__ H2,
    const bf16* __restrict__ W3T, const float* __restrict__ sc3v, const float* __restrict__ sh3v,
    float* __restrict__ G4, float* __restrict__ sum4){
  __shared__ short h2s[64*68];
  __shared__ short H3T[128*68];
  __shared__ float csum[128];
  int tid = threadIdx.x, lane = tid & 63, w = tid >> 6;   // 8 waves
  if (tid < 128) csum[tid] = 0.f;
  int trow = tid >> 3, tc0 = (tid & 7)*8;
  int pl  = lane & 31;
  int ko  = (lane >> 5)*8;
  int pmt = w >> 2, pnt = w & 3;
  int parow = (pmt*32 + pl)*68;
  int pcol  = pnt*32 + pl;
  float psc = sc3v[pcol], psh = sh3v[pcol];
  int prbase = 4*(lane>>5);
  FragQ bfr[4];
  #pragma unroll
  for (int kq=0;kq<4;++kq)
    bfr[kq].q = *(const uint4*)&W3T[(size_t)pcol*64 + kq*16 + ko];
  int gmt = w>>1, gnt0 = (w&1)*2, gnt1 = gnt0+1;
  int garow  = (gmt*32 + pl)*68;
  int gbrow0 = (gnt0*32 + pl)*68;
  int gbrow1 = (gnt1*32 + pl)*68;
  floatx16 acc0, acc1;
  #pragma unroll
  for (int q=0;q<16;++q){ acc0[q]=0.f; acc1[q]=0.f; }
  float cs = 0.f;
  int rpc = Mrows / gridDim.x;
  int r0 = blockIdx.x * rpc;
  uint4 hreg = *(const uint4*)&H2[(size_t)(r0+trow)*64 + tc0];
  for (int rb=r0; rb<r0+rpc; rb+=64){
    {
      short* dst = &h2s[trow*68 + tc0];
      *(uint2*)dst       = make_uint2(hreg.x, hreg.y);
      *(uint2*)(dst + 4) = make_uint2(hreg.z, hreg.w);
    }
    if (rb + 64 < r0 + rpc)
      hreg = *(const uint4*)&H2[(size_t)(rb+64+trow)*64 + tc0];
    __syncthreads();
    {
      floatx16 pacc;
      #pragma unroll
      for (int q=0;q<16;++q) pacc[q]=0.f;
      #pragma unroll
      for (int kq=0;kq<4;++kq){
        Frag a;
        const short* ap = &h2s[parow + kq*16 + ko];
        a.u2[0] = *(const uint2*)ap;  a.u2[1] = *(const uint2*)(ap+4);
        pacc = __builtin_amdgcn_mfma_f32_32x32x16_bf16(a.v, bfr[kq].v, pacc, 0, 0, 0);
      }
      #pragma unroll
      for (int g=0; g<4; ++g){
        unsigned short p[4];
        #pragma unroll
        for (int r=0;r<4;++r){
          float v = fmaxf(fmaf(pacc[g*4+r], psc, psh), 0.f);
          cs += v;
          p[r] = f2bu(v);
        }
        uint2 pk; pk.x = p[0] | ((unsigned)p[1]<<16); pk.y = p[2] | ((unsigned)p[3]<<16);
        *(uint2*)&H3T[pcol*68 + pmt*32 + 8*g + prbase] = pk;
      }
    }
    __syncthreads();
    #pragma unroll
    for (int kc=0;kc<64;kc+=16){
      Frag a, b0, b1;
      const short* ap  = &H3T[garow  + kc + ko];
      const short* bp0 = &H3T[gbrow0 + kc + ko];
      const short* bp1 = &H3T[gbrow1 + kc + ko];
      a.u2[0]  = *(const uint2*)ap;   a.u2[1]  = *(const uint2*)(ap+4);
      b0.u2[0] = *(const uint2*)bp0;  b0.u2[1] = *(const uint2*)(bp0+4);
      b1.u2[0] = *(const uint2*)bp1;  b1.u2[1] = *(const uint2*)(bp1+4);
      acc0 = __builtin_amdgcn_mfma_f32_32x32x16_bf16(a.v, b0.v, acc0, 0, 0, 0);
      acc1 = __builtin_amdgcn_mfma_f32_32x32x16_bf16(a.v, b1.v, acc1, 0, 0, 0);
    }
  }
  int col = pl;
  #pragma unroll
  for (int r=0;r<16;++r){
    int row = (r&3) + 8*(r>>2) + prbase;
    atomicAdd(&G4[(size_t)(gmt*32+row)*128 + gnt0*32+col], acc0[r]);
    atomicAdd(&G4[(size_t)(gmt*32+row)*128 + gnt1*32+col], acc1[r]);
  }
  atomicAdd(&csum[pcol], cs);
  __syncthreads();
  if (tid < 128) atomicAdd(&sum4[tid], csum[tid]);
}

// ---------------- fused layers 3+4: MFMA produce chain + col-owner maxpool ----------------
__global__ __launch_bounds__(512,4) void fl34_kernel(const bf16* __restrict__ H2,
    const bf16* __restrict__ W3T, const float* __restrict__ sc3v, const float* __restrict__ sh3v,
    const bf16* __restrict__ W4T, const float* __restrict__ sc4v, const float* __restrict__ sh4v,
    bf16* __restrict__ cat){
  __shared__ short h2s[64*68];             // 8.5 KB
  __shared__ short h3s[64*132];            // 16.5 KB
  __shared__ unsigned short h4s[64*256];   // 32 KB
  __shared__ unsigned short mx3u[16*128];  // 4 KB
  __shared__ unsigned short mx4u[16*256];  // 8 KB
  int tid = threadIdx.x, lane = tid & 63, w = tid >> 6;
  int pl = lane & 31;
  int ko = (lane >> 5)*8;
  int rbase = 4*(lane>>5);
  {
    unsigned* p4 = (unsigned*)mx4u;
    for (int u=tid; u<2048; u+=512) p4[u]=0u;
    unsigned* p3 = (unsigned*)mx3u;
    for (int u=tid; u<1024; u+=512) p3[u]=0u;
  }
  int mt3 = w >> 2, ct3 = w & 3;
  int c3 = ct3*32 + pl;
  float sc3 = sc3v[c3], sh3 = sh3v[c3];
  int a3row = (mt3*32 + pl)*68;
  int c4 = w*32 + pl;
  float sc4 = sc4v[c4], sh4 = sh4v[c4];
  int trow = tid >> 3, tc0 = (tid & 7)*8;
  int r0 = blockIdx.x * 320;
  uint4 hreg = *(const uint4*)&H2[(size_t)(r0+trow)*64 + tc0];
  {
    short* dst = &h2s[trow*68 + tc0];
    *(uint2*)dst       = make_uint2(hreg.x, hreg.y);
    *(uint2*)(dst + 4) = make_uint2(hreg.z, hreg.w);
  }
  hreg = *(const uint4*)&H2[(size_t)(r0 + 64 + trow)*64 + tc0];
  __syncthreads();
  for (int t=0; t<5; ++t){
    {
      floatx16 pa;
      #pragma unroll
      for (int q=0;q<16;++q) pa[q]=0.f;
      #pragma unroll
      for (int kq=0;kq<4;++kq){
        Frag a; FragQ b;
        const short* ap = &h2s[a3row + kq*16 + ko];
        a.u2[0] = *(const uint2*)ap;  a.u2[1] = *(const uint2*)(ap+4);
        b.q = *(const uint4*)&W3T[(size_t)c3*64 + kq*16 + ko];
        pa = __builtin_amdgcn_mfma_f32_32x32x16_bf16(a.v, b.v, pa, 0, 0, 0);
      }
      #pragma unroll
      for (int r=0;r<16;++r){
        int m = mt3*32 + (r&3) + 8*(r>>2) + rbase;
        float v = fmaxf(fmaf(pa[r], sc3, sh3), 0.f);
        h3s[m*132 + c3] = (short)f2bu(v);
      }
    }
    __syncthreads();
    #pragma unroll
    for (int mt4=0; mt4<2; ++mt4){
      floatx16 acc;
      #pragma unroll
      for (int q=0;q<16;++q) acc[q]=0.f;
      int a4row = (mt4*32 + pl)*132;
      #pragma unroll
      for (int kq=0;kq<8;++kq){
        Frag a; FragQ b;
        const short* ap = &h3s[a4row + kq*16 + ko];
        a.u2[0] = *(const uint2*)ap;  a.u2[1] = *(const uint2*)(ap+4);
        b.q = *(const uint4*)&W4T[(size_t)c4*128 + kq*16 + ko];
        acc = __builtin_amdgcn_mfma_f32_32x32x16_bf16(a.v, b.v, acc, 0, 0, 0);
      }
      #pragma unroll
      for (int r=0;r<16;++r){
        int m = mt4*32 + (r&3) + 8*(r>>2) + rbase;
        float v = fmaxf(fmaf(acc[r], sc4, sh4), 0.f);
        h4s[m*256 + c4] = f2bu(v);
      }
    }
    __syncthreads();
    if (t < 4){
      short* dst = &h2s[trow*68 + tc0];
      *(uint2*)dst       = make_uint2(hreg.x, hreg.y);
      *(uint2*)(dst + 4) = make_uint2(hreg.z, hreg.w);
      if (t < 3) hreg = *(const uint4*)&H2[(size_t)(r0 + (t+2)*64 + trow)*64 + tc0];
    }
    {
      int lr0 = t*64;
      if (tid < 256){
        int c = tid;
        int p = lr0/20;
        int nb = (p+1)*20 - lr0;
        unsigned ml = 0;
        for (int r=0;r<64;++r){
          unsigned v = h4s[r*256 + c];
          ml = v > ml ? v : ml;
          if (--nb == 0){
            unsigned short* mp = &mx4u[p*256 + c];
            unsigned cur = *mp;
            if (ml > cur) *mp = (unsigned short)ml;
            ml = 0; ++p; nb = 20;
          }
        }
        if (nb != 20){
          unsigned short* mp = &mx4u[p*256 + c];
          unsigned cur = *mp;
          if (ml > cur) *mp = (unsigned short)ml;
        }
      } else if (tid < 384){
        int c = tid - 256;
        int p = lr0/20;
        int nb = (p+1)*20 - lr0;
        unsigned ml = 0;
        for (int r=0;r<64;++r){
          unsigned v = (unsigned)(unsigned short)h3s[r*132 + c];
          ml = v > ml ? v : ml;
          if (--nb == 0){
            unsigned short* mp = &mx3u[p*128 + c];
            unsigned cur = *mp;
            if (ml > cur) *mp = (unsigned short)ml;
            ml = 0; ++p; nb = 20;
          }
        }
        if (nb != 20){
          unsigned short* mp = &mx3u[p*128 + c];
          unsigned cur = *mp;
          if (ml > cur) *mp = (unsigned short)ml;
        }
      }
    }
    __syncthreads();
  }
  int bn0 = blockIdx.x*16;
  {
    int p = tid >> 5, c0 = (tid & 31)*8;
    uint4 v = *(const uint4*)&mx4u[p*256 + c0];
    *(uint4*)&cat[(size_t)(bn0+p)*512 + 256 + c0] = v;
  }
  if (tid < 256){
    int p = tid >> 4, c0 = (tid & 15)*8;
    uint4 v = *(const uint4*)&mx3u[p*128 + c0];
    *(uint4*)&cat[(size_t)(bn0+p)*512 + 128 + c0] = v;
  }
}

// ---------------- layer 5 v4: double-buffered A-tiles + ob union (9 barriers vs 16) ----
// cs2[2][64*68] (17.4KB) aliases the epilogue ob buffer (33KB): LDS 41.7->33KB.
// Stage tile kc8+1 into cs2[cur^1] while computing from cs2[cur]; one barrier/iter.
__global__ __launch_bounds__(512) void l5_kernel(const bf16* __restrict__ cat,
                                                const bf16* __restrict__ W5T,
                                                const float* __restrict__ scale,
                                                const float* __restrict__ shift,
                                                float* __restrict__ out){
  __shared__ float obu[64*129];            // 33024 B; aliased as cs2[2][64*68] (17408 B)
  short* cs2 = (short*)obu;
  float* ob = obu;
  int tid = threadIdx.x, lane = tid & 63, w = tid >> 6;
  int pl = lane & 31;
  int ko = (lane >> 5)*8;
  int rbase = 4*(lane>>5);
  int mt = w & 1, ntb = w >> 1;          // nt = ntb + 4*s, s=0..3
  int arow = (mt*32 + pl)*68;
  int trow = tid >> 3, tc0 = (tid & 7)*8;
  int r0 = blockIdx.x*64;
  floatx16 acc[4];
  #pragma unroll
  for (int s=0;s<4;++s)
    #pragma unroll
    for (int q=0;q<16;++q) acc[s][q]=0.f;
  const bf16* arow_g = cat + (size_t)(r0+trow)*512 + tc0;
  // prologue: stage tile 0, prefetch tile 1
  uint4 hreg = *(const uint4*)arow_g;
  {
    short* dst = &cs2[trow*68 + tc0];
    *(uint2*)dst       = make_uint2(hreg.x, hreg.y);
    *(uint2*)(dst + 4) = make_uint2(hreg.z, hreg.w);
  }
  hreg = *(const uint4*)(arow_g + 64);
  __syncthreads();
  for (int kc8=0; kc8<8; ++kc8){
    int cur = kc8 & 1;
    // stage next tile into the other buffer (overlaps with MFMA below)
    if (kc8 < 7){
      short* dst = &cs2[(cur^1)*64*68 + trow*68 + tc0];
      *(uint2*)dst       = make_uint2(hreg.x, hreg.y);
      *(uint2*)(dst + 4) = make_uint2(hreg.z, hreg.w);
      if (kc8 < 6) hreg = *(const uint4*)(arow_g + (kc8+2)*64);
    }
    const short* csb = cs2 + cur*64*68;
    #pragma unroll
    for (int kq=0;kq<4;++kq){
      Frag a;
      const short* ap = &csb[arow + kq*16 + ko];
      a.u2[0] = *(const uint2*)ap;  a.u2[1] = *(const uint2*)(ap+4);
      #pragma unroll
      for (int s=0;s<4;++s){
        FragQ b;
        int col = (ntb + 4*s)*32 + pl;
        b.q = *(const uint4*)&W5T[(size_t)col*512 + kc8*64 + kq*16 + ko];
        acc[s] = __builtin_amdgcn_mfma_f32_32x32x16_bf16(a.v, b.v, acc[s], 0, 0, 0);
      }
    }
    __syncthreads();
  }
  int b = r0 >> 12, n0 = r0 & 4095;
  int colL = ntb*32 + pl;                // 0..127 within chunk
  int colc = tid >> 2, sub = tid & 3;    // writer mapping: 4 threads per col
  for (int s=0;s<4;++s){
    float sc = scale[128*s + colL], sh = shift[128*s + colL];
    #pragma unroll
    for (int q=0;q<16;++q){
      int m = mt*32 + (q&3) + 8*(q>>2) + rbase;
      ob[m*129 + colL] = fmaxf(fmaf(acc[s][q], sc, sh), 0.f);
    }
    __syncthreads();
    float* op = out + ((size_t)b*512 + 128*s + colc)*4096 + n0 + sub*16;
    #pragma unroll
    for (int j=0;j<4;++j){
      int rr = sub*16 + j*4;
      float4 v = make_float4(ob[(rr+0)*129 + colc], ob[(rr+1)*129 + colc],
                             ob[(rr+2)*129 + colc], ob[(rr+3)*129 + colc]);
      *(float4*)(op + j*4) = v;
    }
    __syncthreads();
  }
}

extern "C" void kernel_launch(void* const* d_in, const int* in_sizes, int n_in,
                              void* d_out, int out_size, void* d_ws, size_t ws_size,
                              hipStream_t stream){
  const float* x   = (const float*)d_in[0];
  const float* W1f = (const float*)d_in[1];
  const float* W2f = (const float*)d_in[2];
  const float* W3f = (const float*)d_in[3];
  const float* W4f = (const float*)d_in[4];
  const float* W5f = (const float*)d_in[5];
  const float* g1=(const float*)d_in[6],  *b1=(const float*)d_in[7];
  const float* g2=(const float*)d_in[8],  *b2=(const float*)d_in[9];
  const float* g3=(const float*)d_in[10], *b3=(const float*)d_in[11];
  const float* g4=(const float*)d_in[12], *b4=(const float*)d_in[13];
  const float* g5=(const float*)d_in[14], *b5=(const float*)d_in[15];
  float* out = (float*)d_out;

  char* w = (char*)d_ws;
  size_t off = 0;
  auto alloc = [&](size_t bytes)->void*{
    void* p = w + off;
    off = (off + bytes + 255) & ~(size_t)255;
    return p;
  };

  int*  idxb = (int*) alloc((size_t)BN*Kk*4);
  bf16* H2   = (bf16*)alloc((size_t)Mrows*64*2);
  bf16* catb = (bf16*)alloc((size_t)BN*512*2);
  bf16* W3T  = (bf16*)alloc((size_t)128*64*2);
  bf16* W4T  = (bf16*)alloc((size_t)256*128*2);
  bf16* W5T  = (bf16*)alloc((size_t)512*512*2);
  float* pv  = (float*)H2;
  int*   pib = (int*)((char*)H2 + (size_t)BN*8*Kk*4);

  size_t statsStart = off;
  float* partf=(float*)alloc(256*48*4);
  float* Gf=(float*)alloc(36*4);
  float* sumf=(float*)alloc(8*4);
  float* G2=(float*)alloc(4096*4);   float* sum2=(float*)alloc(64*4);
  float* G3=(float*)alloc(4096*4);   float* sum3=(float*)alloc(64*4);
  float* G4=(float*)alloc(16384*4);  float* sum4=(float*)alloc(128*4);
  float* G5=(float*)alloc(262144*4); float* sum5=(float*)alloc(512*4);
  float* P1=(float*)alloc(384*4);
  float* P2=(float*)alloc(4096*4);
  float* P3=(float*)alloc(8192*4);
  float* P4=(float*)alloc(32768*4);
  float* P5=(float*)alloc(262144*4);
  float* sc1=(float*)alloc(64*4);   float* sh1=(float*)alloc(64*4);
  float* sc2=(float*)alloc(64*4);   float* sh2=(float*)alloc(64*4);
  float* sc3=(float*)alloc(128*4);  float* sh3=(float*)alloc(128*4);
  float* sc4=(float*)alloc(256*4);  float* sh4=(float*)alloc(256*4);
  float* sc5=(float*)alloc(512*4);  float* sh5=(float*)alloc(512*4);
  size_t statsEnd = off;

  int statsFloats = (int)((statsEnd - statsStart)/4);
  zero_kernel<<<(statsFloats+255)/256,256,0,stream>>>((float*)(w+statsStart), statsFloats);
  w3t_kernel<<<32,256,0,stream>>>(W3f, W3T);
  w4t_kernel<<<128,256,0,stream>>>(W4f, W4T);
  w5t_kernel<<<1024,256,0,stream>>>(W5f, W5T);

  knnA_kernel<<<1024,256,0,stream>>>(x, pv, pib);
  knnB_kernel<<<BN/256,256,0,stream>>>(pv, pib, x, idxb, partf);

  const float invM  = 1.0f/(float)Mrows;
  const float invM5 = 1.0f/(float)BN;

  reducef_kernel<<<1,64,0,stream>>>(partf, Gf, sumf);
  kP_kernel<<<2,256,0,stream>>>(Gf, W1f, P1, 6, 64);
  kFinal_kernel<<<1,256,0,stream>>>(P1, sumf, W1f, g1, b1, sc1, sh1, 6, 64, invM);

  stats2_kernel<<<512,512,0,stream>>>(x, idxb, W1f, sc1, sh1, G2, sum2);
  kP_kernel<<<16,256,0,stream>>>(G2, W2f, P2, 64, 64);
  kFinal_kernel<<<1,256,0,stream>>>(P2, sum2, W2f, g2, b2, sc2, sh2, 64, 64, invM);

  fl12_kernel<<<BN,64,0,stream>>>(x, idxb, W1f, sc1, sh1, W2f, sc2, sh2, H2, catb);

  gram3_kernel<<<512,256,0,stream>>>(H2, Mrows, G3, sum3);
  kP_kernel<<<32,256,0,stream>>>(G3, W3f, P3, 64, 128);
  kFinal_kernel<<<1,256,0,stream>>>(P3, sum3, W3f, g3, b3, sc3, sh3, 64, 128, invM);

  stats4_kernel<<<512,512,0,stream>>>(H2, W3T, sc3, sh3, G4, sum4);
  kP_kernel<<<128,256,0,stream>>>(G4, W4f, P4, 128, 256);
  kFinal_kernel<<<1,256,0,stream>>>(P4, sum4, W4f, g4, b4, sc4, sh4, 128, 256, invM);

  fl34_kernel<<<Mrows/320,512,0,stream>>>(H2, W3T, sc3, sh3, W4T, sc4, sh4, catb);

  gram5_kernel<<<512,256,0,stream>>>(catb, G5, sum5);
  kP_kernel<<<1024,256,0,stream>>>(G5, W5f, P5, 512, 512);
  kFinal_kernel<<<2,256,0,stream>>>(P5, sum5, W5f, g5, b5, sc5, sh5, 512, 512, invM5);
  l5_kernel<<<BN/64,512,0,stream>>>(catb, W5T, sc5, sh5, out);
}

// Round 14
// 1074.566 us; speedup vs baseline: 1.4496x; 1.1590x over previous
//
#include <hip/hip_runtime.h>
#include <hip/hip_bf16.h>
#include <cfloat>

using bf16 = __hip_bfloat16;

typedef short short8 __attribute__((ext_vector_type(8)));
typedef float floatx16 __attribute__((ext_vector_type(16)));
union Frag { short8 v; uint2 u2[2]; };
union FragQ { short8 v; uint4 q; uint2 u2[2]; };
union U4b { uint4 q; unsigned short s[8]; };

constexpr int Bb = 8, Nn = 4096, Kk = 20;
constexpr int BN = Bb * Nn;                     // 32768
constexpr int Mrows = BN * Kk;                  // 655360
constexpr float EPSf = 1e-5f;

static __device__ __forceinline__ float b2f(bf16 v){ return __bfloat162float(v); }
static __device__ __forceinline__ bf16 f2b(float v){ return __float2bfloat16(v); }
static __device__ __forceinline__ unsigned short f2bu(float v){
  union { bf16 b; unsigned short u; } cv; cv.b = __float2bfloat16(v); return cv.u;
}
static __device__ __forceinline__ float bits2f(unsigned short u){
  union { unsigned int i; float f; } c; c.i = ((unsigned)u)<<16; return c.f;
}

// ---------------- zero workspace region ----------------
__global__ void zero_kernel(float* __restrict__ p, int n){
  int i = blockIdx.x*256 + threadIdx.x;
  if (i < n) p[i] = 0.f;
}

// ---------------- W3^T bf16 pack ----------------
__global__ void w3t_kernel(const float* __restrict__ W3f, bf16* __restrict__ W3T){
  int id = blockIdx.x*256 + threadIdx.x;   // 128*64 = 8192 elems
  if (id >= 128*64) return;
  int n = id >> 6, k = id & 63;
  W3T[id] = f2b(W3f[(size_t)k*128 + n]);
}

// ---------------- W4^T bf16 pack ----------------
__global__ void w4t_kernel(const float* __restrict__ W4f, bf16* __restrict__ W4T){
  int id = blockIdx.x*256 + threadIdx.x;   // 128*256 = 32768 elems
  if (id >= 128*256) return;
  int k = id >> 8, c = id & 255;           // coalesced read of W4f
  W4T[(size_t)c*128 + k] = f2b(W4f[id]);
}

// ---------------- W5^T bf16 pack ----------------
__global__ void w5t_kernel(const float* __restrict__ W5f, bf16* __restrict__ W5T){
  int id = blockIdx.x*256 + threadIdx.x;   // 512*512 = 262144 elems
  if (id >= 512*512) return;
  int k = id >> 9, c = id & 511;           // coalesced read of W5f
  W5T[(size_t)c*512 + k] = f2b(W5f[id]);
}

// ---------------- KNN phase A v8 (measured best: 143.6us, 81% VALUBusy) ----------
__global__ __launch_bounds__(256) void knnA_kernel(const float* __restrict__ x,
                                                   float* __restrict__ pv, int* __restrict__ pi){
#pragma clang fp contract(off)
  __shared__ float4 p4[512];
  __shared__ unsigned short lst[256*62];
  int blk = blockIdx.x;
  int stripe = blk & 7;
  int chunk  = (blk >> 3) & 15;
  int b      = blk >> 7;
  const float* xb = x + b*3*Nn;
  int j0 = stripe*512;
  for (int u = threadIdx.x; u < 512; u += 256){
    int j = j0 + u;
    float a0 = xb[j];
    float a1 = xb[Nn + j];
    float a2 = xb[2*Nn + j];
    float s = a0*a0; s = s + a1*a1; s = s + a2*a2;
    p4[u] = make_float4(a0, a1, a2, s);
  }
  __syncthreads();
  int i = chunk*256 + threadIdx.x;
  float xi = xb[i], yi = xb[Nn+i], zi = xb[2*Nn+i];
  float ni = xi*xi; ni = ni + yi*yi; ni = ni + zi*zi;
  float mni = -ni;
  float xi2 = xi + xi, yi2 = yi + yi, zi2 = zi + zi;
  float tv[Kk];
  #pragma unroll
  for (int s=0;s<Kk;++s) tv[s] = -FLT_MAX;
  for (int g=0; g<32; ++g){
    float gm = -FLT_MAX;
    #pragma unroll
    for (int e=0;e<16;++e){
      float4 p = p4[g*16+e];
      float base = mni - p.w;
      float nd = fmaf(xi2, p.x, fmaf(yi2, p.y, fmaf(zi2, p.z, base)));
      gm = fmaxf(gm, nd);
    }
    #pragma unroll
    for (int s=Kk-1; s>=1; --s)
      tv[s] = fmaxf(tv[s], fminf(tv[s-1], gm));
    tv[0] = fmaxf(tv[0], gm);
  }
  float thr = tv[Kk-1];
  thr = thr - (fabsf(thr)*1e-5f + 1e-6f);
  unsigned short* ml = &lst[threadIdx.x*62];
  int cnt = 0;
  for (int u=0; u<512; ++u){
    float4 p = p4[u];
    float base = mni - p.w;
    float nd = fmaf(xi2, p.x, fmaf(yi2, p.y, fmaf(zi2, p.z, base)));
    if (nd >= thr && cnt < 60){ ml[cnt] = (unsigned short)u; ++cnt; }
  }
  float av[Kk]; int ai[Kk];
  #pragma unroll
  for (int s=0;s<Kk;++s){ av[s] = -FLT_MAX; ai[s] = 0; }
  if (cnt >= 60){
    for (int u=0; u<512; ++u){
      float4 p = p4[u];
      float dot = xi*p.x; dot = dot + yi*p.y; dot = dot + zi*p.z;
      float inner = -2.0f*dot;
      float nd = mni - inner; nd = nd - p.w;
      if (nd > av[Kk-1]){
        #pragma unroll
        for (int s=Kk-1; s>=1; --s){
          bool cs = nd > av[s];
          bool cp = nd > av[s-1];
          av[s] = cs ? (cp ? av[s-1] : nd) : av[s];
          ai[s] = cs ? (cp ? ai[s-1] : (j0+u)) : ai[s];
        }
        if (nd > av[0]){ av[0] = nd; ai[0] = j0+u; }
      }
    }
  } else {
    for (int t=0; t<cnt; ++t){
      int lj = ml[t];
      float4 p = p4[lj];
      float dot = xi*p.x; dot = dot + yi*p.y; dot = dot + zi*p.z;
      float inner = -2.0f*dot;
      float nd = mni - inner; nd = nd - p.w;
      if (nd > av[Kk-1]){
        #pragma unroll
        for (int s=Kk-1; s>=1; --s){
          bool cs = nd > av[s];
          bool cp = nd > av[s-1];
          av[s] = cs ? (cp ? av[s-1] : nd) : av[s];
          ai[s] = cs ? (cp ? ai[s-1] : (j0+lj)) : ai[s];
        }
        if (nd > av[0]){ av[0] = nd; ai[0] = j0+lj; }
      }
    }
  }
  long long base = ((long long)(b*Nn + i)*8 + stripe)*Kk;
  #pragma unroll
  for (int s=0;s<Kk;++s){ pv[base+s] = av[s]; pi[base+s] = ai[s]; }
}

// ---------------- KNN phase B + fused layer-1 stats ----------------
__global__ __launch_bounds__(256) void knnB_kernel(const float* __restrict__ pv,
                                                   const int* __restrict__ pi,
                                                   const float* __restrict__ x,
                                                   int* __restrict__ idx,
                                                   float* __restrict__ part){
  int p = blockIdx.x*256 + threadIdx.x;    // grid 128 x 256 = BN exactly
  long long base = (long long)p*8*Kk;
  float av[Kk]; int ai[Kk];
  #pragma unroll
  for (int s=0;s<Kk;++s){ av[s]=pv[base+s]; ai[s]=pi[base+s]; }
  for (int t=Kk; t<8*Kk; ++t){
    float nd = pv[base+t]; int j = pi[base+t];
    if (nd > av[Kk-1]){
      #pragma unroll
      for (int s=Kk-1;s>=1;--s){
        bool cs = nd > av[s];
        bool cp = nd > av[s-1];
        av[s] = cs ? (cp?av[s-1]:nd) : av[s];
        ai[s] = cs ? (cp?ai[s-1]:j) : ai[s];
      }
      if (nd > av[0]){ av[0]=nd; ai[0]=j; }
    }
  }
  #pragma unroll
  for (int s=0;s<Kk;++s) idx[(long long)p*Kk+s] = ai[s];
  // ---- fused layer-1 stats ----
  int b = p >> 12, n = p & 4095;
  const float* xb = x + b*3*Nn;
  float cx = xb[n], cy = xb[Nn+n], cz = xb[2*Nn+n];
  float snx=0.f, sny=0.f, snz=0.f;
  float a00=0.f,a01=0.f,a02=0.f,a11=0.f,a12=0.f,a22=0.f;
  #pragma unroll
  for (int s=0;s<Kk;++s){
    int j = ai[s];
    float nx = xb[j], ny = xb[Nn+j], nz = xb[2*Nn+j];
    snx += nx; sny += ny; snz += nz;
    a00 = fmaf(nx,nx,a00); a01 = fmaf(nx,ny,a01); a02 = fmaf(nx,nz,a02);
    a11 = fmaf(ny,ny,a11); a12 = fmaf(ny,nz,a12); a22 = fmaf(nz,nz,a22);
  }
  float acc[36];
  acc[0]=a00;  acc[1]=a01;  acc[2]=a02;
  acc[6]=a01;  acc[7]=a11;  acc[8]=a12;
  acc[12]=a02; acc[13]=a12; acc[14]=a22;
  acc[3]=snx*cx;  acc[4]=snx*cy;  acc[5]=snx*cz;
  acc[9]=sny*cx;  acc[10]=sny*cy; acc[11]=sny*cz;
  acc[15]=snz*cx; acc[16]=snz*cy; acc[17]=snz*cz;
  acc[18]=cx*snx; acc[19]=cx*sny; acc[20]=cx*snz;
  acc[24]=cy*snx; acc[25]=cy*sny; acc[26]=cy*snz;
  acc[30]=cz*snx; acc[31]=cz*sny; acc[32]=cz*snz;
  float k20 = (float)Kk;
  acc[21]=k20*cx*cx; acc[22]=k20*cx*cy; acc[23]=k20*cx*cz;
  acc[27]=k20*cy*cx; acc[28]=k20*cy*cy; acc[29]=k20*cy*cz;
  acc[33]=k20*cz*cx; acc[34]=k20*cz*cy; acc[35]=k20*cz*cz;
  float s6[6] = { snx, sny, snz, k20*cx, k20*cy, k20*cz };
  __shared__ float red[256];
  #pragma unroll
  for (int v=0; v<42; ++v){
    red[threadIdx.x] = (v<36)? acc[v] : s6[v-36];
    __syncthreads();
    for (int s=128; s>0; s>>=1){
      if (threadIdx.x < s) red[threadIdx.x] += red[threadIdx.x+s];
      __syncthreads();
    }
    if (threadIdx.x==0) part[blockIdx.x*48 + v] = red[0];
    __syncthreads();
  }
}

__global__ void reducef_kernel(const float* __restrict__ part, float* __restrict__ Gf,
                               float* __restrict__ sumf){
  int t = threadIdx.x;
  if (t < 42){
    float s = 0.f;
    for (int i=0;i<128;++i) s += part[i*48 + t];
    if (t<36) Gf[t]=s; else sumf[t-36]=s;
  }
}

// ---------------- G3 gram (CIN=64) with fused column sums ----------------
__global__ __launch_bounds__(256) void gram3_kernel(const bf16* __restrict__ H, int M,
                                                    float* __restrict__ G,
                                                    float* __restrict__ sumh){
  __shared__ short HTa[64*68];
  __shared__ float csum[64];
  int tid = threadIdx.x, lane = tid & 63, w = tid >> 6;
  if (tid < 64) csum[tid] = 0.f;
  int nchunks = gridDim.x;
  int rpc = M / nchunks;
  int r0 = blockIdx.x*rpc;
  int mt = w >> 1, nt = w & 1;
  floatx16 acc;
  #pragma unroll
  for (int q=0;q<16;++q) acc[q]=0.f;
  int arow = (mt*32 + (lane&31))*68;
  int brow = (nt*32 + (lane&31))*68;
  int ko = (lane>>5)*8;
  int c0s = (tid & 7)*8;
  float cs[8];
  #pragma unroll
  for (int j=0;j<8;++j) cs[j]=0.f;
  for (int rb=r0; rb<r0+rpc; rb+=64){
    #pragma unroll
    for (int s=0;s<2;++s){
      int e = tid + s*256;
      int row = e >> 3;
      U4b va; va.q = *(const uint4*)&H[(size_t)(rb+row)*64 + c0s];
      #pragma unroll
      for (int j=0;j<8;++j){
        HTa[(c0s+j)*68 + row] = (short)va.s[j];
        cs[j] += bits2f(va.s[j]);
      }
    }
    __syncthreads();
    #pragma unroll
    for (int kc=0;kc<64;kc+=16){
      Frag a, b;
      const short* ap = &HTa[arow + kc + ko];
      const short* bp = &HTa[brow + kc + ko];
      a.u2[0] = *(const uint2*)ap;  a.u2[1] = *(const uint2*)(ap+4);
      b.u2[0] = *(const uint2*)bp;  b.u2[1] = *(const uint2*)(bp+4);
      acc = __builtin_amdgcn_mfma_f32_32x32x16_bf16(a.v, b.v, acc, 0, 0, 0);
    }
    __syncthreads();
  }
  int col = lane & 31, rbase = 4*(lane>>5);
  #pragma unroll
  for (int r=0;r<16;++r){
    int row = (r&3) + 8*(r>>2) + rbase;
    atomicAdd(&G[(size_t)(mt*32 + row)*64 + nt*32 + col], acc[r]);
  }
  #pragma unroll
  for (int j=0;j<8;++j) atomicAdd(&csum[c0s+j], cs[j]);
  __syncthreads();
  if (tid < 64) atomicAdd(&sumh[tid], csum[tid]);
}

// ---------------- G5 gram (CIN=512): 128-wide tiles + fused column sums ----------------
__global__ __launch_bounds__(256) void gram5_kernel(const bf16* __restrict__ H,
                                                    float* __restrict__ G,
                                                    float* __restrict__ sumh){
  __shared__ short HTa[128*68];
  __shared__ short HTb[128*68];
  __shared__ float csum[128];
  int blk = blockIdx.x;
  int pair = blk & 15;
  int chunk = blk >> 4;            // 0..31
  int tr = pair >> 2, tc = pair & 3;
  bool diag = (tr == tc);
  int tid = threadIdx.x, lane = tid & 63, w = tid >> 6;   // 4 waves
  if (tid < 128) csum[tid] = 0.f;
  int rpc = BN / 32;               // 1024
  int r0 = chunk*rpc;
  int pl = lane & 31, ko = (lane>>5)*8, rbase = 4*(lane>>5);
  int mt = w;
  int arow = (mt*32 + pl)*68;
  floatx16 acc[4];
  #pragma unroll
  for (int nt=0;nt<4;++nt)
    #pragma unroll
    for (int q=0;q<16;++q) acc[nt][q]=0.f;
  int c0s = (tid & 15)*8;
  float cs[8];
  #pragma unroll
  for (int j=0;j<8;++j) cs[j]=0.f;
  const short* Bbase = diag ? HTa : HTb;
  for (int rb=r0; rb<r0+rpc; rb+=64){
    #pragma unroll
    for (int s=0;s<4;++s){
      int e = tid + s*256;
      int row = e >> 4;
      U4b va; va.q = *(const uint4*)&H[(size_t)(rb+row)*512 + tr*128 + c0s];
      #pragma unroll
      for (int j=0;j<8;++j) HTa[(c0s+j)*68 + row] = (short)va.s[j];
      if (diag){
        #pragma unroll
        for (int j=0;j<8;++j) cs[j] += bits2f(va.s[j]);
      } else {
        U4b vb; vb.q = *(const uint4*)&H[(size_t)(rb+row)*512 + tc*128 + c0s];
        #pragma unroll
        for (int j=0;j<8;++j) HTb[(c0s+j)*68 + row] = (short)vb.s[j];
      }
    }
    __syncthreads();
    #pragma unroll
    for (int kc=0;kc<64;kc+=16){
      Frag a;
      const short* ap = &HTa[arow + kc + ko];
      a.u2[0] = *(const uint2*)ap;  a.u2[1] = *(const uint2*)(ap+4);
      #pragma unroll
      for (int nt=0;nt<4;++nt){
        Frag b;
        const short* bp = &Bbase[(nt*32 + pl)*68 + kc + ko];
        b.u2[0] = *(const uint2*)bp;  b.u2[1] = *(const uint2*)(bp+4);
        acc[nt] = __builtin_amdgcn_mfma_f32_32x32x16_bf16(a.v, b.v, acc[nt], 0, 0, 0);
      }
    }
    __syncthreads();
  }
  #pragma unroll
  for (int nt=0;nt<4;++nt){
    #pragma unroll
    for (int r=0;r<16;++r){
      int row = (r&3) + 8*(r>>2) + rbase;
      atomicAdd(&G[(size_t)(tr*128 + mt*32 + row)*512 + tc*128 + nt*32 + pl], acc[nt][r]);
    }
  }
  if (diag){
    #pragma unroll
    for (int j=0;j<8;++j) atomicAdd(&csum[c0s+j], cs[j]);
    __syncthreads();
    if (tid < 128) atomicAdd(&sumh[tr*128 + tid], csum[tid]);
  }
}

// ---------------- P = G @ W ----------------
__global__ void kP_kernel(const float* __restrict__ G, const float* __restrict__ Wf,
                          float* __restrict__ P, int Cin, int Cout){
  int id = blockIdx.x*256 + threadIdx.x;
  if (id >= Cin*Cout) return;
  int i = id / Cout, j = id - i*Cout;
  float s = 0.f;
  for (int k=0;k<Cin;++k) s = fmaf(G[(size_t)i*Cin+k], Wf[(size_t)k*Cout+j], s);
  P[id] = s;
}

// ---------------- scale/shift v2: i-parallel (16 sub-slices/column) ----------------
__global__ __launch_bounds__(256) void kFinal_kernel(const float* __restrict__ P,
                              const float* __restrict__ sumh,
                              const float* __restrict__ Wf, const float* __restrict__ g,
                              const float* __restrict__ bb, float* __restrict__ scale,
                              float* __restrict__ shift, int Cin, int Cout, float invM){
  __shared__ float redm[256], rede[256];
  int tid = threadIdx.x;
  int j = blockIdx.x*16 + (tid & 15);
  int sub = tid >> 4;
  float mean = 0.f, e2 = 0.f;
  for (int i = sub; i < Cin; i += 16){
    float w = Wf[(size_t)i*Cout + j];
    mean = fmaf(sumh[i], w, mean);
    e2   = fmaf(w, P[(size_t)i*Cout + j], e2);
  }
  redm[tid] = mean; rede[tid] = e2;
  __syncthreads();
  for (int s = 128; s >= 16; s >>= 1){
    if (tid < s){ redm[tid] += redm[tid+s]; rede[tid] += rede[tid+s]; }
    __syncthreads();
  }
  if (tid < 16){
    float m = redm[tid]*invM, e = rede[tid]*invM;
    float var = e - m*m;
    float inv = rsqrtf(var + EPSf);
    float sc = g[j]*inv;
    scale[j] = sc;
    shift[j] = bb[j] - m*sc;
  }
}

// ---------------- layer-2 stats ----------------
__global__ __launch_bounds__(512) void stats2_kernel(const float* __restrict__ x,
    const int* __restrict__ idx, const float* __restrict__ W1f,
    const float* __restrict__ sc1v, const float* __restrict__ sh1v,
    float* __restrict__ G2, float* __restrict__ sum2){
  __shared__ float W1s[6][64];
  __shared__ float fsh[64][8];
  __shared__ short H1T[64*68];
  __shared__ float csum[64];
  int tid = threadIdx.x, lane = tid & 63, w = tid >> 6;   // 8 waves
  if (tid < 384) W1s[tid>>6][tid&63] = W1f[tid];
  if (tid < 64) csum[tid] = 0.f;
  int rp = tid >> 4, cq = tid & 15, c0 = cq*4;
  float sca[4], sha[4];
  #pragma unroll
  for (int k=0;k<4;++k){ sca[k]=sc1v[c0+k]; sha[k]=sh1v[c0+k]; }
  int mt = w & 1, nt = (w>>1) & 1, kh = w >> 2;
  int arow = (mt*32 + (lane&31))*68;
  int brow = (nt*32 + (lane&31))*68;
  int ko = (lane>>5)*8;
  floatx16 acc;
  #pragma unroll
  for (int q=0;q<16;++q) acc[q]=0.f;
  float cs[4] = {0.f,0.f,0.f,0.f};
  int rpc = Mrows / gridDim.x;
  int r0 = blockIdx.x * rpc;
  __syncthreads();
  for (int rb=r0; rb<r0+rpc; rb+=64){
    {
      int r = tid>>3, e = tid&7;
      if (e < 6){
        int grow = rb + r;
        int bn = grow / Kk;
        int b = bn >> 12, n = bn & 4095;
        int j = idx[grow];
        const float* xb = x + b*3*Nn;
        fsh[r][e] = (e<3) ? xb[e*Nn + j] : xb[(e-3)*Nn + n];
      }
    }
    __syncthreads();
    {
      float y0[4]={0,0,0,0}, y1[4]={0,0,0,0};
      int ra = rp*2, rbw = rp*2+1;
      #pragma unroll
      for (int i=0;i<6;++i){
        float fa = fsh[ra][i], fb = fsh[rbw][i];
        float4 wv = *(const float4*)&W1s[i][c0];
        y0[0]=fmaf(fa,wv.x,y0[0]); y0[1]=fmaf(fa,wv.y,y0[1]);
        y0[2]=fmaf(fa,wv.z,y0[2]); y0[3]=fmaf(fa,wv.w,y0[3]);
        y1[0]=fmaf(fb,wv.x,y1[0]); y1[1]=fmaf(fb,wv.y,y1[1]);
        y1[2]=fmaf(fb,wv.z,y1[2]); y1[3]=fmaf(fb,wv.w,y1[3]);
      }
      #pragma unroll
      for (int k=0;k<4;++k){
        float va = fmaxf(fmaf(y0[k],sca[k],sha[k]),0.f);
        float vb = fmaxf(fmaf(y1[k],sca[k],sha[k]),0.f);
        cs[k] += va; cs[k] += vb;
        unsigned int pk = f2bu(va) | ((unsigned)f2bu(vb)<<16);
        *(unsigned int*)&H1T[(c0+k)*68 + ra] = pk;
      }
    }
    __syncthreads();
    {
      int kc = kh*32;
      #pragma unroll
      for (int s=0;s<2;++s){
        Frag a, b;
        const short* ap = &H1T[arow + kc + s*16 + ko];
        const short* bp = &H1T[brow + kc + s*16 + ko];
        a.u2[0] = *(const uint2*)ap;  a.u2[1] = *(const uint2*)(ap+4);
        b.u2[0] = *(const uint2*)bp;  b.u2[1] = *(const uint2*)(bp+4);
        acc = __builtin_amdgcn_mfma_f32_32x32x16_bf16(a.v, b.v, acc, 0, 0, 0);
      }
    }
    __syncthreads();
  }
  int col = lane & 31, rbase = 4*(lane>>5);
  #pragma unroll
  for (int r=0;r<16;++r){
    int row = (r&3) + 8*(r>>2) + rbase;
    atomicAdd(&G2[(size_t)(mt*32+row)*64 + nt*32+col], acc[r]);
  }
  #pragma unroll
  for (int k=0;k<4;++k) atomicAdd(&csum[c0+k], cs[k]);
  __syncthreads();
  if (tid < 64) atomicAdd(&sum2[tid], csum[tid]);
}

// ---------------- fused layers 1+2 ----------------
__global__ __launch_bounds__(64) void fl12_kernel(const float* __restrict__ x,
    const int* __restrict__ idx, const float* __restrict__ W1f,
    const float* __restrict__ sc1v, const float* __restrict__ sh1v,
    const float* __restrict__ W2f, const float* __restrict__ sc2v,
    const float* __restrict__ sh2v, bf16* __restrict__ H2, bf16* __restrict__ cat){
  __shared__ float fsh[Kk][6];
  __shared__ float h1[Kk][64];
  __shared__ float mm[4][64];
  int bn = blockIdx.x, b = bn>>12, n = bn & 4095;
  int tid = threadIdx.x;
  if (tid < Kk){
    int j = idx[(size_t)bn*Kk + tid];
    const float* xb = x + b*3*Nn;
    fsh[tid][0]=xb[j]; fsh[tid][1]=xb[Nn+j]; fsh[tid][2]=xb[2*Nn+j];
    fsh[tid][3]=xb[n]; fsh[tid][4]=xb[Nn+n]; fsh[tid][5]=xb[2*Nn+n];
  }
  __syncthreads();
  {
    float sc=sc1v[tid], sh=sh1v[tid];
    float w[6];
    #pragma unroll
    for (int i=0;i<6;++i) w[i]=W1f[i*64+tid];
    float mx = 0.f;
    #pragma unroll
    for (int r=0;r<Kk;++r){
      float y=0.f;
      #pragma unroll
      for (int i=0;i<6;++i) y = fmaf(fsh[r][i], w[i], y);
      float v = fmaxf(fmaf(y,sc,sh),0.f);
      h1[r][tid]=v;
      mx = fmaxf(mx,v);
    }
    cat[(size_t)bn*512 + tid] = f2b(mx);
  }
  __syncthreads();
  int q = tid >> 4, c0 = (tid & 15)*4;
  float acc[5][4]={};
  for (int i0=0;i0<64;i0+=4){
    float hv[5][4];
    #pragma unroll
    for (int l=0;l<5;++l){
      float4 t4 = *(const float4*)&h1[q*5+l][i0];
      hv[l][0]=t4.x; hv[l][1]=t4.y; hv[l][2]=t4.z; hv[l][3]=t4.w;
    }
    #pragma unroll
    for (int ii=0;ii<4;++ii){
      const float* wp = W2f + (i0+ii)*64 + c0;
      float w0=wp[0],w1=wp[1],w2=wp[2],w3=wp[3];
      #pragma unroll
      for (int l=0;l<5;++l){
        float hvv=hv[l][ii];
        acc[l][0]=fmaf(hvv,w0,acc[l][0]);
        acc[l][1]=fmaf(hvv,w1,acc[l][1]);
        acc[l][2]=fmaf(hvv,w2,acc[l][2]);
        acc[l][3]=fmaf(hvv,w3,acc[l][3]);
      }
    }
  }
  float sc[4],sh[4];
  #pragma unroll
  for (int cb=0;cb<4;++cb){ sc[cb]=sc2v[c0+cb]; sh[cb]=sh2v[c0+cb]; }
  float mx[4]={0,0,0,0};
  #pragma unroll
  for (int l=0;l<5;++l){
    unsigned short us[4];
    #pragma unroll
    for (int cb=0;cb<4;++cb){
      float v=fmaxf(fmaf(acc[l][cb],sc[cb],sh[cb]),0.f);
      mx[cb]=fmaxf(mx[cb],v);
      us[cb]=f2bu(v);
    }
    uint2 v2; v2.x = us[0]|((unsigned)us[1]<<16); v2.y=us[2]|((unsigned)us[3]<<16);
    *(uint2*)(H2 + ((size_t)bn*Kk + q*5+l)*64 + c0) = v2;
  }
  #pragma unroll
  for (int cb=0;cb<4;++cb) mm[q][c0+cb]=mx[cb];
  __syncthreads();
  {
    float M0 = fmaxf(fmaxf(mm[0][tid],mm[1][tid]),fmaxf(mm[2][tid],mm[3][tid]));
    cat[(size_t)bn*512 + 64 + tid] = f2b(M0);
  }
}

// ---------------- layer-4 stats: MFMA produce + MFMA Gram ----------------
__global__ __launch_bounds__(512) void stats4_kernel(const bf16* __restrict__ H2,
    const bf16* __restrict__ W3T, const float* __restrict__ sc3v, const float* __restrict__ sh3v,
    float* __restrict__ G4, float* __restrict__ sum4){
  __shared__ short h2s[64*68];
  __shared__ short H3T[128*68];
  __shared__ float csum[128];
  int tid = threadIdx.x, lane = tid & 63, w = tid >> 6;   // 8 waves
  if (tid < 128) csum[tid] = 0.f;
  int trow = tid >> 3, tc0 = (tid & 7)*8;
  int pl  = lane & 31;
  int ko  = (lane >> 5)*8;
  int pmt = w >> 2, pnt = w & 3;
  int parow = (pmt*32 + pl)*68;
  int pcol  = pnt*32 + pl;
  float psc = sc3v[pcol], psh = sh3v[pcol];
  int prbase = 4*(lane>>5);
  FragQ bfr[4];
  #pragma unroll
  for (int kq=0;kq<4;++kq)
    bfr[kq].q = *(const uint4*)&W3T[(size_t)pcol*64 + kq*16 + ko];
  int gmt = w>>1, gnt0 = (w&1)*2, gnt1 = gnt0+1;
  int garow  = (gmt*32 + pl)*68;
  int gbrow0 = (gnt0*32 + pl)*68;
  int gbrow1 = (gnt1*32 + pl)*68;
  floatx16 acc0, acc1;
  #pragma unroll
  for (int q=0;q<16;++q){ acc0[q]=0.f; acc1[q]=0.f; }
  float cs = 0.f;
  int rpc = Mrows / gridDim.x;
  int r0 = blockIdx.x * rpc;
  uint4 hreg = *(const uint4*)&H2[(size_t)(r0+trow)*64 + tc0];
  for (int rb=r0; rb<r0+rpc; rb+=64){
    {
      short* dst = &h2s[trow*68 + tc0];
      *(uint2*)dst       = make_uint2(hreg.x, hreg.y);
      *(uint2*)(dst + 4) = make_uint2(hreg.z, hreg.w);
    }
    if (rb + 64 < r0 + rpc)
      hreg = *(const uint4*)&H2[(size_t)(rb+64+trow)*64 + tc0];
    __syncthreads();
    {
      floatx16 pacc;
      #pragma unroll
      for (int q=0;q<16;++q) pacc[q]=0.f;
      #pragma unroll
      for (int kq=0;kq<4;++kq){
        Frag a;
        const short* ap = &h2s[parow + kq*16 + ko];
        a.u2[0] = *(const uint2*)ap;  a.u2[1] = *(const uint2*)(ap+4);
        pacc = __builtin_amdgcn_mfma_f32_32x32x16_bf16(a.v, bfr[kq].v, pacc, 0, 0, 0);
      }
      #pragma unroll
      for (int g=0; g<4; ++g){
        unsigned short p[4];
        #pragma unroll
        for (int r=0;r<4;++r){
          float v = fmaxf(fmaf(pacc[g*4+r], psc, psh), 0.f);
          cs += v;
          p[r] = f2bu(v);
        }
        uint2 pk; pk.x = p[0] | ((unsigned)p[1]<<16); pk.y = p[2] | ((unsigned)p[3]<<16);
        *(uint2*)&H3T[pcol*68 + pmt*32 + 8*g + prbase] = pk;
      }
    }
    __syncthreads();
    #pragma unroll
    for (int kc=0;kc<64;kc+=16){
      Frag a, b0, b1;
      const short* ap  = &H3T[garow  + kc + ko];
      const short* bp0 = &H3T[gbrow0 + kc + ko];
      const short* bp1 = &H3T[gbrow1 + kc + ko];
      a.u2[0]  = *(const uint2*)ap;   a.u2[1]  = *(const uint2*)(ap+4);
      b0.u2[0] = *(const uint2*)bp0;  b0.u2[1] = *(const uint2*)(bp0+4);
      b1.u2[0] = *(const uint2*)bp1;  b1.u2[1] = *(const uint2*)(bp1+4);
      acc0 = __builtin_amdgcn_mfma_f32_32x32x16_bf16(a.v, b0.v, acc0, 0, 0, 0);
      acc1 = __builtin_amdgcn_mfma_f32_32x32x16_bf16(a.v, b1.v, acc1, 0, 0, 0);
    }
  }
  int col = pl;
  #pragma unroll
  for (int r=0;r<16;++r){
    int row = (r&3) + 8*(r>>2) + prbase;
    atomicAdd(&G4[(size_t)(gmt*32+row)*128 + gnt0*32+col], acc0[r]);
    atomicAdd(&G4[(size_t)(gmt*32+row)*128 + gnt1*32+col], acc1[r]);
  }
  atomicAdd(&csum[pcol], cs);
  __syncthreads();
  if (tid < 128) atomicAdd(&sum4[tid], csum[tid]);
}

// ---------------- fused layers 3+4: MFMA produce chain + col-owner maxpool ----------------
__global__ __launch_bounds__(512,4) void fl34_kernel(const bf16* __restrict__ H2,
    const bf16* __restrict__ W3T, const float* __restrict__ sc3v, const float* __restrict__ sh3v,
    const bf16* __restrict__ W4T, const float* __restrict__ sc4v, const float* __restrict__ sh4v,
    bf16* __restrict__ cat){
  __shared__ short h2s[64*68];             // 8.5 KB
  __shared__ short h3s[64*132];            // 16.5 KB
  __shared__ unsigned short h4s[64*256];   // 32 KB
  __shared__ unsigned short mx3u[16*128];  // 4 KB
  __shared__ unsigned short mx4u[16*256];  // 8 KB
  int tid = threadIdx.x, lane = tid & 63, w = tid >> 6;
  int pl = lane & 31;
  int ko = (lane >> 5)*8;
  int rbase = 4*(lane>>5);
  {
    unsigned* p4 = (unsigned*)mx4u;
    for (int u=tid; u<2048; u+=512) p4[u]=0u;
    unsigned* p3 = (unsigned*)mx3u;
    for (int u=tid; u<1024; u+=512) p3[u]=0u;
  }
  int mt3 = w >> 2, ct3 = w & 3;
  int c3 = ct3*32 + pl;
  float sc3 = sc3v[c3], sh3 = sh3v[c3];
  int a3row = (mt3*32 + pl)*68;
  int c4 = w*32 + pl;
  float sc4 = sc4v[c4], sh4 = sh4v[c4];
  int trow = tid >> 3, tc0 = (tid & 7)*8;
  int r0 = blockIdx.x * 320;
  uint4 hreg = *(const uint4*)&H2[(size_t)(r0+trow)*64 + tc0];
  {
    short* dst = &h2s[trow*68 + tc0];
    *(uint2*)dst       = make_uint2(hreg.x, hreg.y);
    *(uint2*)(dst + 4) = make_uint2(hreg.z, hreg.w);
  }
  hreg = *(const uint4*)&H2[(size_t)(r0 + 64 + trow)*64 + tc0];
  __syncthreads();
  for (int t=0; t<5; ++t){
    {
      floatx16 pa;
      #pragma unroll
      for (int q=0;q<16;++q) pa[q]=0.f;
      #pragma unroll
      for (int kq=0;kq<4;++kq){
        Frag a; FragQ b;
        const short* ap = &h2s[a3row + kq*16 + ko];
        a.u2[0] = *(const uint2*)ap;  a.u2[1] = *(const uint2*)(ap+4);
        b.q = *(const uint4*)&W3T[(size_t)c3*64 + kq*16 + ko];
        pa = __builtin_amdgcn_mfma_f32_32x32x16_bf16(a.v, b.v, pa, 0, 0, 0);
      }
      #pragma unroll
      for (int r=0;r<16;++r){
        int m = mt3*32 + (r&3) + 8*(r>>2) + rbase;
        float v = fmaxf(fmaf(pa[r], sc3, sh3), 0.f);
        h3s[m*132 + c3] = (short)f2bu(v);
      }
    }
    __syncthreads();
    #pragma unroll
    for (int mt4=0; mt4<2; ++mt4){
      floatx16 acc;
      #pragma unroll
      for (int q=0;q<16;++q) acc[q]=0.f;
      int a4row = (mt4*32 + pl)*132;
      #pragma unroll
      for (int kq=0;kq<8;++kq){
        Frag a; FragQ b;
        const short* ap = &h3s[a4row + kq*16 + ko];
        a.u2[0] = *(const uint2*)ap;  a.u2[1] = *(const uint2*)(ap+4);
        b.q = *(const uint4*)&W4T[(size_t)c4*128 + kq*16 + ko];
        acc = __builtin_amdgcn_mfma_f32_32x32x16_bf16(a.v, b.v, acc, 0, 0, 0);
      }
      #pragma unroll
      for (int r=0;r<16;++r){
        int m = mt4*32 + (r&3) + 8*(r>>2) + rbase;
        float v = fmaxf(fmaf(acc[r], sc4, sh4), 0.f);
        h4s[m*256 + c4] = f2bu(v);
      }
    }
    __syncthreads();
    if (t < 4){
      short* dst = &h2s[trow*68 + tc0];
      *(uint2*)dst       = make_uint2(hreg.x, hreg.y);
      *(uint2*)(dst + 4) = make_uint2(hreg.z, hreg.w);
      if (t < 3) hreg = *(const uint4*)&H2[(size_t)(r0 + (t+2)*64 + trow)*64 + tc0];
    }
    {
      int lr0 = t*64;
      if (tid < 256){
        int c = tid;
        int p = lr0/20;
        int nb = (p+1)*20 - lr0;
        unsigned ml = 0;
        for (int r=0;r<64;++r){
          unsigned v = h4s[r*256 + c];
          ml = v > ml ? v : ml;
          if (--nb == 0){
            unsigned short* mp = &mx4u[p*256 + c];
            unsigned cur = *mp;
            if (ml > cur) *mp = (unsigned short)ml;
            ml = 0; ++p; nb = 20;
          }
        }
        if (nb != 20){
          unsigned short* mp = &mx4u[p*256 + c];
          unsigned cur = *mp;
          if (ml > cur) *mp = (unsigned short)ml;
        }
      } else if (tid < 384){
        int c = tid - 256;
        int p = lr0/20;
        int nb = (p+1)*20 - lr0;
        unsigned ml = 0;
        for (int r=0;r<64;++r){
          unsigned v = (unsigned)(unsigned short)h3s[r*132 + c];
          ml = v > ml ? v : ml;
          if (--nb == 0){
            unsigned short* mp = &mx3u[p*128 + c];
            unsigned cur = *mp;
            if (ml > cur) *mp = (unsigned short)ml;
            ml = 0; ++p; nb = 20;
          }
        }
        if (nb != 20){
          unsigned short* mp = &mx3u[p*128 + c];
          unsigned cur = *mp;
          if (ml > cur) *mp = (unsigned short)ml;
        }
      }
    }
    __syncthreads();
  }
  int bn0 = blockIdx.x*16;
  {
    int p = tid >> 5, c0 = (tid & 31)*8;
    uint4 v = *(const uint4*)&mx4u[p*256 + c0];
    *(uint4*)&cat[(size_t)(bn0+p)*512 + 256 + c0] = v;
  }
  if (tid < 256){
    int p = tid >> 4, c0 = (tid & 15)*8;
    uint4 v = *(const uint4*)&mx3u[p*128 + c0];
    *(uint4*)&cat[(size_t)(bn0+p)*512 + 128 + c0] = v;
  }
}

// ---------------- layer 5 v4: double-buffered A-tiles + ob union (9 barriers vs 16) ----
__global__ __launch_bounds__(512) void l5_kernel(const bf16* __restrict__ cat,
                                                const bf16* __restrict__ W5T,
                                                const float* __restrict__ scale,
                                                const float* __restrict__ shift,
                                                float* __restrict__ out){
  __shared__ float obu[64*129];            // 33024 B; aliased as cs2[2][64*68] (17408 B)
  short* cs2 = (short*)obu;
  float* ob = obu;
  int tid = threadIdx.x, lane = tid & 63, w = tid >> 6;
  int pl = lane & 31;
  int ko = (lane >> 5)*8;
  int rbase = 4*(lane>>5);
  int mt = w & 1, ntb = w >> 1;          // nt = ntb + 4*s, s=0..3
  int arow = (mt*32 + pl)*68;
  int trow = tid >> 3, tc0 = (tid & 7)*8;
  int r0 = blockIdx.x*64;
  floatx16 acc[4];
  #pragma unroll
  for (int s=0;s<4;++s)
    #pragma unroll
    for (int q=0;q<16;++q) acc[s][q]=0.f;
  const bf16* arow_g = cat + (size_t)(r0+trow)*512 + tc0;
  uint4 hreg = *(const uint4*)arow_g;
  {
    short* dst = &cs2[trow*68 + tc0];
    *(uint2*)dst       = make_uint2(hreg.x, hreg.y);
    *(uint2*)(dst + 4) = make_uint2(hreg.z, hreg.w);
  }
  hreg = *(const uint4*)(arow_g + 64);
  __syncthreads();
  for (int kc8=0; kc8<8; ++kc8){
    int cur = kc8 & 1;
    if (kc8 < 7){
      short* dst = &cs2[(cur^1)*64*68 + trow*68 + tc0];
      *(uint2*)dst       = make_uint2(hreg.x, hreg.y);
      *(uint2*)(dst + 4) = make_uint2(hreg.z, hreg.w);
      if (kc8 < 6) hreg = *(const uint4*)(arow_g + (kc8+2)*64);
    }
    const short* csb = cs2 + cur*64*68;
    #pragma unroll
    for (int kq=0;kq<4;++kq){
      Frag a;
      const short* ap = &csb[arow + kq*16 + ko];
      a.u2[0] = *(const uint2*)ap;  a.u2[1] = *(const uint2*)(ap+4);
      #pragma unroll
      for (int s=0;s<4;++s){
        FragQ b;
        int col = (ntb + 4*s)*32 + pl;
        b.q = *(const uint4*)&W5T[(size_t)col*512 + kc8*64 + kq*16 + ko];
        acc[s] = __builtin_amdgcn_mfma_f32_32x32x16_bf16(a.v, b.v, acc[s], 0, 0, 0);
      }
    }
    __syncthreads();
  }
  int b = r0 >> 12, n0 = r0 & 4095;
  int colL = ntb*32 + pl;                // 0..127 within chunk
  int colc = tid >> 2, sub = tid & 3;    // writer mapping: 4 threads per col
  for (int s=0;s<4;++s){
    float sc = scale[128*s + colL], sh = shift[128*s + colL];
    #pragma unroll
    for (int q=0;q<16;++q){
      int m = mt*32 + (q&3) + 8*(q>>2) + rbase;
      ob[m*129 + colL] = fmaxf(fmaf(acc[s][q], sc, sh), 0.f);
    }
    __syncthreads();
    float* op = out + ((size_t)b*512 + 128*s + colc)*4096 + n0 + sub*16;
    #pragma unroll
    for (int j=0;j<4;++j){
      int rr = sub*16 + j*4;
      float4 v = make_float4(ob[(rr+0)*129 + colc], ob[(rr+1)*129 + colc],
                             ob[(rr+2)*129 + colc], ob[(rr+3)*129 + colc]);
      *(float4*)(op + j*4) = v;
    }
    __syncthreads();
  }
}

extern "C" void kernel_launch(void* const* d_in, const int* in_sizes, int n_in,
                              void* d_out, int out_size, void* d_ws, size_t ws_size,
                              hipStream_t stream){
  const float* x   = (const float*)d_in[0];
  const float* W1f = (const float*)d_in[1];
  const float* W2f = (const float*)d_in[2];
  const float* W3f = (const float*)d_in[3];
  const float* W4f = (const float*)d_in[4];
  const float* W5f = (const float*)d_in[5];
  const float* g1=(const float*)d_in[6],  *b1=(const float*)d_in[7];
  const float* g2=(const float*)d_in[8],  *b2=(const float*)d_in[9];
  const float* g3=(const float*)d_in[10], *b3=(const float*)d_in[11];
  const float* g4=(const float*)d_in[12], *b4=(const float*)d_in[13];
  const float* g5=(const float*)d_in[14], *b5=(const float*)d_in[15];
  float* out = (float*)d_out;

  char* w = (char*)d_ws;
  size_t off = 0;
  auto alloc = [&](size_t bytes)->void*{
    void* p = w + off;
    off = (off + bytes + 255) & ~(size_t)255;
    return p;
  };

  int*  idxb = (int*) alloc((size_t)BN*Kk*4);
  bf16* H2   = (bf16*)alloc((size_t)Mrows*64*2);
  bf16* catb = (bf16*)alloc((size_t)BN*512*2);
  bf16* W3T  = (bf16*)alloc((size_t)128*64*2);
  bf16* W4T  = (bf16*)alloc((size_t)256*128*2);
  bf16* W5T  = (bf16*)alloc((size_t)512*512*2);
  float* pv  = (float*)H2;
  int*   pib = (int*)((char*)H2 + (size_t)BN*8*Kk*4);

  size_t statsStart = off;
  float* partf=(float*)alloc(256*48*4);
  float* Gf=(float*)alloc(36*4);
  float* sumf=(float*)alloc(8*4);
  float* G2=(float*)alloc(4096*4);   float* sum2=(float*)alloc(64*4);
  float* G3=(float*)alloc(4096*4);   float* sum3=(float*)alloc(64*4);
  float* G4=(float*)alloc(16384*4);  float* sum4=(float*)alloc(128*4);
  float* G5=(float*)alloc(262144*4); float* sum5=(float*)alloc(512*4);
  float* P1=(float*)alloc(384*4);
  float* P2=(float*)alloc(4096*4);
  float* P3=(float*)alloc(8192*4);
  float* P4=(float*)alloc(32768*4);
  float* P5=(float*)alloc(262144*4);
  float* sc1=(float*)alloc(64*4);   float* sh1=(float*)alloc(64*4);
  float* sc2=(float*)alloc(64*4);   float* sh2=(float*)alloc(64*4);
  float* sc3=(float*)alloc(128*4);  float* sh3=(float*)alloc(128*4);
  float* sc4=(float*)alloc(256*4);  float* sh4=(float*)alloc(256*4);
  float* sc5=(float*)alloc(512*4);  float* sh5=(float*)alloc(512*4);
  size_t statsEnd = off;

  int statsFloats = (int)((statsEnd - statsStart)/4);
  zero_kernel<<<(statsFloats+255)/256,256,0,stream>>>((float*)(w+statsStart), statsFloats);
  w3t_kernel<<<32,256,0,stream>>>(W3f, W3T);
  w4t_kernel<<<128,256,0,stream>>>(W4f, W4T);
  w5t_kernel<<<1024,256,0,stream>>>(W5f, W5T);

  knnA_kernel<<<1024,256,0,stream>>>(x, pv, pib);
  knnB_kernel<<<BN/256,256,0,stream>>>(pv, pib, x, idxb, partf);

  const float invM  = 1.0f/(float)Mrows;
  const float invM5 = 1.0f/(float)BN;

  reducef_kernel<<<1,64,0,stream>>>(partf, Gf, sumf);
  kP_kernel<<<2,256,0,stream>>>(Gf, W1f, P1, 6, 64);
  kFinal_kernel<<<4,256,0,stream>>>(P1, sumf, W1f, g1, b1, sc1, sh1, 6, 64, invM);

  stats2_kernel<<<512,512,0,stream>>>(x, idxb, W1f, sc1, sh1, G2, sum2);
  kP_kernel<<<16,256,0,stream>>>(G2, W2f, P2, 64, 64);
  kFinal_kernel<<<4,256,0,stream>>>(P2, sum2, W2f, g2, b2, sc2, sh2, 64, 64, invM);

  fl12_kernel<<<BN,64,0,stream>>>(x, idxb, W1f, sc1, sh1, W2f, sc2, sh2, H2, catb);

  gram3_kernel<<<512,256,0,stream>>>(H2, Mrows, G3, sum3);
  kP_kernel<<<32,256,0,stream>>>(G3, W3f, P3, 64, 128);
  kFinal_kernel<<<8,256,0,stream>>>(P3, sum3, W3f, g3, b3, sc3, sh3, 64, 128, invM);

  stats4_kernel<<<512,512,0,stream>>>(H2, W3T, sc3, sh3, G4, sum4);
  kP_kernel<<<128,256,0,stream>>>(G4, W4f, P4, 128, 256);
  kFinal_kernel<<<16,256,0,stream>>>(P4, sum4, W4f, g4, b4, sc4, sh4, 128, 256, invM);

  fl34_kernel<<<Mrows/320,512,0,stream>>>(H2, W3T, sc3, sh3, W4T, sc4, sh4, catb);

  gram5_kernel<<<512,256,0,stream>>>(catb, G5, sum5);
  kP_kernel<<<1024,256,0,stream>>>(G5, W5f, P5, 512, 512);
  kFinal_kernel<<<32,256,0,stream>>>(P5, sum5, W5f, g5, b5, sc5, sh5, 512, 512, invM5);
  l5_kernel<<<BN/64,512,0,stream>>>(catb, W5T, sc5, sh5, out);
}

// Round 15
// 976.169 us; speedup vs baseline: 1.5957x; 1.1008x over previous
//
#include <hip/hip_runtime.h>
#include <hip/hip_bf16.h>
#include <cfloat>

using bf16 = __hip_bfloat16;

typedef short short8 __attribute__((ext_vector_type(8)));
typedef float floatx16 __attribute__((ext_vector_type(16)));
union Frag { short8 v; uint2 u2[2]; };
union FragQ { short8 v; uint4 q; uint2 u2[2]; };
union U4b { uint4 q; unsigned short s[8]; };

constexpr int Bb = 8, Nn = 4096, Kk = 20;
constexpr int BN = Bb * Nn;                     // 32768
constexpr int Mrows = BN * Kk;                  // 655360
constexpr float EPSf = 1e-5f;

static __device__ __forceinline__ float b2f(bf16 v){ return __bfloat162float(v); }
static __device__ __forceinline__ bf16 f2b(float v){ return __float2bfloat16(v); }
static __device__ __forceinline__ unsigned short f2bu(float v){
  union { bf16 b; unsigned short u; } cv; cv.b = __float2bfloat16(v); return cv.u;
}
static __device__ __forceinline__ float bits2f(unsigned short u){
  union { unsigned int i; float f; } c; c.i = ((unsigned)u)<<16; return c.f;
}

// ---------------- zero workspace region ----------------
__global__ void zero_kernel(float* __restrict__ p, int n){
  int i = blockIdx.x*256 + threadIdx.x;
  if (i < n) p[i] = 0.f;
}

// ---------------- W3^T bf16 pack ----------------
__global__ void w3t_kernel(const float* __restrict__ W3f, bf16* __restrict__ W3T){
  int id = blockIdx.x*256 + threadIdx.x;   // 128*64 = 8192 elems
  if (id >= 128*64) return;
  int n = id >> 6, k = id & 63;
  W3T[id] = f2b(W3f[(size_t)k*128 + n]);
}

// ---------------- W4^T bf16 pack ----------------
__global__ void w4t_kernel(const float* __restrict__ W4f, bf16* __restrict__ W4T){
  int id = blockIdx.x*256 + threadIdx.x;   // 128*256 = 32768 elems
  if (id >= 128*256) return;
  int k = id >> 8, c = id & 255;           // coalesced read of W4f
  W4T[(size_t)c*128 + k] = f2b(W4f[id]);
}

// ---------------- W5^T bf16 pack ----------------
__global__ void w5t_kernel(const float* __restrict__ W5f, bf16* __restrict__ W5T){
  int id = blockIdx.x*256 + threadIdx.x;   // 512*512 = 262144 elems
  if (id >= 512*512) return;
  int k = id >> 9, c = id & 511;           // coalesced read of W5f
  W5T[(size_t)c*512 + k] = f2b(W5f[id]);
}

// ---------------- KNN phase A v9: bottom-13 min-network threshold ----------------
// Pass A only consumes the 20th-largest of 32 group-maxes = 13th-SMALLEST (32-13+1=20).
// Maintain the 13 smallest gmaxes (25 ops/insert, dual of the proven max-network)
// instead of the full top-20 (39 ops): -448 ops/thread, thr bit-identical => same
// admits => same output. Everything else is the measured-best v8 shape.
__global__ __launch_bounds__(256) void knnA_kernel(const float* __restrict__ x,
                                                   float* __restrict__ pv, int* __restrict__ pi){
#pragma clang fp contract(off)
  __shared__ float4 p4[512];
  __shared__ unsigned short lst[256*62];
  int blk = blockIdx.x;
  int stripe = blk & 7;
  int chunk  = (blk >> 3) & 15;
  int b      = blk >> 7;
  const float* xb = x + b*3*Nn;
  int j0 = stripe*512;
  for (int u = threadIdx.x; u < 512; u += 256){
    int j = j0 + u;
    float a0 = xb[j];
    float a1 = xb[Nn + j];
    float a2 = xb[2*Nn + j];
    float s = a0*a0; s = s + a1*a1; s = s + a2*a2;
    p4[u] = make_float4(a0, a1, a2, s);
  }
  __syncthreads();
  int i = chunk*256 + threadIdx.x;
  float xi = xb[i], yi = xb[Nn+i], zi = xb[2*Nn+i];
  float ni = xi*xi; ni = ni + yi*yi; ni = ni + zi*zi;
  float mni = -ni;
  float xi2 = xi + xi, yi2 = yi + yi, zi2 = zi + zi;
  // ---- pass A: 32 group-maxes (groups of 16, fast nd) -> bottom-13 min-network ----
  float bv[13];
  #pragma unroll
  for (int s=0;s<13;++s) bv[s] = FLT_MAX;
  for (int g=0; g<32; ++g){
    float gm = -FLT_MAX;
    #pragma unroll
    for (int e=0;e<16;++e){
      float4 p = p4[g*16+e];
      float base = mni - p.w;
      float nd = fmaf(xi2, p.x, fmaf(yi2, p.y, fmaf(zi2, p.z, base)));
      gm = fmaxf(gm, nd);
    }
    #pragma unroll
    for (int s=12; s>=1; --s)
      bv[s] = fminf(bv[s], fmaxf(bv[s-1], gm));
    bv[0] = fminf(bv[0], gm);
  }
  float thr = bv[12];                       // == 20th-largest of the 32 gmaxes
  thr = thr - (fabsf(thr)*1e-5f + 1e-6f);   // margin >> fast-vs-exact fp discrepancy
  // ---- pass B: fast compare, collect u16 indices (ascending u => stable) ----
  unsigned short* ml = &lst[threadIdx.x*62];
  int cnt = 0;
  for (int u=0; u<512; ++u){
    float4 p = p4[u];
    float base = mni - p.w;
    float nd = fmaf(xi2, p.x, fmaf(yi2, p.y, fmaf(zi2, p.z, base)));
    if (nd >= thr && cnt < 60){ ml[cnt] = (unsigned short)u; ++cnt; }
  }
  // ---- final: EXACT (val,idx) insertion sort ----
  float av[Kk]; int ai[Kk];
  #pragma unroll
  for (int s=0;s<Kk;++s){ av[s] = -FLT_MAX; ai[s] = 0; }
  if (cnt >= 60){
    // exact fallback: full branchy scan (statistically never; correctness guarantee)
    for (int u=0; u<512; ++u){
      float4 p = p4[u];
      float dot = xi*p.x; dot = dot + yi*p.y; dot = dot + zi*p.z;
      float inner = -2.0f*dot;
      float nd = mni - inner; nd = nd - p.w;
      if (nd > av[Kk-1]){
        #pragma unroll
        for (int s=Kk-1; s>=1; --s){
          bool cs = nd > av[s];
          bool cp = nd > av[s-1];
          av[s] = cs ? (cp ? av[s-1] : nd) : av[s];
          ai[s] = cs ? (cp ? ai[s-1] : (j0+u)) : ai[s];
        }
        if (nd > av[0]){ av[0] = nd; ai[0] = j0+u; }
      }
    }
  } else {
    for (int t=0; t<cnt; ++t){
      int lj = ml[t];
      float4 p = p4[lj];
      float dot = xi*p.x; dot = dot + yi*p.y; dot = dot + zi*p.z;
      float inner = -2.0f*dot;
      float nd = mni - inner; nd = nd - p.w;
      if (nd > av[Kk-1]){
        #pragma unroll
        for (int s=Kk-1; s>=1; --s){
          bool cs = nd > av[s];
          bool cp = nd > av[s-1];
          av[s] = cs ? (cp ? av[s-1] : nd) : av[s];
          ai[s] = cs ? (cp ? ai[s-1] : (j0+lj)) : ai[s];
        }
        if (nd > av[0]){ av[0] = nd; ai[0] = j0+lj; }
      }
    }
  }
  long long base = ((long long)(b*Nn + i)*8 + stripe)*Kk;
  #pragma unroll
  for (int s=0;s<Kk;++s){ pv[base+s] = av[s]; pi[base+s] = ai[s]; }
}

// ---------------- KNN phase B + fused layer-1 stats ----------------
__global__ __launch_bounds__(256) void knnB_kernel(const float* __restrict__ pv,
                                                   const int* __restrict__ pi,
                                                   const float* __restrict__ x,
                                                   int* __restrict__ idx,
                                                   float* __restrict__ part){
  int p = blockIdx.x*256 + threadIdx.x;    // grid 128 x 256 = BN exactly
  long long base = (long long)p*8*Kk;
  float av[Kk]; int ai[Kk];
  #pragma unroll
  for (int s=0;s<Kk;++s){ av[s]=pv[base+s]; ai[s]=pi[base+s]; }
  for (int t=Kk; t<8*Kk; ++t){
    float nd = pv[base+t]; int j = pi[base+t];
    if (nd > av[Kk-1]){
      #pragma unroll
      for (int s=Kk-1;s>=1;--s){
        bool cs = nd > av[s];
        bool cp = nd > av[s-1];
        av[s] = cs ? (cp?av[s-1]:nd) : av[s];
        ai[s] = cs ? (cp?ai[s-1]:j) : ai[s];
      }
      if (nd > av[0]){ av[0]=nd; ai[0]=j; }
    }
  }
  #pragma unroll
  for (int s=0;s<Kk;++s) idx[(long long)p*Kk+s] = ai[s];
  // ---- fused layer-1 stats ----
  int b = p >> 12, n = p & 4095;
  const float* xb = x + b*3*Nn;
  float cx = xb[n], cy = xb[Nn+n], cz = xb[2*Nn+n];
  float snx=0.f, sny=0.f, snz=0.f;
  float a00=0.f,a01=0.f,a02=0.f,a11=0.f,a12=0.f,a22=0.f;
  #pragma unroll
  for (int s=0;s<Kk;++s){
    int j = ai[s];
    float nx = xb[j], ny = xb[Nn+j], nz = xb[2*Nn+j];
    snx += nx; sny += ny; snz += nz;
    a00 = fmaf(nx,nx,a00); a01 = fmaf(nx,ny,a01); a02 = fmaf(nx,nz,a02);
    a11 = fmaf(ny,ny,a11); a12 = fmaf(ny,nz,a12); a22 = fmaf(nz,nz,a22);
  }
  float acc[36];
  acc[0]=a00;  acc[1]=a01;  acc[2]=a02;
  acc[6]=a01;  acc[7]=a11;  acc[8]=a12;
  acc[12]=a02; acc[13]=a12; acc[14]=a22;
  acc[3]=snx*cx;  acc[4]=snx*cy;  acc[5]=snx*cz;
  acc[9]=sny*cx;  acc[10]=sny*cy; acc[11]=sny*cz;
  acc[15]=snz*cx; acc[16]=snz*cy; acc[17]=snz*cz;
  acc[18]=cx*snx; acc[19]=cx*sny; acc[20]=cx*snz;
  acc[24]=cy*snx; acc[25]=cy*sny; acc[26]=cy*snz;
  acc[30]=cz*snx; acc[31]=cz*sny; acc[32]=cz*snz;
  float k20 = (float)Kk;
  acc[21]=k20*cx*cx; acc[22]=k20*cx*cy; acc[23]=k20*cx*cz;
  acc[27]=k20*cy*cx; acc[28]=k20*cy*cy; acc[29]=k20*cy*cz;
  acc[33]=k20*cz*cx; acc[34]=k20*cz*cy; acc[35]=k20*cz*cz;
  float s6[6] = { snx, sny, snz, k20*cx, k20*cy, k20*cz };
  __shared__ float red[256];
  #pragma unroll
  for (int v=0; v<42; ++v){
    red[threadIdx.x] = (v<36)? acc[v] : s6[v-36];
    __syncthreads();
    for (int s=128; s>0; s>>=1){
      if (threadIdx.x < s) red[threadIdx.x] += red[threadIdx.x+s];
      __syncthreads();
    }
    if (threadIdx.x==0) part[blockIdx.x*48 + v] = red[0];
    __syncthreads();
  }
}

__global__ void reducef_kernel(const float* __restrict__ part, float* __restrict__ Gf,
                               float* __restrict__ sumf){
  int t = threadIdx.x;
  if (t < 42){
    float s = 0.f;
    for (int i=0;i<128;++i) s += part[i*48 + t];
    if (t<36) Gf[t]=s; else sumf[t-36]=s;
  }
}

// ---------------- G3 gram (CIN=64) with fused column sums ----------------
__global__ __launch_bounds__(256) void gram3_kernel(const bf16* __restrict__ H, int M,
                                                    float* __restrict__ G,
                                                    float* __restrict__ sumh){
  __shared__ short HTa[64*68];
  __shared__ float csum[64];
  int tid = threadIdx.x, lane = tid & 63, w = tid >> 6;
  if (tid < 64) csum[tid] = 0.f;
  int nchunks = gridDim.x;
  int rpc = M / nchunks;
  int r0 = blockIdx.x*rpc;
  int mt = w >> 1, nt = w & 1;
  floatx16 acc;
  #pragma unroll
  for (int q=0;q<16;++q) acc[q]=0.f;
  int arow = (mt*32 + (lane&31))*68;
  int brow = (nt*32 + (lane&31))*68;
  int ko = (lane>>5)*8;
  int c0s = (tid & 7)*8;
  float cs[8];
  #pragma unroll
  for (int j=0;j<8;++j) cs[j]=0.f;
  for (int rb=r0; rb<r0+rpc; rb+=64){
    #pragma unroll
    for (int s=0;s<2;++s){
      int e = tid + s*256;
      int row = e >> 3;
      U4b va; va.q = *(const uint4*)&H[(size_t)(rb+row)*64 + c0s];
      #pragma unroll
      for (int j=0;j<8;++j){
        HTa[(c0s+j)*68 + row] = (short)va.s[j];
        cs[j] += bits2f(va.s[j]);
      }
    }
    __syncthreads();
    #pragma unroll
    for (int kc=0;kc<64;kc+=16){
      Frag a, b;
      const short* ap = &HTa[arow + kc + ko];
      const short* bp = &HTa[brow + kc + ko];
      a.u2[0] = *(const uint2*)ap;  a.u2[1] = *(const uint2*)(ap+4);
      b.u2[0] = *(const uint2*)bp;  b.u2[1] = *(const uint2*)(bp+4);
      acc = __builtin_amdgcn_mfma_f32_32x32x16_bf16(a.v, b.v, acc, 0, 0, 0);
    }
    __syncthreads();
  }
  int col = lane & 31, rbase = 4*(lane>>5);
  #pragma unroll
  for (int r=0;r<16;++r){
    int row = (r&3) + 8*(r>>2) + rbase;
    atomicAdd(&G[(size_t)(mt*32 + row)*64 + nt*32 + col], acc[r]);
  }
  #pragma unroll
  for (int j=0;j<8;++j) atomicAdd(&csum[c0s+j], cs[j]);
  __syncthreads();
  if (tid < 64) atomicAdd(&sumh[tid], csum[tid]);
}

// ---------------- G5 gram (CIN=512): 128-wide tiles + fused column sums ----------------
__global__ __launch_bounds__(256) void gram5_kernel(const bf16* __restrict__ H,
                                                    float* __restrict__ G,
                                                    float* __restrict__ sumh){
  __shared__ short HTa[128*68];
  __shared__ short HTb[128*68];
  __shared__ float csum[128];
  int blk = blockIdx.x;
  int pair = blk & 15;
  int chunk = blk >> 4;            // 0..31
  int tr = pair >> 2, tc = pair & 3;
  bool diag = (tr == tc);
  int tid = threadIdx.x, lane = tid & 63, w = tid >> 6;   // 4 waves
  if (tid < 128) csum[tid] = 0.f;
  int rpc = BN / 32;               // 1024
  int r0 = chunk*rpc;
  int pl = lane & 31, ko = (lane>>5)*8, rbase = 4*(lane>>5);
  int mt = w;
  int arow = (mt*32 + pl)*68;
  floatx16 acc[4];
  #pragma unroll
  for (int nt=0;nt<4;++nt)
    #pragma unroll
    for (int q=0;q<16;++q) acc[nt][q]=0.f;
  int c0s = (tid & 15)*8;
  float cs[8];
  #pragma unroll
  for (int j=0;j<8;++j) cs[j]=0.f;
  const short* Bbase = diag ? HTa : HTb;
  for (int rb=r0; rb<r0+rpc; rb+=64){
    #pragma unroll
    for (int s=0;s<4;++s){
      int e = tid + s*256;
      int row = e >> 4;
      U4b va; va.q = *(const uint4*)&H[(size_t)(rb+row)*512 + tr*128 + c0s];
      #pragma unroll
      for (int j=0;j<8;++j) HTa[(c0s+j)*68 + row] = (short)va.s[j];
      if (diag){
        #pragma unroll
        for (int j=0;j<8;++j) cs[j] += bits2f(va.s[j]);
      } else {
        U4b vb; vb.q = *(const uint4*)&H[(size_t)(rb+row)*512 + tc*128 + c0s];
        #pragma unroll
        for (int j=0;j<8;++j) HTb[(c0s+j)*68 + row] = (short)vb.s[j];
      }
    }
    __syncthreads();
    #pragma unroll
    for (int kc=0;kc<64;kc+=16){
      Frag a;
      const short* ap = &HTa[arow + kc + ko];
      a.u2[0] = *(const uint2*)ap;  a.u2[1] = *(const uint2*)(ap+4);
      #pragma unroll
      for (int nt=0;nt<4;++nt){
        Frag b;
        const short* bp = &Bbase[(nt*32 + pl)*68 + kc + ko];
        b.u2[0] = *(const uint2*)bp;  b.u2[1] = *(const uint2*)(bp+4);
        acc[nt] = __builtin_amdgcn_mfma_f32_32x32x16_bf16(a.v, b.v, acc[nt], 0, 0, 0);
      }
    }
    __syncthreads();
  }
  #pragma unroll
  for (int nt=0;nt<4;++nt){
    #pragma unroll
    for (int r=0;r<16;++r){
      int row = (r&3) + 8*(r>>2) + rbase;
      atomicAdd(&G[(size_t)(tr*128 + mt*32 + row)*512 + tc*128 + nt*32 + pl], acc[nt][r]);
    }
  }
  if (diag){
    #pragma unroll
    for (int j=0;j<8;++j) atomicAdd(&csum[c0s+j], cs[j]);
    __syncthreads();
    if (tid < 128) atomicAdd(&sumh[tr*128 + tid], csum[tid]);
  }
}

// ---------------- P = G @ W (generic, small cases) ----------------
__global__ void kP_kernel(const float* __restrict__ G, const float* __restrict__ Wf,
                          float* __restrict__ P, int Cin, int Cout){
  int id = blockIdx.x*256 + threadIdx.x;
  if (id >= Cin*Cout) return;
  int i = id / Cout, j = id - i*Cout;
  float s = 0.f;
  for (int k=0;k<Cin;++k) s = fmaf(G[(size_t)i*Cin+k], Wf[(size_t)k*Cout+j], s);
  P[id] = s;
}

// ---------------- P5 = G5 @ W5 specialized (512x512x512) ----------------
// Generic kP at this size re-reads all of W5f per block (~1 GB L2, 268M load-ops).
// Here: 8 G-rows staged in LDS (broadcast reads), one coalesced Wf row-load per k
// shared across 8 outputs. Same k-ascending fma order => bit-identical P5.
__global__ __launch_bounds__(256) void kP512_kernel(const float* __restrict__ G,
                                                    const float* __restrict__ Wf,
                                                    float* __restrict__ P){
  __shared__ float Gs[8][512];   // 16 KB
  int tid = threadIdx.x;
  int r0 = (blockIdx.x >> 1) * 8;          // 64 row-groups
  int j  = (blockIdx.x & 1) * 256 + tid;   // col
  for (int u = tid; u < 8*512; u += 256)
    Gs[u >> 9][u & 511] = G[(size_t)(r0 + (u >> 9))*512 + (u & 511)];
  __syncthreads();
  float acc[8];
  #pragma unroll
  for (int i=0;i<8;++i) acc[i]=0.f;
  for (int k=0;k<512;++k){
    float wv = Wf[(size_t)k*512 + j];
    #pragma unroll
    for (int i=0;i<8;++i) acc[i] = fmaf(Gs[i][k], wv, acc[i]);
  }
  #pragma unroll
  for (int i=0;i<8;++i) P[(size_t)(r0+i)*512 + j] = acc[i];
}

// ---------------- scale/shift v2: i-parallel (16 sub-slices/column) ----------------
__global__ __launch_bounds__(256) void kFinal_kernel(const float* __restrict__ P,
                              const float* __restrict__ sumh,
                              const float* __restrict__ Wf, const float* __restrict__ g,
                              const float* __restrict__ bb, float* __restrict__ scale,
                              float* __restrict__ shift, int Cin, int Cout, float invM){
  __shared__ float redm[256], rede[256];
  int tid = threadIdx.x;
  int j = blockIdx.x*16 + (tid & 15);
  int sub = tid >> 4;
  float mean = 0.f, e2 = 0.f;
  for (int i = sub; i < Cin; i += 16){
    float w = Wf[(size_t)i*Cout + j];
    mean = fmaf(sumh[i], w, mean);
    e2   = fmaf(w, P[(size_t)i*Cout + j], e2);
  }
  redm[tid] = mean; rede[tid] = e2;
  __syncthreads();
  for (int s = 128; s >= 16; s >>= 1){
    if (tid < s){ redm[tid] += redm[tid+s]; rede[tid] += rede[tid+s]; }
    __syncthreads();
  }
  if (tid < 16){
    float m = redm[tid]*invM, e = rede[tid]*invM;
    float var = e - m*m;
    float inv = rsqrtf(var + EPSf);
    float sc = g[j]*inv;
    scale[j] = sc;
    shift[j] = bb[j] - m*sc;
  }
}

// ---------------- layer-2 stats ----------------
__global__ __launch_bounds__(512) void stats2_kernel(const float* __restrict__ x,
    const int* __restrict__ idx, const float* __restrict__ W1f,
    const float* __restrict__ sc1v, const float* __restrict__ sh1v,
    float* __restrict__ G2, float* __restrict__ sum2){
  __shared__ float W1s[6][64];
  __shared__ float fsh[64][8];
  __shared__ short H1T[64*68];
  __shared__ float csum[64];
  int tid = threadIdx.x, lane = tid & 63, w = tid >> 6;   // 8 waves
  if (tid < 384) W1s[tid>>6][tid&63] = W1f[tid];
  if (tid < 64) csum[tid] = 0.f;
  int rp = tid >> 4, cq = tid & 15, c0 = cq*4;
  float sca[4], sha[4];
  #pragma unroll
  for (int k=0;k<4;++k){ sca[k]=sc1v[c0+k]; sha[k]=sh1v[c0+k]; }
  int mt = w & 1, nt = (w>>1) & 1, kh = w >> 2;
  int arow = (mt*32 + (lane&31))*68;
  int brow = (nt*32 + (lane&31))*68;
  int ko = (lane>>5)*8;
  floatx16 acc;
  #pragma unroll
  for (int q=0;q<16;++q) acc[q]=0.f;
  float cs[4] = {0.f,0.f,0.f,0.f};
  int rpc = Mrows / gridDim.x;
  int r0 = blockIdx.x * rpc;
  __syncthreads();
  for (int rb=r0; rb<r0+rpc; rb+=64){
    {
      int r = tid>>3, e = tid&7;
      if (e < 6){
        int grow = rb + r;
        int bn = grow / Kk;
        int b = bn >> 12, n = bn & 4095;
        int j = idx[grow];
        const float* xb = x + b*3*Nn;
        fsh[r][e] = (e<3) ? xb[e*Nn + j] : xb[(e-3)*Nn + n];
      }
    }
    __syncthreads();
    {
      float y0[4]={0,0,0,0}, y1[4]={0,0,0,0};
      int ra = rp*2, rbw = rp*2+1;
      #pragma unroll
      for (int i=0;i<6;++i){
        float fa = fsh[ra][i], fb = fsh[rbw][i];
        float4 wv = *(const float4*)&W1s[i][c0];
        y0[0]=fmaf(fa,wv.x,y0[0]); y0[1]=fmaf(fa,wv.y,y0[1]);
        y0[2]=fmaf(fa,wv.z,y0[2]); y0[3]=fmaf(fa,wv.w,y0[3]);
        y1[0]=fmaf(fb,wv.x,y1[0]); y1[1]=fmaf(fb,wv.y,y1[1]);
        y1[2]=fmaf(fb,wv.z,y1[2]); y1[3]=fmaf(fb,wv.w,y1[3]);
      }
      #pragma unroll
      for (int k=0;k<4;++k){
        float va = fmaxf(fmaf(y0[k],sca[k],sha[k]),0.f);
        float vb = fmaxf(fmaf(y1[k],sca[k],sha[k]),0.f);
        cs[k] += va; cs[k] += vb;
        unsigned int pk = f2bu(va) | ((unsigned)f2bu(vb)<<16);
        *(unsigned int*)&H1T[(c0+k)*68 + ra] = pk;
      }
    }
    __syncthreads();
    {
      int kc = kh*32;
      #pragma unroll
      for (int s=0;s<2;++s){
        Frag a, b;
        const short* ap = &H1T[arow + kc + s*16 + ko];
        const short* bp = &H1T[brow + kc + s*16 + ko];
        a.u2[0] = *(const uint2*)ap;  a.u2[1] = *(const uint2*)(ap+4);
        b.u2[0] = *(const uint2*)bp;  b.u2[1] = *(const uint2*)(bp+4);
        acc = __builtin_amdgcn_mfma_f32_32x32x16_bf16(a.v, b.v, acc, 0, 0, 0);
      }
    }
    __syncthreads();
  }
  int col = lane & 31, rbase = 4*(lane>>5);
  #pragma unroll
  for (int r=0;r<16;++r){
    int row = (r&3) + 8*(r>>2) + rbase;
    atomicAdd(&G2[(size_t)(mt*32+row)*64 + nt*32+col], acc[r]);
  }
  #pragma unroll
  for (int k=0;k<4;++k) atomicAdd(&csum[c0+k], cs[k]);
  __syncthreads();
  if (tid < 64) atomicAdd(&sum2[tid], csum[tid]);
}

// ---------------- fused layers 1+2 ----------------
__global__ __launch_bounds__(64) void fl12_kernel(const float* __restrict__ x,
    const int* __restrict__ idx, const float* __restrict__ W1f,
    const float* __restrict__ sc1v, const float* __restrict__ sh1v,
    const float* __restrict__ W2f, const float* __restrict__ sc2v,
    const float* __restrict__ sh2v, bf16* __restrict__ H2, bf16* __restrict__ cat){
  __shared__ float fsh[Kk][6];
  __shared__ float h1[Kk][64];
  __shared__ float mm[4][64];
  int bn = blockIdx.x, b = bn>>12, n = bn & 4095;
  int tid = threadIdx.x;
  if (tid < Kk){
    int j = idx[(size_t)bn*Kk + tid];
    const float* xb = x + b*3*Nn;
    fsh[tid][0]=xb[j]; fsh[tid][1]=xb[Nn+j]; fsh[tid][2]=xb[2*Nn+j];
    fsh[tid][3]=xb[n]; fsh[tid][4]=xb[Nn+n]; fsh[tid][5]=xb[2*Nn+n];
  }
  __syncthreads();
  {
    float sc=sc1v[tid], sh=sh1v[tid];
    float w[6];
    #pragma unroll
    for (int i=0;i<6;++i) w[i]=W1f[i*64+tid];
    float mx = 0.f;
    #pragma unroll
    for (int r=0;r<Kk;++r){
      float y=0.f;
      #pragma unroll
      for (int i=0;i<6;++i) y = fmaf(fsh[r][i], w[i], y);
      float v = fmaxf(fmaf(y,sc,sh),0.f);
      h1[r][tid]=v;
      mx = fmaxf(mx,v);
    }
    cat[(size_t)bn*512 + tid] = f2b(mx);
  }
  __syncthreads();
  int q = tid >> 4, c0 = (tid & 15)*4;
  float acc[5][4]={};
  for (int i0=0;i0<64;i0+=4){
    float hv[5][4];
    #pragma unroll
    for (int l=0;l<5;++l){
      float4 t4 = *(const float4*)&h1[q*5+l][i0];
      hv[l][0]=t4.x; hv[l][1]=t4.y; hv[l][2]=t4.z; hv[l][3]=t4.w;
    }
    #pragma unroll
    for (int ii=0;ii<4;++ii){
      const float* wp = W2f + (i0+ii)*64 + c0;
      float w0=wp[0],w1=wp[1],w2=wp[2],w3=wp[3];
      #pragma unroll
      for (int l=0;l<5;++l){
        float hvv=hv[l][ii];
        acc[l][0]=fmaf(hvv,w0,acc[l][0]);
        acc[l][1]=fmaf(hvv,w1,acc[l][1]);
        acc[l][2]=fmaf(hvv,w2,acc[l][2]);
        acc[l][3]=fmaf(hvv,w3,acc[l][3]);
      }
    }
  }
  float sc[4],sh[4];
  #pragma unroll
  for (int cb=0;cb<4;++cb){ sc[cb]=sc2v[c0+cb]; sh[cb]=sh2v[c0+cb]; }
  float mx[4]={0,0,0,0};
  #pragma unroll
  for (int l=0;l<5;++l){
    unsigned short us[4];
    #pragma unroll
    for (int cb=0;cb<4;++cb){
      float v=fmaxf(fmaf(acc[l][cb],sc[cb],sh[cb]),0.f);
      mx[cb]=fmaxf(mx[cb],v);
      us[cb]=f2bu(v);
    }
    uint2 v2; v2.x = us[0]|((unsigned)us[1]<<16); v2.y=us[2]|((unsigned)us[3]<<16);
    *(uint2*)(H2 + ((size_t)bn*Kk + q*5+l)*64 + c0) = v2;
  }
  #pragma unroll
  for (int cb=0;cb<4;++cb) mm[q][c0+cb]=mx[cb];
  __syncthreads();
  {
    float M0 = fmaxf(fmaxf(mm[0][tid],mm[1][tid]),fmaxf(mm[2][tid],mm[3][tid]));
    cat[(size_t)bn*512 + 64 + tid] = f2b(M0);
  }
}

// ---------------- layer-4 stats: MFMA produce + MFMA Gram ----------------
__global__ __launch_bounds__(512) void stats4_kernel(const bf16* __restrict__ H2,
    const bf16* __restrict__ W3T, const float* __restrict__ sc3v, const float* __restrict__ sh3v,
    float* __restrict__ G4, float* __restrict__ sum4){
  __shared__ short h2s[64*68];
  __shared__ short H3T[128*68];
  __shared__ float csum[128];
  int tid = threadIdx.x, lane = tid & 63, w = tid >> 6;   // 8 waves
  if (tid < 128) csum[tid] = 0.f;
  int trow = tid >> 3, tc0 = (tid & 7)*8;
  int pl  = lane & 31;
  int ko  = (lane >> 5)*8;
  int pmt = w >> 2, pnt = w & 3;
  int parow = (pmt*32 + pl)*68;
  int pcol  = pnt*32 + pl;
  float psc = sc3v[pcol], psh = sh3v[pcol];
  int prbase = 4*(lane>>5);
  FragQ bfr[4];
  #pragma unroll
  for (int kq=0;kq<4;++kq)
    bfr[kq].q = *(const uint4*)&W3T[(size_t)pcol*64 + kq*16 + ko];
  int gmt = w>>1, gnt0 = (w&1)*2, gnt1 = gnt0+1;
  int garow  = (gmt*32 + pl)*68;
  int gbrow0 = (gnt0*32 + pl)*68;
  int gbrow1 = (gnt1*32 + pl)*68;
  floatx16 acc0, acc1;
  #pragma unroll
  for (int q=0;q<16;++q){ acc0[q]=0.f; acc1[q]=0.f; }
  float cs = 0.f;
  int rpc = Mrows / gridDim.x;
  int r0 = blockIdx.x * rpc;
  uint4 hreg = *(const uint4*)&H2[(size_t)(r0+trow)*64 + tc0];
  for (int rb=r0; rb<r0+rpc; rb+=64){
    {
      short* dst = &h2s[trow*68 + tc0];
      *(uint2*)dst       = make_uint2(hreg.x, hreg.y);
      *(uint2*)(dst + 4) = make_uint2(hreg.z, hreg.w);
    }
    if (rb + 64 < r0 + rpc)
      hreg = *(const uint4*)&H2[(size_t)(rb+64+trow)*64 + tc0];
    __syncthreads();
    {
      floatx16 pacc;
      #pragma unroll
      for (int q=0;q<16;++q) pacc[q]=0.f;
      #pragma unroll
      for (int kq=0;kq<4;++kq){
        Frag a;
        const short* ap = &h2s[parow + kq*16 + ko];
        a.u2[0] = *(const uint2*)ap;  a.u2[1] = *(const uint2*)(ap+4);
        pacc = __builtin_amdgcn_mfma_f32_32x32x16_bf16(a.v, bfr[kq].v, pacc, 0, 0, 0);
      }
      #pragma unroll
      for (int g=0; g<4; ++g){
        unsigned short p[4];
        #pragma unroll
        for (int r=0;r<4;++r){
          float v = fmaxf(fmaf(pacc[g*4+r], psc, psh), 0.f);
          cs += v;
          p[r] = f2bu(v);
        }
        uint2 pk; pk.x = p[0] | ((unsigned)p[1]<<16); pk.y = p[2] | ((unsigned)p[3]<<16);
        *(uint2*)&H3T[pcol*68 + pmt*32 + 8*g + prbase] = pk;
      }
    }
    __syncthreads();
    #pragma unroll
    for (int kc=0;kc<64;kc+=16){
      Frag a, b0, b1;
      const short* ap  = &H3T[garow  + kc + ko];
      const short* bp0 = &H3T[gbrow0 + kc + ko];
      const short* bp1 = &H3T[gbrow1 + kc + ko];
      a.u2[0]  = *(const uint2*)ap;   a.u2[1]  = *(const uint2*)(ap+4);
      b0.u2[0] = *(const uint2*)bp0;  b0.u2[1] = *(const uint2*)(bp0+4);
      b1.u2[0] = *(const uint2*)bp1;  b1.u2[1] = *(const uint2*)(bp1+4);
      acc0 = __builtin_amdgcn_mfma_f32_32x32x16_bf16(a.v, b0.v, acc0, 0, 0, 0);
      acc1 = __builtin_amdgcn_mfma_f32_32x32x16_bf16(a.v, b1.v, acc1, 0, 0, 0);
    }
  }
  int col = pl;
  #pragma unroll
  for (int r=0;r<16;++r){
    int row = (r&3) + 8*(r>>2) + prbase;
    atomicAdd(&G4[(size_t)(gmt*32+row)*128 + gnt0*32+col], acc0[r]);
    atomicAdd(&G4[(size_t)(gmt*32+row)*128 + gnt1*32+col], acc1[r]);
  }
  atomicAdd(&csum[pcol], cs);
  __syncthreads();
  if (tid < 128) atomicAdd(&sum4[tid], csum[tid]);
}

// ---------------- fused layers 3+4: MFMA produce chain + col-owner maxpool ----------------
__global__ __launch_bounds__(512,4) void fl34_kernel(const bf16* __restrict__ H2,
    const bf16* __restrict__ W3T, const float* __restrict__ sc3v, const float* __restrict__ sh3v,
    const bf16* __restrict__ W4T, const float* __restrict__ sc4v, const float* __restrict__ sh4v,
    bf16* __restrict__ cat){
  __shared__ short h2s[64*68];             // 8.5 KB
  __shared__ short h3s[64*132];            // 16.5 KB
  __shared__ unsigned short h4s[64*256];   // 32 KB
  __shared__ unsigned short mx3u[16*128];  // 4 KB
  __shared__ unsigned short mx4u[16*256];  // 8 KB
  int tid = threadIdx.x, lane = tid & 63, w = tid >> 6;
  int pl = lane & 31;
  int ko = (lane >> 5)*8;
  int rbase = 4*(lane>>5);
  {
    unsigned* p4 = (unsigned*)mx4u;
    for (int u=tid; u<2048; u+=512) p4[u]=0u;
    unsigned* p3 = (unsigned*)mx3u;
    for (int u=tid; u<1024; u+=512) p3[u]=0u;
  }
  int mt3 = w >> 2, ct3 = w & 3;
  int c3 = ct3*32 + pl;
  float sc3 = sc3v[c3], sh3 = sh3v[c3];
  int a3row = (mt3*32 + pl)*68;
  int c4 = w*32 + pl;
  float sc4 = sc4v[c4], sh4 = sh4v[c4];
  int trow = tid >> 3, tc0 = (tid & 7)*8;
  int r0 = blockIdx.x * 320;
  uint4 hreg = *(const uint4*)&H2[(size_t)(r0+trow)*64 + tc0];
  {
    short* dst = &h2s[trow*68 + tc0];
    *(uint2*)dst       = make_uint2(hreg.x, hreg.y);
    *(uint2*)(dst + 4) = make_uint2(hreg.z, hreg.w);
  }
  hreg = *(const uint4*)&H2[(size_t)(r0 + 64 + trow)*64 + tc0];
  __syncthreads();
  for (int t=0; t<5; ++t){
    {
      floatx16 pa;
      #pragma unroll
      for (int q=0;q<16;++q) pa[q]=0.f;
      #pragma unroll
      for (int kq=0;kq<4;++kq){
        Frag a; FragQ b;
        const short* ap = &h2s[a3row + kq*16 + ko];
        a.u2[0] = *(const uint2*)ap;  a.u2[1] = *(const uint2*)(ap+4);
        b.q = *(const uint4*)&W3T[(size_t)c3*64 + kq*16 + ko];
        pa = __builtin_amdgcn_mfma_f32_32x32x16_bf16(a.v, b.v, pa, 0, 0, 0);
      }
      #pragma unroll
      for (int r=0;r<16;++r){
        int m = mt3*32 + (r&3) + 8*(r>>2) + rbase;
        float v = fmaxf(fmaf(pa[r], sc3, sh3), 0.f);
        h3s[m*132 + c3] = (short)f2bu(v);
      }
    }
    __syncthreads();
    #pragma unroll
    for (int mt4=0; mt4<2; ++mt4){
      floatx16 acc;
      #pragma unroll
      for (int q=0;q<16;++q) acc[q]=0.f;
      int a4row = (mt4*32 + pl)*132;
      #pragma unroll
      for (int kq=0;kq<8;++kq){
        Frag a; FragQ b;
        const short* ap = &h3s[a4row + kq*16 + ko];
        a.u2[0] = *(const uint2*)ap;  a.u2[1] = *(const uint2*)(ap+4);
        b.q = *(const uint4*)&W4T[(size_t)c4*128 + kq*16 + ko];
        acc = __builtin_amdgcn_mfma_f32_32x32x16_bf16(a.v, b.v, acc, 0, 0, 0);
      }
      #pragma unroll
      for (int r=0;r<16;++r){
        int m = mt4*32 + (r&3) + 8*(r>>2) + rbase;
        float v = fmaxf(fmaf(acc[r], sc4, sh4), 0.f);
        h4s[m*256 + c4] = f2bu(v);
      }
    }
    __syncthreads();
    if (t < 4){
      short* dst = &h2s[trow*68 + tc0];
      *(uint2*)dst       = make_uint2(hreg.x, hreg.y);
      *(uint2*)(dst + 4) = make_uint2(hreg.z, hreg.w);
      if (t < 3) hreg = *(const uint4*)&H2[(size_t)(r0 + (t+2)*64 + trow)*64 + tc0];
    }
    {
      int lr0 = t*64;
      if (tid < 256){
        int c = tid;
        int p = lr0/20;
        int nb = (p+1)*20 - lr0;
        unsigned ml = 0;
        for (int r=0;r<64;++r){
          unsigned v = h4s[r*256 + c];
          ml = v > ml ? v : ml;
          if (--nb == 0){
            unsigned short* mp = &mx4u[p*256 + c];
            unsigned cur = *mp;
            if (ml > cur) *mp = (unsigned short)ml;
            ml = 0; ++p; nb = 20;
          }
        }
        if (nb != 20){
          unsigned short* mp = &mx4u[p*256 + c];
          unsigned cur = *mp;
          if (ml > cur) *mp = (unsigned short)ml;
        }
      } else if (tid < 384){
        int c = tid - 256;
        int p = lr0/20;
        int nb = (p+1)*20 - lr0;
        unsigned ml = 0;
        for (int r=0;r<64;++r){
          unsigned v = (unsigned)(unsigned short)h3s[r*132 + c];
          ml = v > ml ? v : ml;
          if (--nb == 0){
            unsigned short* mp = &mx3u[p*128 + c];
            unsigned cur = *mp;
            if (ml > cur) *mp = (unsigned short)ml;
            ml = 0; ++p; nb = 20;
          }
        }
        if (nb != 20){
          unsigned short* mp = &mx3u[p*128 + c];
          unsigned cur = *mp;
          if (ml > cur) *mp = (unsigned short)ml;
        }
      }
    }
    __syncthreads();
  }
  int bn0 = blockIdx.x*16;
  {
    int p = tid >> 5, c0 = (tid & 31)*8;
    uint4 v = *(const uint4*)&mx4u[p*256 + c0];
    *(uint4*)&cat[(size_t)(bn0+p)*512 + 256 + c0] = v;
  }
  if (tid < 256){
    int p = tid >> 4, c0 = (tid & 15)*8;
    uint4 v = *(const uint4*)&mx3u[p*128 + c0];
    *(uint4*)&cat[(size_t)(bn0+p)*512 + 128 + c0] = v;
  }
}

// ---------------- layer 5 v4: double-buffered A-tiles + ob union (9 barriers vs 16) ----
__global__ __launch_bounds__(512) void l5_kernel(const bf16* __restrict__ cat,
                                                const bf16* __restrict__ W5T,
                                                const float* __restrict__ scale,
                                                const float* __restrict__ shift,
                                                float* __restrict__ out){
  __shared__ float obu[64*129];            // 33024 B; aliased as cs2[2][64*68] (17408 B)
  short* cs2 = (short*)obu;
  float* ob = obu;
  int tid = threadIdx.x, lane = tid & 63, w = tid >> 6;
  int pl = lane & 31;
  int ko = (lane >> 5)*8;
  int rbase = 4*(lane>>5);
  int mt = w & 1, ntb = w >> 1;          // nt = ntb + 4*s, s=0..3
  int arow = (mt*32 + pl)*68;
  int trow = tid >> 3, tc0 = (tid & 7)*8;
  int r0 = blockIdx.x*64;
  floatx16 acc[4];
  #pragma unroll
  for (int s=0;s<4;++s)
    #pragma unroll
    for (int q=0;q<16;++q) acc[s][q]=0.f;
  const bf16* arow_g = cat + (size_t)(r0+trow)*512 + tc0;
  uint4 hreg = *(const uint4*)arow_g;
  {
    short* dst = &cs2[trow*68 + tc0];
    *(uint2*)dst       = make_uint2(hreg.x, hreg.y);
    *(uint2*)(dst + 4) = make_uint2(hreg.z, hreg.w);
  }
  hreg = *(const uint4*)(arow_g + 64);
  __syncthreads();
  for (int kc8=0; kc8<8; ++kc8){
    int cur = kc8 & 1;
    if (kc8 < 7){
      short* dst = &cs2[(cur^1)*64*68 + trow*68 + tc0];
      *(uint2*)dst       = make_uint2(hreg.x, hreg.y);
      *(uint2*)(dst + 4) = make_uint2(hreg.z, hreg.w);
      if (kc8 < 6) hreg = *(const uint4*)(arow_g + (kc8+2)*64);
    }
    const short* csb = cs2 + cur*64*68;
    #pragma unroll
    for (int kq=0;kq<4;++kq){
      Frag a;
      const short* ap = &csb[arow + kq*16 + ko];
      a.u2[0] = *(const uint2*)ap;  a.u2[1] = *(const uint2*)(ap+4);
      #pragma unroll
      for (int s=0;s<4;++s){
        FragQ b;
        int col = (ntb + 4*s)*32 + pl;
        b.q = *(const uint4*)&W5T[(size_t)col*512 + kc8*64 + kq*16 + ko];
        acc[s] = __builtin_amdgcn_mfma_f32_32x32x16_bf16(a.v, b.v, acc[s], 0, 0, 0);
      }
    }
    __syncthreads();
  }
  int b = r0 >> 12, n0 = r0 & 4095;
  int colL = ntb*32 + pl;                // 0..127 within chunk
  int colc = tid >> 2, sub = tid & 3;    // writer mapping: 4 threads per col
  for (int s=0;s<4;++s){
    float sc = scale[128*s + colL], sh = shift[128*s + colL];
    #pragma unroll
    for (int q=0;q<16;++q){
      int m = mt*32 + (q&3) + 8*(q>>2) + rbase;
      ob[m*129 + colL] = fmaxf(fmaf(acc[s][q], sc, sh), 0.f);
    }
    __syncthreads();
    float* op = out + ((size_t)b*512 + 128*s + colc)*4096 + n0 + sub*16;
    #pragma unroll
    for (int j=0;j<4;++j){
      int rr = sub*16 + j*4;
      float4 v = make_float4(ob[(rr+0)*129 + colc], ob[(rr+1)*129 + colc],
                             ob[(rr+2)*129 + colc], ob[(rr+3)*129 + colc]);
      *(float4*)(op + j*4) = v;
    }
    __syncthreads();
  }
}

extern "C" void kernel_launch(void* const* d_in, const int* in_sizes, int n_in,
                              void* d_out, int out_size, void* d_ws, size_t ws_size,
                              hipStream_t stream){
  const float* x   = (const float*)d_in[0];
  const float* W1f = (const float*)d_in[1];
  const float* W2f = (const float*)d_in[2];
  const float* W3f = (const float*)d_in[3];
  const float* W4f = (const float*)d_in[4];
  const float* W5f = (const float*)d_in[5];
  const float* g1=(const float*)d_in[6],  *b1=(const float*)d_in[7];
  const float* g2=(const float*)d_in[8],  *b2=(const float*)d_in[9];
  const float* g3=(const float*)d_in[10], *b3=(const float*)d_in[11];
  const float* g4=(const float*)d_in[12], *b4=(const float*)d_in[13];
  const float* g5=(const float*)d_in[14], *b5=(const float*)d_in[15];
  float* out = (float*)d_out;

  char* w = (char*)d_ws;
  size_t off = 0;
  auto alloc = [&](size_t bytes)->void*{
    void* p = w + off;
    off = (off + bytes + 255) & ~(size_t)255;
    return p;
  };

  int*  idxb = (int*) alloc((size_t)BN*Kk*4);
  bf16* H2   = (bf16*)alloc((size_t)Mrows*64*2);
  bf16* catb = (bf16*)alloc((size_t)BN*512*2);
  bf16* W3T  = (bf16*)alloc((size_t)128*64*2);
  bf16* W4T  = (bf16*)alloc((size_t)256*128*2);
  bf16* W5T  = (bf16*)alloc((size_t)512*512*2);
  float* pv  = (float*)H2;
  int*   pib = (int*)((char*)H2 + (size_t)BN*8*Kk*4);

  size_t statsStart = off;
  float* partf=(float*)alloc(256*48*4);
  float* Gf=(float*)alloc(36*4);
  float* sumf=(float*)alloc(8*4);
  float* G2=(float*)alloc(4096*4);   float* sum2=(float*)alloc(64*4);
  float* G3=(float*)alloc(4096*4);   float* sum3=(float*)alloc(64*4);
  float* G4=(float*)alloc(16384*4);  float* sum4=(float*)alloc(128*4);
  float* G5=(float*)alloc(262144*4); float* sum5=(float*)alloc(512*4);
  float* P1=(float*)alloc(384*4);
  float* P2=(float*)alloc(4096*4);
  float* P3=(float*)alloc(8192*4);
  float* P4=(float*)alloc(32768*4);
  float* P5=(float*)alloc(262144*4);
  float* sc1=(float*)alloc(64*4);   float* sh1=(float*)alloc(64*4);
  float* sc2=(float*)alloc(64*4);   float* sh2=(float*)alloc(64*4);
  float* sc3=(float*)alloc(128*4);  float* sh3=(float*)alloc(128*4);
  float* sc4=(float*)alloc(256*4);  float* sh4=(float*)alloc(256*4);
  float* sc5=(float*)alloc(512*4);  float* sh5=(float*)alloc(512*4);
  size_t statsEnd = off;

  int statsFloats = (int)((statsEnd - statsStart)/4);
  zero_kernel<<<(statsFloats+255)/256,256,0,stream>>>((float*)(w+statsStart), statsFloats);
  w3t_kernel<<<32,256,0,stream>>>(W3f, W3T);
  w4t_kernel<<<128,256,0,stream>>>(W4f, W4T);
  w5t_kernel<<<1024,256,0,stream>>>(W5f, W5T);

  knnA_kernel<<<1024,256,0,stream>>>(x, pv, pib);
  knnB_kernel<<<BN/256,256,0,stream>>>(pv, pib, x, idxb, partf);

  const float invM  = 1.0f/(float)Mrows;
  const float invM5 = 1.0f/(float)BN;

  reducef_kernel<<<1,64,0,stream>>>(partf, Gf, sumf);
  kP_kernel<<<2,256,0,stream>>>(Gf, W1f, P1, 6, 64);
  kFinal_kernel<<<4,256,0,stream>>>(P1, sumf, W1f, g1, b1, sc1, sh1, 6, 64, invM);

  stats2_kernel<<<512,512,0,stream>>>(x, idxb, W1f, sc1, sh1, G2, sum2);
  kP_kernel<<<16,256,0,stream>>>(G2, W2f, P2, 64, 64);
  kFinal_kernel<<<4,256,0,stream>>>(P2, sum2, W2f, g2, b2, sc2, sh2, 64, 64, invM);

  fl12_kernel<<<BN,64,0,stream>>>(x, idxb, W1f, sc1, sh1, W2f, sc2, sh2, H2, catb);

  gram3_kernel<<<512,256,0,stream>>>(H2, Mrows, G3, sum3);
  kP_kernel<<<32,256,0,stream>>>(G3, W3f, P3, 64, 128);
  kFinal_kernel<<<8,256,0,stream>>>(P3, sum3, W3f, g3, b3, sc3, sh3, 64, 128, invM);

  stats4_kernel<<<512,512,0,stream>>>(H2, W3T, sc3, sh3, G4, sum4);
  kP_kernel<<<128,256,0,stream>>>(G4, W4f, P4, 128, 256);
  kFinal_kernel<<<16,256,0,stream>>>(P4, sum4, W4f, g4, b4, sc4, sh4, 128, 256, invM);

  fl34_kernel<<<Mrows/320,512,0,stream>>>(H2, W3T, sc3, sh3, W4T, sc4, sh4, catb);

  gram5_kernel<<<512,256,0,stream>>>(catb, G5, sum5);
  kP512_kernel<<<128,256,0,stream>>>(G5, W5f, P5);
  kFinal_kernel<<<32,256,0,stream>>>(P5, sum5, W5f, g5, b5, sc5, sh5, 512, 512, invM5);
  l5_kernel<<<BN/64,512,0,stream>>>(catb, W5T, sc5, sh5, out);
}